// Round 2
// baseline (16028.194 us; speedup 1.0000x reference)
//
#include <hip/hip_runtime.h>

// ---------------------------------------------------------------------------
// Seq2seq: 3-layer LSTM encoder + 3-layer LSTM decoder + dense vocab head
// B=32 T=128 V=32000 E=H=1024 L=3
// Sequences stored [T][B][*]; final dense epilogue permutes rows to [B][T][V].
// Recurrence: one persistent kernel per layer, 64 co-resident blocks,
// device-scope atomic grid barrier per timestep.
// ---------------------------------------------------------------------------

typedef __bf16 bf8 __attribute__((ext_vector_type(8)));
typedef float  f4  __attribute__((ext_vector_type(4)));

#define TLEN  128
#define HID   1024
#define G4    4096
#define VOC   32000
#define NBLK_SEQ 64

__device__ __forceinline__ ushort f2bf(float f) {
  unsigned u = __builtin_bit_cast(unsigned, f);
  u += 0x7fffu + ((u >> 16) & 1u);          // round-to-nearest-even
  return (ushort)(u >> 16);
}
__device__ __forceinline__ float sigmoidf_(float x) { return 1.f / (1.f + expf(-x)); }

typedef const __attribute__((address_space(1))) void GvoidC;
typedef __attribute__((address_space(3))) void Lvoid;
__device__ __forceinline__ void g2l16(const void* g, void* l) {
  // async global->LDS, 16B per lane; LDS dest = wave-uniform base + lane*16
  __builtin_amdgcn_global_load_lds((GvoidC*)g, (Lvoid*)l, 16, 0, 0);
}

// --- embedding gather: out[t*32+b][e] = bf16(emb[ids[b][t]][e]) -------------
__global__ __launch_bounds__(256) void embed_kernel(const int* __restrict__ ids,
    const float* __restrict__ emb, ushort* __restrict__ out) {
  int r = blockIdx.x;            // r = t*32 + b
  int b = r & 31, t = r >> 5;
  int id = ids[b * TLEN + t];
  const float4* src = (const float4*)(emb + (size_t)id * HID);
  float4 v = src[threadIdx.x];
  ushort4 o;
  o.x = f2bf(v.x); o.y = f2bf(v.y); o.z = f2bf(v.z); o.w = f2bf(v.w);
  *(ushort4*)(out + (size_t)r * HID + threadIdx.x * 4) = o;
}

// --- f32 [R][C] -> bf16 [C][R] tiled transpose ------------------------------
__global__ __launch_bounds__(256) void transpose_cvt(const float* __restrict__ W,
    ushort* __restrict__ Wt, int R, int C) {
  __shared__ float tile[32][33];
  int tx = threadIdx.x & 31, ty = threadIdx.x >> 5;   // ty 0..7
  int c0 = blockIdx.x * 32, r0 = blockIdx.y * 32;
  #pragma unroll
  for (int i = 0; i < 32; i += 8)
    tile[ty + i][tx] = W[(size_t)(r0 + ty + i) * C + c0 + tx];
  __syncthreads();
  #pragma unroll
  for (int i = 0; i < 32; i += 8)
    Wt[(size_t)(c0 + ty + i) * R + r0 + tx] = f2bf(tile[tx][ty + i]);
}

// --- bf16 MFMA GEMM: C[M][N] = A[M][K] @ Bt[N][K]^T + bias ------------------
// 128x128 tile, BK=32, 4 waves (2x2), 4x4 16x16 frags; m97-style staging via
// global_load_lds width=16 (each wave: 2x 1KB chunks per operand per K-step).
__global__ __launch_bounds__(256) void gemm_bt(const ushort* __restrict__ A,
    const ushort* __restrict__ Bt, const float* __restrict__ bias,
    float* __restrict__ C, int M, int N, int K, int permute) {
  __shared__ __align__(16) ushort lA[128 * 32];
  __shared__ __align__(16) ushort lB[128 * 32];
  int tid = threadIdx.x;
  int lane = tid & 63, wave = tid >> 6;
  int m0 = blockIdx.y * 128, n0 = blockIdx.x * 128;
  int wr = wave >> 1, wc = wave & 1;
  f4 zero = {0.f, 0.f, 0.f, 0.f};
  f4 acc[4][4];
  #pragma unroll
  for (int i = 0; i < 4; i++)
    #pragma unroll
    for (int j = 0; j < 4; j++) acc[i][j] = zero;

  const ushort* Ag = A  + (size_t)(m0 + wave * 32 + (lane >> 2)) * K + (lane & 3) * 8;
  const ushort* Bg = Bt + (size_t)(n0 + wave * 32 + (lane >> 2)) * K + (lane & 3) * 8;
  ushort* lAp = lA + wave * 32 * 32;   // wave-uniform LDS base (rows wave*32..)
  ushort* lBp = lB + wave * 32 * 32;

  for (int kt = 0; kt < K; kt += 32) {
    g2l16(Ag + kt, lAp);
    g2l16(Ag + (size_t)16 * K + kt, lAp + 16 * 32);
    g2l16(Bg + kt, lBp);
    g2l16(Bg + (size_t)16 * K + kt, lBp + 16 * 32);
    __syncthreads();                 // compiler emits vmcnt(0) drain
    bf8 aF[4], bF[4];
    #pragma unroll
    for (int i = 0; i < 4; i++)
      aF[i] = *(const bf8*)(lA + (wr * 64 + i * 16 + (lane & 15)) * 32 + (lane >> 4) * 8);
    #pragma unroll
    for (int j = 0; j < 4; j++)
      bF[j] = *(const bf8*)(lB + (wc * 64 + j * 16 + (lane & 15)) * 32 + (lane >> 4) * 8);
    #pragma unroll
    for (int i = 0; i < 4; i++)
      #pragma unroll
      for (int j = 0; j < 4; j++)
        acc[i][j] = __builtin_amdgcn_mfma_f32_16x16x32_bf16(aF[i], bF[j], acc[i][j], 0, 0, 0);
    __syncthreads();
  }
  #pragma unroll
  for (int i = 0; i < 4; i++) {
    #pragma unroll
    for (int j = 0; j < 4; j++) {
      int col = n0 + wc * 64 + j * 16 + (lane & 15);
      float bv = bias ? bias[col] : 0.f;
      #pragma unroll
      for (int v = 0; v < 4; v++) {
        int row = m0 + wr * 64 + i * 16 + (lane >> 4) * 4 + v;
        int orow = permute ? ((row & 31) * TLEN + (row >> 5)) : row;
        C[(size_t)orow * N + col] = acc[i][j][v] + bv;
      }
    }
  }
}

// --- persistent per-layer LSTM recurrence -----------------------------------
// 64 blocks x 256 threads (4 waves = 4 gates). Block jg owns h-cols
// [jg*16, jg*16+16). c state in registers across all 128 steps. Grid barrier
// (sense-reversing, device scope) between steps; Zpre prefetched 1 step ahead.
__global__ __launch_bounds__(256) void lstm_seq(
    const float*  __restrict__ Zpre,   // [TLEN][32][4096]
    const ushort* __restrict__ Wht,    // [4096][1024]
    const ushort* __restrict__ h0,     // [32][1024] initial h (dedicated buf)
    float*        __restrict__ cS,     // [32][1024] c state in/out
    ushort*       __restrict__ yout,   // [TLEN][32][1024]
    unsigned*     __restrict__ bar)    // bar[0]=cnt, bar[16]=gen
{
  const int jg = blockIdx.x;
  const int j0 = jg * 16;
  const int tid = threadIdx.x;
  const int lane = tid & 63, wave = tid >> 6;
  const int jj = tid & 15, rbase = tid >> 4;       // combine-phase mapping

  __shared__ float zbuf[4][32][16];

  float c0 = cS[(size_t)rbase * HID + j0 + jj];
  float c1 = cS[(size_t)(rbase + 16) * HID + j0 + jj];

  const ushort* Bp = Wht + (size_t)(wave * HID + j0 + (lane & 15)) * HID + (lane >> 4) * 8;
  const int aoff = (lane & 15) * HID + (lane >> 4) * 8;

  float zv[2][4], zn[2][4];
  #pragma unroll
  for (int p = 0; p < 2; p++)
    #pragma unroll
    for (int g = 0; g < 4; g++)
      zv[p][g] = Zpre[(size_t)(rbase + p * 16) * G4 + g * HID + j0 + jj];

  for (int t = 0; t < TLEN; ++t) {
    // prefetch next step's Z (overlaps MFMA + barrier)
    if (t + 1 < TLEN) {
      const float* Ztn = Zpre + (size_t)(t + 1) * 32 * G4;
      #pragma unroll
      for (int p = 0; p < 2; p++)
        #pragma unroll
        for (int g = 0; g < 4; g++)
          zn[p][g] = Ztn[(size_t)(rbase + p * 16) * G4 + g * HID + j0 + jj];
    }
    const ushort* hp = (t == 0) ? h0 : (yout + (size_t)(t - 1) * 32 * HID);
    const ushort* Ap = hp + aoff;
    f4 acc0 = {0.f, 0.f, 0.f, 0.f}, acc1 = {0.f, 0.f, 0.f, 0.f};
    #pragma unroll
    for (int kt = 0; kt < HID; kt += 32) {
      bf8 b  = *(const bf8*)(Bp + kt);
      bf8 a0 = *(const bf8*)(Ap + kt);
      bf8 a1 = *(const bf8*)(Ap + 16 * HID + kt);
      acc0 = __builtin_amdgcn_mfma_f32_16x16x32_bf16(a0, b, acc0, 0, 0, 0);
      acc1 = __builtin_amdgcn_mfma_f32_16x16x32_bf16(a1, b, acc1, 0, 0, 0);
    }
    #pragma unroll
    for (int v = 0; v < 4; v++) {
      zbuf[wave][(lane >> 4) * 4 + v][lane & 15]      = acc0[v];
      zbuf[wave][16 + (lane >> 4) * 4 + v][lane & 15] = acc1[v];
    }
    __syncthreads();
    float zi0 = zv[0][0] + zbuf[0][rbase][jj];
    float zf0 = zv[0][1] + zbuf[1][rbase][jj];
    float zg0 = zv[0][2] + zbuf[2][rbase][jj];
    float zo0 = zv[0][3] + zbuf[3][rbase][jj];
    float zi1 = zv[1][0] + zbuf[0][rbase + 16][jj];
    float zf1 = zv[1][1] + zbuf[1][rbase + 16][jj];
    float zg1 = zv[1][2] + zbuf[2][rbase + 16][jj];
    float zo1 = zv[1][3] + zbuf[3][rbase + 16][jj];
    c0 = sigmoidf_(zf0) * c0 + sigmoidf_(zi0) * tanhf(zg0);
    c1 = sigmoidf_(zf1) * c1 + sigmoidf_(zi1) * tanhf(zg1);
    float h0v = sigmoidf_(zo0) * tanhf(c0);
    float h1v = sigmoidf_(zo1) * tanhf(c1);
    ushort* yrow = yout + (size_t)t * 32 * HID;
    yrow[(size_t)rbase * HID + j0 + jj]        = f2bf(h0v);
    yrow[(size_t)(rbase + 16) * HID + j0 + jj] = f2bf(h1v);
    #pragma unroll
    for (int p = 0; p < 2; p++)
      #pragma unroll
      for (int g = 0; g < 4; g++)
        zv[p][g] = zn[p][g];

    if (t + 1 < TLEN) {
      // ---- grid barrier (release h, acquire others' h) ----
      __threadfence();               // drain + writeback (release side)
      __syncthreads();
      if (tid == 0) {
        unsigned g = __hip_atomic_load(bar + 16, __ATOMIC_RELAXED, __HIP_MEMORY_SCOPE_AGENT);
        unsigned a = __hip_atomic_fetch_add(bar, 1u, __ATOMIC_ACQ_REL, __HIP_MEMORY_SCOPE_AGENT);
        if (a == (unsigned)(NBLK_SEQ - 1)) {
          __hip_atomic_store(bar, 0u, __ATOMIC_RELAXED, __HIP_MEMORY_SCOPE_AGENT);
          __hip_atomic_store(bar + 16, g + 1u, __ATOMIC_RELEASE, __HIP_MEMORY_SCOPE_AGENT);
        } else {
          while (__hip_atomic_load(bar + 16, __ATOMIC_RELAXED, __HIP_MEMORY_SCOPE_AGENT) == g)
            __builtin_amdgcn_s_sleep(1);
        }
      }
      __syncthreads();
      __threadfence();               // acquire side: invalidate stale caches
    }
  }
  cS[(size_t)rbase * HID + j0 + jj]        = c0;
  cS[(size_t)(rbase + 16) * HID + j0 + jj] = c1;
}

// --- tiny state helpers -----------------------------------------------------
__global__ __launch_bounds__(256) void init_state(ushort* h, float* c, unsigned* bar) {
  int i = blockIdx.x * 256 + threadIdx.x;     // 128 blocks * 256 = 32768
  h[i] = 0; c[i] = 0.f;
  if (i == 0) { bar[0] = 0; bar[16] = 0; }
}
__global__ __launch_bounds__(256) void copy_h0(const ushort* __restrict__ src,
                                               ushort* __restrict__ h0) {
  int i = blockIdx.x * 256 + threadIdx.x;
  h0[i] = src[i];
}

// ---------------------------------------------------------------------------
extern "C" void kernel_launch(void* const* d_in, const int* in_sizes, int n_in,
                              void* d_out, int out_size, void* d_ws, size_t ws_size,
                              hipStream_t stream) {
  const int*   enc_ids = (const int*)d_in[0];
  const int*   dec_ids = (const int*)d_in[1];
  const float* emb     = (const float*)d_in[2];
  const float* Wx_enc  = (const float*)d_in[3];
  const float* Wh_enc  = (const float*)d_in[4];
  const float* b_enc   = (const float*)d_in[5];
  const float* Wx_dec  = (const float*)d_in[6];
  const float* Wh_dec  = (const float*)d_in[7];
  const float* b_dec   = (const float*)d_in[8];
  const float* dense_W = (const float*)d_in[9];
  const float* dense_b = (const float*)d_in[10];
  float* out = (float*)d_out;

  // workspace: bufA, bufB (bf16 ping-pong), Wxt, Wht, dWt, hstate, cS, bar
  char* ws = (char*)d_ws;
  const size_t SZ_BUF = (size_t)4096 * 1024 * 2;   // 8 MiB
  ushort*   bufA   = (ushort*)(ws);
  ushort*   bufB   = (ushort*)(ws + SZ_BUF);
  ushort*   Wxt    = (ushort*)(ws + 2 * SZ_BUF);
  ushort*   Wht    = (ushort*)(ws + 3 * SZ_BUF);
  ushort*   dWt    = (ushort*)(ws + 4 * SZ_BUF);   // VOC*1024*2 B
  char*     p2     = ws + 4 * SZ_BUF + (size_t)VOC * 1024 * 2;
  ushort*   hstate = (ushort*)p2;                            // 64 KiB
  float*    cS     = (float*)(p2 + (size_t)32 * 1024 * 2);   // 128 KiB
  unsigned* bar    = (unsigned*)(p2 + (size_t)32 * 1024 * 2 + (size_t)32 * 1024 * 4);
  float*    Zpre   = out;   // 64 MB scratch inside d_out (dead until dense)

  transpose_cvt<<<dim3(VOC / 32, 1024 / 32), 256, 0, stream>>>(dense_W, dWt, 1024, VOC);

  // ---------------- encoder ----------------
  embed_kernel<<<4096, 256, 0, stream>>>(enc_ids, emb, bufA);
  ushort* cur = bufA; ushort* oth = bufB;
  for (int l = 0; l < 3; l++) {
    transpose_cvt<<<dim3(G4 / 32, 32), 256, 0, stream>>>(Wx_enc + (size_t)l * 1024 * G4, Wxt, 1024, G4);
    transpose_cvt<<<dim3(G4 / 32, 32), 256, 0, stream>>>(Wh_enc + (size_t)l * 1024 * G4, Wht, 1024, G4);
    gemm_bt<<<dim3(G4 / 128, 4096 / 128), 256, 0, stream>>>(cur, Wxt, b_enc + (size_t)l * G4,
                                                            Zpre, 4096, G4, 1024, 0);
    init_state<<<128, 256, 0, stream>>>(hstate, cS, bar);    // zero h0, c, barrier
    lstm_seq<<<NBLK_SEQ, 256, 0, stream>>>(Zpre, Wht, hstate, cS, oth, bar);
    ushort* tmp = cur; cur = oth; oth = tmp;
  }
  ushort* encY = cur;    // encoder final y; rows 127*32.. hold enc-final h

  // ---------------- decoder ----------------
  embed_kernel<<<4096, 256, 0, stream>>>(dec_ids, emb, oth);
  { ushort* tmp = cur; cur = oth; oth = tmp; }   // cur = dec input, oth = encY
  for (int l = 0; l < 3; l++) {
    transpose_cvt<<<dim3(G4 / 32, 32), 256, 0, stream>>>(Wx_dec + (size_t)l * 1024 * G4, Wxt, 1024, G4);
    transpose_cvt<<<dim3(G4 / 32, 32), 256, 0, stream>>>(Wh_dec + (size_t)l * 1024 * G4, Wht, 1024, G4);
    gemm_bt<<<dim3(G4 / 128, 4096 / 128), 256, 0, stream>>>(cur, Wxt, b_dec + (size_t)l * G4,
                                                            Zpre, 4096, G4, 1024, 0);
    // h0 = previous stage's final h (copy BEFORE lstm_seq may overwrite buffer);
    // c chains in cS untouched (faithful state chaining)
    const ushort* h0src = (l == 0 ? encY : cur) + (size_t)127 * 32 * HID;
    copy_h0<<<128, 256, 0, stream>>>(h0src, hstate);
    lstm_seq<<<NBLK_SEQ, 256, 0, stream>>>(Zpre, Wht, hstate, cS, oth, bar);
    ushort* tmp = cur; cur = oth; oth = tmp;
  }

  // ---------------- dense head: logits[b][t][v] ----------------
  gemm_bt<<<dim3(VOC / 128, 4096 / 128), 256, 0, stream>>>(cur, dWt, dense_b, out,
                                                           4096, VOC, 1024, 1);
}

// Round 3
// 6678.825 us; speedup vs baseline: 2.3999x; 2.3999x over previous
//
#include <hip/hip_runtime.h>

// ---------------------------------------------------------------------------
// Seq2seq: 3-layer LSTM encoder + 3-layer LSTM decoder + dense vocab head
// B=32 T=128 V=32000 E=H=1024 L=3
// Sequences stored [T][B][*]; final dense epilogue permutes rows to [B][T][V].
// Recurrence: persistent kernel per layer, 64 co-resident blocks.
// Cross-block h exchange via system-scope (sc0 sc1) loads/stores = L1/L2
// bypass to shared L3 -> Wh stays hot in per-XCD L2 (no fences, no invalidate).
// Barrier: per-block step-tagged flag stores + wave-parallel flag polling
// (no atomic RMW, no L2 writeback/invalidate).
// ---------------------------------------------------------------------------

typedef __bf16 bf8 __attribute__((ext_vector_type(8)));
typedef float  f4  __attribute__((ext_vector_type(4)));

#define TLEN  128
#define HID   1024
#define G4    4096
#define VOC   32000
#define NBLK_SEQ 64

__device__ __forceinline__ ushort f2bf(float f) {
  unsigned u = __builtin_bit_cast(unsigned, f);
  u += 0x7fffu + ((u >> 16) & 1u);          // round-to-nearest-even
  return (ushort)(u >> 16);
}
__device__ __forceinline__ float sigmoidf_(float x) { return 1.f / (1.f + expf(-x)); }

// ---- system-scope (bypass L1+L2, coherent at L3) memory ops ----------------
__device__ __forceinline__ void ld16_sys(uint4& v, const void* p) {
  asm volatile("global_load_dwordx4 %0, %1, off sc0 sc1" : "=v"(v) : "v"(p));
}
__device__ __forceinline__ unsigned ld4_sys(const void* p) {
  unsigned v;
  asm volatile("global_load_dword %0, %1, off sc0 sc1\n\ts_waitcnt vmcnt(0)"
               : "=v"(v) : "v"(p) : "memory");
  return v;
}
__device__ __forceinline__ void st4_sys(void* p, unsigned v) {
  asm volatile("global_store_dword %0, %1, off sc0 sc1" :: "v"(p), "v"(v) : "memory");
}
__device__ __forceinline__ void wait_vm0() {
  asm volatile("s_waitcnt vmcnt(0)" ::: "memory");
  __builtin_amdgcn_sched_barrier(0);
}

typedef const __attribute__((address_space(1))) void GvoidC;
typedef __attribute__((address_space(3))) void Lvoid;
__device__ __forceinline__ void g2l16(const void* g, void* l) {
  __builtin_amdgcn_global_load_lds((GvoidC*)g, (Lvoid*)l, 16, 0, 0);
}

// --- embedding gather: out[t*32+b][e] = bf16(emb[ids[b][t]][e]) -------------
__global__ __launch_bounds__(256) void embed_kernel(const int* __restrict__ ids,
    const float* __restrict__ emb, ushort* __restrict__ out) {
  int r = blockIdx.x;            // r = t*32 + b
  int b = r & 31, t = r >> 5;
  int id = ids[b * TLEN + t];
  const float4* src = (const float4*)(emb + (size_t)id * HID);
  float4 v = src[threadIdx.x];
  ushort4 o;
  o.x = f2bf(v.x); o.y = f2bf(v.y); o.z = f2bf(v.z); o.w = f2bf(v.w);
  *(ushort4*)(out + (size_t)r * HID + threadIdx.x * 4) = o;
}

// --- f32 [R][C] -> bf16 [C][R] tiled transpose ------------------------------
__global__ __launch_bounds__(256) void transpose_cvt(const float* __restrict__ W,
    ushort* __restrict__ Wt, int R, int C) {
  __shared__ float tile[32][33];
  int tx = threadIdx.x & 31, ty = threadIdx.x >> 5;   // ty 0..7
  int c0 = blockIdx.x * 32, r0 = blockIdx.y * 32;
  #pragma unroll
  for (int i = 0; i < 32; i += 8)
    tile[ty + i][tx] = W[(size_t)(r0 + ty + i) * C + c0 + tx];
  __syncthreads();
  #pragma unroll
  for (int i = 0; i < 32; i += 8)
    Wt[(size_t)(c0 + ty + i) * R + r0 + tx] = f2bf(tile[tx][ty + i]);
}

// --- bf16 MFMA GEMM: C[M][N] = A[M][K] @ Bt[N][K]^T + bias ------------------
__global__ __launch_bounds__(256) void gemm_bt(const ushort* __restrict__ A,
    const ushort* __restrict__ Bt, const float* __restrict__ bias,
    float* __restrict__ C, int M, int N, int K, int permute) {
  __shared__ __align__(16) ushort lA[128 * 32];
  __shared__ __align__(16) ushort lB[128 * 32];
  int tid = threadIdx.x;
  int lane = tid & 63, wave = tid >> 6;
  int m0 = blockIdx.y * 128, n0 = blockIdx.x * 128;
  int wr = wave >> 1, wc = wave & 1;
  f4 zero = {0.f, 0.f, 0.f, 0.f};
  f4 acc[4][4];
  #pragma unroll
  for (int i = 0; i < 4; i++)
    #pragma unroll
    for (int j = 0; j < 4; j++) acc[i][j] = zero;

  const ushort* Ag = A  + (size_t)(m0 + wave * 32 + (lane >> 2)) * K + (lane & 3) * 8;
  const ushort* Bg = Bt + (size_t)(n0 + wave * 32 + (lane >> 2)) * K + (lane & 3) * 8;
  ushort* lAp = lA + wave * 32 * 32;
  ushort* lBp = lB + wave * 32 * 32;

  for (int kt = 0; kt < K; kt += 32) {
    g2l16(Ag + kt, lAp);
    g2l16(Ag + (size_t)16 * K + kt, lAp + 16 * 32);
    g2l16(Bg + kt, lBp);
    g2l16(Bg + (size_t)16 * K + kt, lBp + 16 * 32);
    __syncthreads();
    bf8 aF[4], bF[4];
    #pragma unroll
    for (int i = 0; i < 4; i++)
      aF[i] = *(const bf8*)(lA + (wr * 64 + i * 16 + (lane & 15)) * 32 + (lane >> 4) * 8);
    #pragma unroll
    for (int j = 0; j < 4; j++)
      bF[j] = *(const bf8*)(lB + (wc * 64 + j * 16 + (lane & 15)) * 32 + (lane >> 4) * 8);
    #pragma unroll
    for (int i = 0; i < 4; i++)
      #pragma unroll
      for (int j = 0; j < 4; j++)
        acc[i][j] = __builtin_amdgcn_mfma_f32_16x16x32_bf16(aF[i], bF[j], acc[i][j], 0, 0, 0);
    __syncthreads();
  }
  #pragma unroll
  for (int i = 0; i < 4; i++) {
    #pragma unroll
    for (int j = 0; j < 4; j++) {
      int col = n0 + wc * 64 + j * 16 + (lane & 15);
      float bv = bias ? bias[col] : 0.f;
      #pragma unroll
      for (int v = 0; v < 4; v++) {
        int row = m0 + wr * 64 + i * 16 + (lane >> 4) * 4 + v;
        int orow = permute ? ((row & 31) * TLEN + (row >> 5)) : row;
        C[(size_t)orow * N + col] = acc[i][j][v] + bv;
      }
    }
  }
}

// --- persistent per-layer LSTM recurrence -----------------------------------
// 64 blocks x 256 threads (4 waves = 4 gates). Block jg owns h-cols
// [jg*16, jg*16+16). c in registers across all 128 steps.
// Per step: poll flags -> stage h into LDS (swizzled) -> MFMA (A:LDS, B:L2)
// -> gate exchange -> combine/gates -> sys-store packed h -> flag.
__global__ __launch_bounds__(256) void lstm_seq(
    const float*  __restrict__ Zpre,   // [TLEN][32][4096] (incl bias)
    const ushort* __restrict__ Wht,    // [4096][1024]
    const ushort* __restrict__ h0,     // [32][1024] initial h
    float*        __restrict__ cS,     // [32][1024] c state in/out
    ushort*       __restrict__ yout,   // [TLEN][32][1024]
    unsigned*     __restrict__ flags)  // 64 flags, stride 4 dwords
{
  const int jg = blockIdx.x;
  const int j0 = jg * 16;
  const int tid = threadIdx.x;
  const int lane = tid & 63, wave = tid >> 6;
  const int rr = tid >> 3, cp = tid & 7;            // combine: row 0..31, colpair 0..7

  __shared__ __align__(16) char hLDS[65536];        // [32][1024] bf16, XOR-swizzled
  __shared__ float zbuf[4][32][16];

  float2 cc = *(const float2*)(cS + (size_t)rr * HID + j0 + 2 * cp);

  const ushort* Bp = Wht + (size_t)(wave * HID + j0 + (lane & 15)) * HID + (lane >> 4) * 8;
  const int r0 = lane & 15, r1 = r0 + 16;
  const int klb = (lane >> 4) * 16;                 // byte offset of k-slice in row
  const int swz = (r0 & 7) << 4;                    // same for r0 and r1

  float2 zv[4], zn[4];
  #pragma unroll
  for (int g = 0; g < 4; g++)
    zv[g] = *(const float2*)(Zpre + (size_t)rr * G4 + g * HID + j0 + 2 * cp);

  for (int t = 0; t < TLEN; ++t) {
    // ---- wait for all blocks to have published h_{t-1} ----
    if (t > 0) {
      if (wave == 0) {
        const unsigned* fp = flags + lane * 4;
        while (__ballot(ld4_sys(fp) < (unsigned)t)) __builtin_amdgcn_s_sleep(1);
      }
      __syncthreads();
    }
    // ---- stage h_{t-1} (64KB) into LDS via L2-bypassing loads ----
    const char* hsrc = (t == 0) ? (const char*)h0
                                : (const char*)(yout + (size_t)(t - 1) * 32 * HID);
    uint4 hreg[16];
    #pragma unroll
    for (int it = 0; it < 16; it++)
      ld16_sys(hreg[it], hsrc + (size_t)(tid + it * 256) * 16);
    wait_vm0();
    #pragma unroll
    for (int it = 0; it < 16; it++) {
      int c = tid + it * 256;
      int row = c >> 7;                       // 128 chunks per 2048B row
      int o = (c & 127) * 16;
      *(uint4*)(hLDS + row * 2048 + (o ^ ((row & 7) << 4))) = hreg[it];
    }
    __syncthreads();

    // prefetch next step's Z (normal cached loads; overlaps MFMA)
    if (t + 1 < TLEN) {
      const float* Ztn = Zpre + (size_t)(t + 1) * 32 * G4;
      #pragma unroll
      for (int g = 0; g < 4; g++)
        zn[g] = *(const float2*)(Ztn + (size_t)rr * G4 + g * HID + j0 + 2 * cp);
    }

    // ---- h @ Wh: A from LDS (swizzled), B from L2-resident Wht ----
    f4 acc0 = {0.f, 0.f, 0.f, 0.f}, acc1 = {0.f, 0.f, 0.f, 0.f};
    #pragma unroll
    for (int kt = 0; kt < HID; kt += 32) {
      bf8 b  = *(const bf8*)(Bp + kt);
      int cb = kt * 2 + klb;
      bf8 a0 = *(const bf8*)(hLDS + r0 * 2048 + (cb ^ swz));
      bf8 a1 = *(const bf8*)(hLDS + r1 * 2048 + (cb ^ swz));
      acc0 = __builtin_amdgcn_mfma_f32_16x16x32_bf16(a0, b, acc0, 0, 0, 0);
      acc1 = __builtin_amdgcn_mfma_f32_16x16x32_bf16(a1, b, acc1, 0, 0, 0);
    }
    #pragma unroll
    for (int v = 0; v < 4; v++) {
      zbuf[wave][(lane >> 4) * 4 + v][lane & 15]      = acc0[v];
      zbuf[wave][16 + (lane >> 4) * 4 + v][lane & 15] = acc1[v];
    }
    __syncthreads();

    // ---- combine + gates (thread owns row rr, cols 2cp,2cp+1) ----
    float zi0 = zv[0].x + zbuf[0][rr][2 * cp],     zi1 = zv[0].y + zbuf[0][rr][2 * cp + 1];
    float zf0 = zv[1].x + zbuf[1][rr][2 * cp],     zf1 = zv[1].y + zbuf[1][rr][2 * cp + 1];
    float zg0 = zv[2].x + zbuf[2][rr][2 * cp],     zg1 = zv[2].y + zbuf[2][rr][2 * cp + 1];
    float zo0 = zv[3].x + zbuf[3][rr][2 * cp],     zo1 = zv[3].y + zbuf[3][rr][2 * cp + 1];
    cc.x = sigmoidf_(zf0) * cc.x + sigmoidf_(zi0) * tanhf(zg0);
    cc.y = sigmoidf_(zf1) * cc.y + sigmoidf_(zi1) * tanhf(zg1);
    float hv0 = sigmoidf_(zo0) * tanhf(cc.x);
    float hv1 = sigmoidf_(zo1) * tanhf(cc.y);
    unsigned packed = (unsigned)f2bf(hv0) | ((unsigned)f2bf(hv1) << 16);
    st4_sys((char*)(yout + (size_t)t * 32 * HID) + ((size_t)rr * HID + j0 + 2 * cp) * 2,
            packed);
    #pragma unroll
    for (int g = 0; g < 4; g++) zv[g] = zn[g];

    // ---- publish: drain stores (per wave), sync, raise flag ----
    wait_vm0();
    __syncthreads();
    if (tid == 0) st4_sys(flags + jg * 4, (unsigned)(t + 1));
  }
  *(float2*)(cS + (size_t)rr * HID + j0 + 2 * cp) = cc;
}

// --- state prep (also zeroes barrier flags; runs before each lstm_seq) ------
__global__ __launch_bounds__(256) void prep_zero(ushort* h0, float* c, unsigned* flags) {
  int i = blockIdx.x * 256 + threadIdx.x;     // 128 blocks * 256 = 32768
  h0[i] = 0; c[i] = 0.f;
  if (i < NBLK_SEQ) flags[i * 4] = 0;
}
__global__ __launch_bounds__(256) void prep_copy(const ushort* __restrict__ src,
                                                 ushort* __restrict__ h0,
                                                 unsigned* __restrict__ flags) {
  int i = blockIdx.x * 256 + threadIdx.x;
  h0[i] = src[i];
  if (i < NBLK_SEQ) flags[i * 4] = 0;
}

// ---------------------------------------------------------------------------
extern "C" void kernel_launch(void* const* d_in, const int* in_sizes, int n_in,
                              void* d_out, int out_size, void* d_ws, size_t ws_size,
                              hipStream_t stream) {
  const int*   enc_ids = (const int*)d_in[0];
  const int*   dec_ids = (const int*)d_in[1];
  const float* emb     = (const float*)d_in[2];
  const float* Wx_enc  = (const float*)d_in[3];
  const float* Wh_enc  = (const float*)d_in[4];
  const float* b_enc   = (const float*)d_in[5];
  const float* Wx_dec  = (const float*)d_in[6];
  const float* Wh_dec  = (const float*)d_in[7];
  const float* b_dec   = (const float*)d_in[8];
  const float* dense_W = (const float*)d_in[9];
  const float* dense_b = (const float*)d_in[10];
  float* out = (float*)d_out;

  char* ws = (char*)d_ws;
  const size_t SZ_BUF = (size_t)4096 * 1024 * 2;   // 8 MiB
  ushort*   bufA   = (ushort*)(ws);
  ushort*   bufB   = (ushort*)(ws + SZ_BUF);
  ushort*   Wxt    = (ushort*)(ws + 2 * SZ_BUF);
  ushort*   Wht    = (ushort*)(ws + 3 * SZ_BUF);
  ushort*   dWt    = (ushort*)(ws + 4 * SZ_BUF);   // VOC*1024*2 B
  char*     p2     = ws + 4 * SZ_BUF + (size_t)VOC * 1024 * 2;
  ushort*   hstate = (ushort*)p2;                            // 64 KiB
  float*    cS     = (float*)(p2 + (size_t)32 * 1024 * 2);   // 128 KiB
  unsigned* flags  = (unsigned*)(p2 + (size_t)32 * 1024 * 2 + (size_t)32 * 1024 * 4);
  float*    Zpre   = out;   // 64 MB scratch inside d_out (dead until dense)

  transpose_cvt<<<dim3(VOC / 32, 1024 / 32), 256, 0, stream>>>(dense_W, dWt, 1024, VOC);

  // ---------------- encoder ----------------
  embed_kernel<<<4096, 256, 0, stream>>>(enc_ids, emb, bufA);
  ushort* cur = bufA; ushort* oth = bufB;
  for (int l = 0; l < 3; l++) {
    transpose_cvt<<<dim3(G4 / 32, 32), 256, 0, stream>>>(Wx_enc + (size_t)l * 1024 * G4, Wxt, 1024, G4);
    transpose_cvt<<<dim3(G4 / 32, 32), 256, 0, stream>>>(Wh_enc + (size_t)l * 1024 * G4, Wht, 1024, G4);
    gemm_bt<<<dim3(G4 / 128, 4096 / 128), 256, 0, stream>>>(cur, Wxt, b_enc + (size_t)l * G4,
                                                            Zpre, 4096, G4, 1024, 0);
    prep_zero<<<128, 256, 0, stream>>>(hstate, cS, flags);
    lstm_seq<<<NBLK_SEQ, 256, 0, stream>>>(Zpre, Wht, hstate, cS, oth, flags);
    ushort* tmp = cur; cur = oth; oth = tmp;
  }
  ushort* encY = cur;    // rows 127*32.. hold enc-final h

  // ---------------- decoder ----------------
  embed_kernel<<<4096, 256, 0, stream>>>(dec_ids, emb, oth);
  { ushort* tmp = cur; cur = oth; oth = tmp; }   // cur = dec input, oth = encY
  for (int l = 0; l < 3; l++) {
    transpose_cvt<<<dim3(G4 / 32, 32), 256, 0, stream>>>(Wx_dec + (size_t)l * 1024 * G4, Wxt, 1024, G4);
    transpose_cvt<<<dim3(G4 / 32, 32), 256, 0, stream>>>(Wh_dec + (size_t)l * 1024 * G4, Wht, 1024, G4);
    gemm_bt<<<dim3(G4 / 128, 4096 / 128), 256, 0, stream>>>(cur, Wxt, b_dec + (size_t)l * G4,
                                                            Zpre, 4096, G4, 1024, 0);
    const ushort* h0src = (l == 0 ? encY : cur) + (size_t)127 * 32 * HID;
    prep_copy<<<128, 256, 0, stream>>>(h0src, hstate, flags);   // c chains in cS
    lstm_seq<<<NBLK_SEQ, 256, 0, stream>>>(Zpre, Wht, hstate, cS, oth, flags);
    ushort* tmp = cur; cur = oth; oth = tmp;
  }

  // ---------------- dense head: logits[b][t][v] ----------------
  gemm_bt<<<dim3(VOC / 128, 4096 / 128), 256, 0, stream>>>(cur, dWt, dense_b, out,
                                                           4096, VOC, 1024, 1);
}

// Round 4
// 4449.800 us; speedup vs baseline: 3.6020x; 1.5009x over previous
//
#include <hip/hip_runtime.h>

// ---------------------------------------------------------------------------
// Seq2seq: 3-layer LSTM encoder + 3-layer LSTM decoder + dense vocab head
// B=32 T=128 V=32000 E=H=1024 L=3
// Sequences stored [T][B][*]; final dense epilogue permutes rows to [B][T][V].
// Recurrence: persistent kernel per layer, 64 co-resident blocks.
//  - Wh tile per wave preloaded into 32 bf8 register fragments (128 VGPR),
//    loaded ONCE per layer -> MFMA loop has no global loads at all.
//  - Cross-block h exchange via system-scope (sc0 sc1) loads/stores (L1/L2
//    bypass, coherent at L3); no fences -> L2 state (Zpre) stays warm.
//  - Barrier: per-block step-tagged flag stores + wave-parallel flag polling.
// ---------------------------------------------------------------------------

typedef __bf16 bf8 __attribute__((ext_vector_type(8)));
typedef float  f4  __attribute__((ext_vector_type(4)));

#define TLEN  128
#define HID   1024
#define G4    4096
#define VOC   32000
#define NBLK_SEQ 64

__device__ __forceinline__ ushort f2bf(float f) {
  unsigned u = __builtin_bit_cast(unsigned, f);
  u += 0x7fffu + ((u >> 16) & 1u);          // round-to-nearest-even
  return (ushort)(u >> 16);
}
__device__ __forceinline__ float sigmoidf_(float x) { return 1.f / (1.f + expf(-x)); }

// ---- system-scope (bypass L1+L2, coherent at L3) memory ops ----------------
__device__ __forceinline__ void ld16_sys(uint4& v, const void* p) {
  asm volatile("global_load_dwordx4 %0, %1, off sc0 sc1" : "=v"(v) : "v"(p));
}
__device__ __forceinline__ unsigned ld4_sys(const void* p) {
  unsigned v;
  asm volatile("global_load_dword %0, %1, off sc0 sc1\n\ts_waitcnt vmcnt(0)"
               : "=v"(v) : "v"(p) : "memory");
  return v;
}
__device__ __forceinline__ void st4_sys(void* p, unsigned v) {
  asm volatile("global_store_dword %0, %1, off sc0 sc1" :: "v"(p), "v"(v) : "memory");
}
__device__ __forceinline__ void wait_vm0() {
  asm volatile("s_waitcnt vmcnt(0)" ::: "memory");
  __builtin_amdgcn_sched_barrier(0);
}

typedef const __attribute__((address_space(1))) void GvoidC;
typedef __attribute__((address_space(3))) void Lvoid;
__device__ __forceinline__ void g2l16(const void* g, void* l) {
  __builtin_amdgcn_global_load_lds((GvoidC*)g, (Lvoid*)l, 16, 0, 0);
}

// --- embedding gather: out[t*32+b][e] = bf16(emb[ids[b][t]][e]) -------------
__global__ __launch_bounds__(256) void embed_kernel(const int* __restrict__ ids,
    const float* __restrict__ emb, ushort* __restrict__ out) {
  int r = blockIdx.x;            // r = t*32 + b
  int b = r & 31, t = r >> 5;
  int id = ids[b * TLEN + t];
  const float4* src = (const float4*)(emb + (size_t)id * HID);
  float4 v = src[threadIdx.x];
  ushort4 o;
  o.x = f2bf(v.x); o.y = f2bf(v.y); o.z = f2bf(v.z); o.w = f2bf(v.w);
  *(ushort4*)(out + (size_t)r * HID + threadIdx.x * 4) = o;
}

// --- f32 [R][C] -> bf16 [C][R] tiled transpose ------------------------------
__global__ __launch_bounds__(256) void transpose_cvt(const float* __restrict__ W,
    ushort* __restrict__ Wt, int R, int C) {
  __shared__ float tile[32][33];
  int tx = threadIdx.x & 31, ty = threadIdx.x >> 5;   // ty 0..7
  int c0 = blockIdx.x * 32, r0 = blockIdx.y * 32;
  #pragma unroll
  for (int i = 0; i < 32; i += 8)
    tile[ty + i][tx] = W[(size_t)(r0 + ty + i) * C + c0 + tx];
  __syncthreads();
  #pragma unroll
  for (int i = 0; i < 32; i += 8)
    Wt[(size_t)(c0 + ty + i) * R + r0 + tx] = f2bf(tile[tx][ty + i]);
}

// --- bf16 MFMA GEMM: C[M][N] = A[M][K] @ Bt[N][K]^T + bias ------------------
__global__ __launch_bounds__(256) void gemm_bt(const ushort* __restrict__ A,
    const ushort* __restrict__ Bt, const float* __restrict__ bias,
    float* __restrict__ C, int M, int N, int K, int permute) {
  __shared__ __align__(16) ushort lA[128 * 32];
  __shared__ __align__(16) ushort lB[128 * 32];
  int tid = threadIdx.x;
  int lane = tid & 63, wave = tid >> 6;
  int m0 = blockIdx.y * 128, n0 = blockIdx.x * 128;
  int wr = wave >> 1, wc = wave & 1;
  f4 zero = {0.f, 0.f, 0.f, 0.f};
  f4 acc[4][4];
  #pragma unroll
  for (int i = 0; i < 4; i++)
    #pragma unroll
    for (int j = 0; j < 4; j++) acc[i][j] = zero;

  const ushort* Ag = A  + (size_t)(m0 + wave * 32 + (lane >> 2)) * K + (lane & 3) * 8;
  const ushort* Bg = Bt + (size_t)(n0 + wave * 32 + (lane >> 2)) * K + (lane & 3) * 8;
  ushort* lAp = lA + wave * 32 * 32;
  ushort* lBp = lB + wave * 32 * 32;

  for (int kt = 0; kt < K; kt += 32) {
    g2l16(Ag + kt, lAp);
    g2l16(Ag + (size_t)16 * K + kt, lAp + 16 * 32);
    g2l16(Bg + kt, lBp);
    g2l16(Bg + (size_t)16 * K + kt, lBp + 16 * 32);
    __syncthreads();
    bf8 aF[4], bF[4];
    #pragma unroll
    for (int i = 0; i < 4; i++)
      aF[i] = *(const bf8*)(lA + (wr * 64 + i * 16 + (lane & 15)) * 32 + (lane >> 4) * 8);
    #pragma unroll
    for (int j = 0; j < 4; j++)
      bF[j] = *(const bf8*)(lB + (wc * 64 + j * 16 + (lane & 15)) * 32 + (lane >> 4) * 8);
    #pragma unroll
    for (int i = 0; i < 4; i++)
      #pragma unroll
      for (int j = 0; j < 4; j++)
        acc[i][j] = __builtin_amdgcn_mfma_f32_16x16x32_bf16(aF[i], bF[j], acc[i][j], 0, 0, 0);
    __syncthreads();
  }
  #pragma unroll
  for (int i = 0; i < 4; i++) {
    #pragma unroll
    for (int j = 0; j < 4; j++) {
      int col = n0 + wc * 64 + j * 16 + (lane & 15);
      float bv = bias ? bias[col] : 0.f;
      #pragma unroll
      for (int v = 0; v < 4; v++) {
        int row = m0 + wr * 64 + i * 16 + (lane >> 4) * 4 + v;
        int orow = permute ? ((row & 31) * TLEN + (row >> 5)) : row;
        C[(size_t)orow * N + col] = acc[i][j][v] + bv;
      }
    }
  }
}

// --- persistent per-layer LSTM recurrence -----------------------------------
// 64 blocks x 256 threads (4 waves = 4 gates). Block jg owns h-cols
// [jg*16, jg*16+16). c in registers; Wh tile in registers (loaded once).
// Per step: poll flags -> stage h into LDS (swizzled) -> MFMA (A:LDS, B:reg)
// -> gate exchange -> combine/gates -> sys-store packed h -> flag.
__global__ __launch_bounds__(256, 1) void lstm_seq(
    const float*  __restrict__ Zpre,   // [TLEN][32][4096] (incl bias)
    const ushort* __restrict__ Wht,    // [4096][1024]
    const ushort* __restrict__ h0,     // [32][1024] initial h
    float*        __restrict__ cS,     // [32][1024] c state in/out
    ushort*       __restrict__ yout,   // [TLEN][32][1024]
    unsigned*     __restrict__ flags)  // 64 flags, stride 4 dwords
{
  const int jg = blockIdx.x;
  const int j0 = jg * 16;
  const int tid = threadIdx.x;
  const int lane = tid & 63, wave = tid >> 6;
  const int rr = tid >> 3, cp = tid & 7;            // combine: row 0..31, colpair 0..7

  __shared__ __align__(16) char hLDS[65536];        // [32][1024] bf16, XOR-swizzled
  __shared__ float zbuf[4][32][16];

  float2 cc = *(const float2*)(cS + (size_t)rr * HID + j0 + 2 * cp);

  // ---- preload this wave's Wh tile into registers (128 VGPR, once/layer) ---
  const ushort* Bp = Wht + (size_t)(wave * HID + j0 + (lane & 15)) * HID + (lane >> 4) * 8;
  bf8 bw[32];
  #pragma unroll
  for (int kk = 0; kk < 32; kk++)
    bw[kk] = *(const bf8*)(Bp + kk * 32);

  const int r0 = lane & 15, r1 = r0 + 16;
  const int klb = (lane >> 4) * 16;                 // byte offset of k-slice in row
  const int swz = (r0 & 7) << 4;                    // same for r0 and r1

  float2 zv[4], zn[4];
  #pragma unroll
  for (int g = 0; g < 4; g++)
    zv[g] = *(const float2*)(Zpre + (size_t)rr * G4 + g * HID + j0 + 2 * cp);

  for (int t = 0; t < TLEN; ++t) {
    // ---- wait for all blocks to have published h_{t-1} ----
    if (t > 0) {
      if (wave == 0) {
        const unsigned* fp = flags + lane * 4;
        while (__ballot(ld4_sys(fp) < (unsigned)t)) __builtin_amdgcn_s_sleep(1);
      }
      __syncthreads();
    }
    // ---- stage h_{t-1} (64KB) into LDS via L2-bypassing loads ----
    const char* hsrc = (t == 0) ? (const char*)h0
                                : (const char*)(yout + (size_t)(t - 1) * 32 * HID);
    uint4 hreg[16];
    #pragma unroll
    for (int it = 0; it < 16; it++)
      ld16_sys(hreg[it], hsrc + (size_t)(tid + it * 256) * 16);
    wait_vm0();
    #pragma unroll
    for (int it = 0; it < 16; it++) {
      int c = tid + it * 256;
      int row = c >> 7;                       // 128 chunks per 2048B row
      int o = (c & 127) * 16;
      *(uint4*)(hLDS + row * 2048 + (o ^ ((row & 7) << 4))) = hreg[it];
    }
    __syncthreads();

    // prefetch next step's Z (normal cached loads; overlaps MFMA)
    if (t + 1 < TLEN) {
      const float* Ztn = Zpre + (size_t)(t + 1) * 32 * G4;
      #pragma unroll
      for (int g = 0; g < 4; g++)
        zn[g] = *(const float2*)(Ztn + (size_t)rr * G4 + g * HID + j0 + 2 * cp);
    }

    // ---- h @ Wh: A from LDS (swizzled), B from registers ----
    f4 acc0 = {0.f, 0.f, 0.f, 0.f}, acc1 = {0.f, 0.f, 0.f, 0.f};
    #pragma unroll
    for (int kk = 0; kk < 32; kk++) {
      int cb = kk * 64 + klb;
      bf8 a0 = *(const bf8*)(hLDS + r0 * 2048 + (cb ^ swz));
      bf8 a1 = *(const bf8*)(hLDS + r1 * 2048 + (cb ^ swz));
      acc0 = __builtin_amdgcn_mfma_f32_16x16x32_bf16(a0, bw[kk], acc0, 0, 0, 0);
      acc1 = __builtin_amdgcn_mfma_f32_16x16x32_bf16(a1, bw[kk], acc1, 0, 0, 0);
    }
    #pragma unroll
    for (int v = 0; v < 4; v++) {
      zbuf[wave][(lane >> 4) * 4 + v][lane & 15]      = acc0[v];
      zbuf[wave][16 + (lane >> 4) * 4 + v][lane & 15] = acc1[v];
    }
    __syncthreads();

    // ---- combine + gates (thread owns row rr, cols 2cp,2cp+1) ----
    float zi0 = zv[0].x + zbuf[0][rr][2 * cp],     zi1 = zv[0].y + zbuf[0][rr][2 * cp + 1];
    float zf0 = zv[1].x + zbuf[1][rr][2 * cp],     zf1 = zv[1].y + zbuf[1][rr][2 * cp + 1];
    float zg0 = zv[2].x + zbuf[2][rr][2 * cp],     zg1 = zv[2].y + zbuf[2][rr][2 * cp + 1];
    float zo0 = zv[3].x + zbuf[3][rr][2 * cp],     zo1 = zv[3].y + zbuf[3][rr][2 * cp + 1];
    cc.x = sigmoidf_(zf0) * cc.x + sigmoidf_(zi0) * tanhf(zg0);
    cc.y = sigmoidf_(zf1) * cc.y + sigmoidf_(zi1) * tanhf(zg1);
    float hv0 = sigmoidf_(zo0) * tanhf(cc.x);
    float hv1 = sigmoidf_(zo1) * tanhf(cc.y);
    unsigned packed = (unsigned)f2bf(hv0) | ((unsigned)f2bf(hv1) << 16);
    st4_sys((char*)(yout + (size_t)t * 32 * HID) + ((size_t)rr * HID + j0 + 2 * cp) * 2,
            packed);
    #pragma unroll
    for (int g = 0; g < 4; g++) zv[g] = zn[g];

    // ---- publish: drain stores (per wave), sync, raise flag ----
    wait_vm0();
    __syncthreads();
    if (tid == 0) st4_sys(flags + jg * 4, (unsigned)(t + 1));
  }
  *(float2*)(cS + (size_t)rr * HID + j0 + 2 * cp) = cc;
}

// --- state prep (also zeroes barrier flags; runs before each lstm_seq) ------
__global__ __launch_bounds__(256) void prep_zero(ushort* h0, float* c, unsigned* flags) {
  int i = blockIdx.x * 256 + threadIdx.x;     // 128 blocks * 256 = 32768
  h0[i] = 0; c[i] = 0.f;
  if (i < NBLK_SEQ) flags[i * 4] = 0;
}
__global__ __launch_bounds__(256) void prep_copy(const ushort* __restrict__ src,
                                                 ushort* __restrict__ h0,
                                                 unsigned* __restrict__ flags) {
  int i = blockIdx.x * 256 + threadIdx.x;
  h0[i] = src[i];
  if (i < NBLK_SEQ) flags[i * 4] = 0;
}

// ---------------------------------------------------------------------------
extern "C" void kernel_launch(void* const* d_in, const int* in_sizes, int n_in,
                              void* d_out, int out_size, void* d_ws, size_t ws_size,
                              hipStream_t stream) {
  const int*   enc_ids = (const int*)d_in[0];
  const int*   dec_ids = (const int*)d_in[1];
  const float* emb     = (const float*)d_in[2];
  const float* Wx_enc  = (const float*)d_in[3];
  const float* Wh_enc  = (const float*)d_in[4];
  const float* b_enc   = (const float*)d_in[5];
  const float* Wx_dec  = (const float*)d_in[6];
  const float* Wh_dec  = (const float*)d_in[7];
  const float* b_dec   = (const float*)d_in[8];
  const float* dense_W = (const float*)d_in[9];
  const float* dense_b = (const float*)d_in[10];
  float* out = (float*)d_out;

  char* ws = (char*)d_ws;
  const size_t SZ_BUF = (size_t)4096 * 1024 * 2;   // 8 MiB
  ushort*   bufA   = (ushort*)(ws);
  ushort*   bufB   = (ushort*)(ws + SZ_BUF);
  ushort*   Wxt    = (ushort*)(ws + 2 * SZ_BUF);
  ushort*   Wht    = (ushort*)(ws + 3 * SZ_BUF);
  ushort*   dWt    = (ushort*)(ws + 4 * SZ_BUF);   // VOC*1024*2 B
  char*     p2     = ws + 4 * SZ_BUF + (size_t)VOC * 1024 * 2;
  ushort*   hstate = (ushort*)p2;                            // 64 KiB
  float*    cS     = (float*)(p2 + (size_t)32 * 1024 * 2);   // 128 KiB
  unsigned* flags  = (unsigned*)(p2 + (size_t)32 * 1024 * 2 + (size_t)32 * 1024 * 4);
  float*    Zpre   = out;   // 64 MB scratch inside d_out (dead until dense)

  transpose_cvt<<<dim3(VOC / 32, 1024 / 32), 256, 0, stream>>>(dense_W, dWt, 1024, VOC);

  // ---------------- encoder ----------------
  embed_kernel<<<4096, 256, 0, stream>>>(enc_ids, emb, bufA);
  ushort* cur = bufA; ushort* oth = bufB;
  for (int l = 0; l < 3; l++) {
    transpose_cvt<<<dim3(G4 / 32, 32), 256, 0, stream>>>(Wx_enc + (size_t)l * 1024 * G4, Wxt, 1024, G4);
    transpose_cvt<<<dim3(G4 / 32, 32), 256, 0, stream>>>(Wh_enc + (size_t)l * 1024 * G4, Wht, 1024, G4);
    gemm_bt<<<dim3(G4 / 128, 4096 / 128), 256, 0, stream>>>(cur, Wxt, b_enc + (size_t)l * G4,
                                                            Zpre, 4096, G4, 1024, 0);
    prep_zero<<<128, 256, 0, stream>>>(hstate, cS, flags);
    lstm_seq<<<NBLK_SEQ, 256, 0, stream>>>(Zpre, Wht, hstate, cS, oth, flags);
    ushort* tmp = cur; cur = oth; oth = tmp;
  }
  ushort* encY = cur;    // rows 127*32.. hold enc-final h

  // ---------------- decoder ----------------
  embed_kernel<<<4096, 256, 0, stream>>>(dec_ids, emb, oth);
  { ushort* tmp = cur; cur = oth; oth = tmp; }   // cur = dec input, oth = encY
  for (int l = 0; l < 3; l++) {
    transpose_cvt<<<dim3(G4 / 32, 32), 256, 0, stream>>>(Wx_dec + (size_t)l * 1024 * G4, Wxt, 1024, G4);
    transpose_cvt<<<dim3(G4 / 32, 32), 256, 0, stream>>>(Wh_dec + (size_t)l * 1024 * G4, Wht, 1024, G4);
    gemm_bt<<<dim3(G4 / 128, 4096 / 128), 256, 0, stream>>>(cur, Wxt, b_dec + (size_t)l * G4,
                                                            Zpre, 4096, G4, 1024, 0);
    const ushort* h0src = (l == 0 ? encY : cur) + (size_t)127 * 32 * HID;
    prep_copy<<<128, 256, 0, stream>>>(h0src, hstate, flags);   // c chains in cS
    lstm_seq<<<NBLK_SEQ, 256, 0, stream>>>(Zpre, Wht, hstate, cS, oth, flags);
    ushort* tmp = cur; cur = oth; oth = tmp;
  }

  // ---------------- dense head: logits[b][t][v] ----------------
  gemm_bt<<<dim3(VOC / 128, 4096 / 128), 256, 0, stream>>>(cur, dWt, dense_b, out,
                                                           4096, VOC, 1024, 1);
}

// Round 6
// 3639.288 us; speedup vs baseline: 4.4042x; 1.2227x over previous
//
#include <hip/hip_runtime.h>

// ---------------------------------------------------------------------------
// Seq2seq: 3-layer LSTM encoder + 3-layer LSTM decoder + dense vocab head
// B=32 T=128 V=32000 E=H=1024 L=3
// Encoder: single persistent wavefront kernel (192 blocks = 3 layers x 64
//   col-blocks, 512 thr = 8 waves: 4 gates x {x,h} operands). Layer l at
//   global wave-step w executes t = w-l; x for l>0 comes from layer l-1's y
//   via sys-scope L3 exchange. 130 wave-steps instead of 384 serial steps.
// Decoder: serial state chaining forbids wavefront -> per-layer persistent
//   kernel (64 blocks), Zpre batched GEMM per layer.
// Exchange: sys-scope (sc0 sc1) loads/stores bypass L1/L2, coherent at L3;
//   no fences so L2-resident data (Zpre, weights) stays warm.
// All large scratch lives in d_out's dead region (500 MB, dead until the
// dense head); d_ws usage matches the proven round-4 footprint.
// ---------------------------------------------------------------------------

typedef __bf16 bf8 __attribute__((ext_vector_type(8)));
typedef float  f4  __attribute__((ext_vector_type(4)));

#define TLEN  128
#define HID   1024
#define G4    4096
#define VOC   32000
#define NBLK_SEQ 64

__device__ __forceinline__ ushort f2bf(float f) {
  unsigned u = __builtin_bit_cast(unsigned, f);
  u += 0x7fffu + ((u >> 16) & 1u);          // round-to-nearest-even
  return (ushort)(u >> 16);
}
__device__ __forceinline__ float sigmoidf_(float x) { return 1.f / (1.f + expf(-x)); }

// ---- system-scope (bypass L1+L2, coherent at L3) memory ops ----------------
__device__ __forceinline__ void ld16_sys(uint4& v, const void* p) {
  asm volatile("global_load_dwordx4 %0, %1, off sc0 sc1" : "=v"(v) : "v"(p));
}
__device__ __forceinline__ unsigned ld4_sys(const void* p) {
  unsigned v;
  asm volatile("global_load_dword %0, %1, off sc0 sc1\n\ts_waitcnt vmcnt(0)"
               : "=v"(v) : "v"(p) : "memory");
  return v;
}
__device__ __forceinline__ void ld4_sys3(unsigned& a, unsigned& b, unsigned& c,
                                         const void* pa, const void* pb, const void* pc) {
  asm volatile("global_load_dword %0, %3, off sc0 sc1\n\t"
               "global_load_dword %1, %4, off sc0 sc1\n\t"
               "global_load_dword %2, %5, off sc0 sc1\n\t"
               "s_waitcnt vmcnt(0)"
               : "=&v"(a), "=&v"(b), "=&v"(c)
               : "v"(pa), "v"(pb), "v"(pc) : "memory");
}
__device__ __forceinline__ void st4_sys(void* p, unsigned v) {
  asm volatile("global_store_dword %0, %1, off sc0 sc1" :: "v"(p), "v"(v) : "memory");
}
__device__ __forceinline__ void st2_sys(void* p, unsigned v) {
  asm volatile("global_store_short %0, %1, off sc0 sc1" :: "v"(p), "v"(v) : "memory");
}
__device__ __forceinline__ void wait_vm0() {
  asm volatile("s_waitcnt vmcnt(0)" ::: "memory");
  __builtin_amdgcn_sched_barrier(0);
}

typedef const __attribute__((address_space(1))) void GvoidC;
typedef __attribute__((address_space(3))) void Lvoid;
__device__ __forceinline__ void g2l16(const void* g, void* l) {
  __builtin_amdgcn_global_load_lds((GvoidC*)g, (Lvoid*)l, 16, 0, 0);
}

// --- embedding gather: out[t*32+b][e] = bf16(emb[ids[b][t]][e]) -------------
__global__ __launch_bounds__(256) void embed_kernel(const int* __restrict__ ids,
    const float* __restrict__ emb, ushort* __restrict__ out) {
  int r = blockIdx.x;            // r = t*32 + b
  int b = r & 31, t = r >> 5;
  int id = ids[b * TLEN + t];
  const float4* src = (const float4*)(emb + (size_t)id * HID);
  float4 v = src[threadIdx.x];
  ushort4 o;
  o.x = f2bf(v.x); o.y = f2bf(v.y); o.z = f2bf(v.z); o.w = f2bf(v.w);
  *(ushort4*)(out + (size_t)r * HID + threadIdx.x * 4) = o;
}

// --- f32 [R][C] -> bf16 [C][R] tiled transpose ------------------------------
__global__ __launch_bounds__(256) void transpose_cvt(const float* __restrict__ W,
    ushort* __restrict__ Wt, int R, int C) {
  __shared__ float tile[32][33];
  int tx = threadIdx.x & 31, ty = threadIdx.x >> 5;   // ty 0..7
  int c0 = blockIdx.x * 32, r0 = blockIdx.y * 32;
  #pragma unroll
  for (int i = 0; i < 32; i += 8)
    tile[ty + i][tx] = W[(size_t)(r0 + ty + i) * C + c0 + tx];
  __syncthreads();
  #pragma unroll
  for (int i = 0; i < 32; i += 8)
    Wt[(size_t)(c0 + ty + i) * R + r0 + tx] = f2bf(tile[tx][ty + i]);
}

// --- bf16 MFMA GEMM: C[M][N] = A[M][K] @ Bt[N][K]^T + bias ------------------
__global__ __launch_bounds__(256) void gemm_bt(const ushort* __restrict__ A,
    const ushort* __restrict__ Bt, const float* __restrict__ bias,
    float* __restrict__ C, int M, int N, int K, int permute) {
  __shared__ __align__(16) ushort lA[128 * 32];
  __shared__ __align__(16) ushort lB[128 * 32];
  int tid = threadIdx.x;
  int lane = tid & 63, wave = tid >> 6;
  int m0 = blockIdx.y * 128, n0 = blockIdx.x * 128;
  int wr = wave >> 1, wc = wave & 1;
  f4 zero = {0.f, 0.f, 0.f, 0.f};
  f4 acc[4][4];
  #pragma unroll
  for (int i = 0; i < 4; i++)
    #pragma unroll
    for (int j = 0; j < 4; j++) acc[i][j] = zero;

  const ushort* Ag = A  + (size_t)(m0 + wave * 32 + (lane >> 2)) * K + (lane & 3) * 8;
  const ushort* Bg = Bt + (size_t)(n0 + wave * 32 + (lane >> 2)) * K + (lane & 3) * 8;
  ushort* lAp = lA + wave * 32 * 32;
  ushort* lBp = lB + wave * 32 * 32;

  for (int kt = 0; kt < K; kt += 32) {
    g2l16(Ag + kt, lAp);
    g2l16(Ag + (size_t)16 * K + kt, lAp + 16 * 32);
    g2l16(Bg + kt, lBp);
    g2l16(Bg + (size_t)16 * K + kt, lBp + 16 * 32);
    __syncthreads();
    bf8 aF[4], bF[4];
    #pragma unroll
    for (int i = 0; i < 4; i++)
      aF[i] = *(const bf8*)(lA + (wr * 64 + i * 16 + (lane & 15)) * 32 + (lane >> 4) * 8);
    #pragma unroll
    for (int j = 0; j < 4; j++)
      bF[j] = *(const bf8*)(lB + (wc * 64 + j * 16 + (lane & 15)) * 32 + (lane >> 4) * 8);
    #pragma unroll
    for (int i = 0; i < 4; i++)
      #pragma unroll
      for (int j = 0; j < 4; j++)
        acc[i][j] = __builtin_amdgcn_mfma_f32_16x16x32_bf16(aF[i], bF[j], acc[i][j], 0, 0, 0);
    __syncthreads();
  }
  #pragma unroll
  for (int i = 0; i < 4; i++) {
    #pragma unroll
    for (int j = 0; j < 4; j++) {
      int col = n0 + wc * 64 + j * 16 + (lane & 15);
      float bv = bias ? bias[col] : 0.f;
      #pragma unroll
      for (int v = 0; v < 4; v++) {
        int row = m0 + wr * 64 + i * 16 + (lane >> 4) * 4 + v;
        int orow = permute ? ((row & 31) * TLEN + (row >> 5)) : row;
        C[(size_t)orow * N + col] = acc[i][j][v] + bv;
      }
    }
  }
}

// --- encoder wavefront: all 3 layers in one persistent kernel ---------------
// 192 blocks (l = bx>>6, jg = bx&63), 512 threads = 8 waves (gate g = wave&3,
// operand op = wave>>2 : 0->h@Wh, 1->x@Wx). Layer 0 skips x-MFMA (Zpre GEMM).
// Global lockstep: every block posts flag=w+1 each wave-step; wave0 polls all.
__global__ __launch_bounds__(512, 1) void enc_wave(
    const float*  __restrict__ Zpre,   // [128][32][4096] layer-0 pregates (incl bias)
    const ushort* __restrict__ WhT,    // 3 x [4096][1024] (stride 4096*1024)
    const ushort* __restrict__ WxT,    // 2 x [4096][1024] (layers 1,2 -> idx l-1)
    const float*  __restrict__ bE,     // [3][4096]
    ushort*       __restrict__ hxe,    // [3][2][32][1024] bf16 exchange (pre-zeroed)
    float*        __restrict__ cSe,    // [3][32][1024] c state (pre-zeroed)
    ushort*       __restrict__ hS,     // [3][32][1024] final h out
    unsigned*     __restrict__ flags)  // 192 flags, stride 4 dwords
{
  const int bx = blockIdx.x;
  const int l = bx >> 6, jg = bx & 63;
  const int j0 = jg * 16;
  const int tid = threadIdx.x;
  const int lane = tid & 63, wave = tid >> 6;
  const int g = wave & 3, op = wave >> 2;
  const int rr = tid >> 4, jj = tid & 15;           // combine: row 0..31, col 0..15

  __shared__ __align__(16) char hLDS[65536];
  __shared__ __align__(16) char xLDS[65536];
  __shared__ float zbuf[8][32][17];

  float cc = cSe[(size_t)l * 32768 + rr * HID + j0 + jj];
  float bias4[4];
  #pragma unroll
  for (int gg = 0; gg < 4; gg++)
    bias4[gg] = bE[l * G4 + gg * HID + j0 + jj];

  const bool mfma_on = (l > 0) || (op == 0);
  bf8 bw[32];
  if (mfma_on) {
    const ushort* Wb = op ? (WxT + (size_t)(l - 1) * G4 * HID)
                          : (WhT + (size_t)l * G4 * HID);
    const ushort* Bp = Wb + (size_t)(g * HID + j0 + (lane & 15)) * HID + (lane >> 4) * 8;
    #pragma unroll
    for (int kk = 0; kk < 32; kk++) bw[kk] = *(const bf8*)(Bp + kk * 32);
  }

  const int r0 = lane & 15, r1 = r0 + 16;
  const int klb = (lane >> 4) * 16;
  const int swz = (r0 & 7) << 4;

  float zv4[4], zn4[4];
  if (l == 0) {
    #pragma unroll
    for (int gg = 0; gg < 4; gg++)
      zv4[gg] = Zpre[(size_t)rr * G4 + gg * HID + j0 + jj];
  }

  for (int w = 0; w < 130; ++w) {
    if (w > 0) {
      if (wave == 0) {
        for (;;) {
          unsigned a, b, c;
          ld4_sys3(a, b, c, flags + lane * 4, flags + (64 + lane) * 4,
                   flags + (128 + lane) * 4);
          if (!__ballot(a < (unsigned)w || b < (unsigned)w || c < (unsigned)w)) break;
          __builtin_amdgcn_s_sleep(1);
        }
      }
      __syncthreads();
    }
    const int t = w - l;
    if (t >= 0 && t < TLEN) {
      // ---- stage h_{t-1} (and x = below's y_t for l>0) into LDS ----
      const char* hsrc = (const char*)(hxe + ((size_t)l * 2 + ((t - 1) & 1)) * 32768);
      uint4 hreg[8], xreg[8];
      #pragma unroll
      for (int it = 0; it < 8; it++)
        ld16_sys(hreg[it], hsrc + (size_t)(tid + it * 512) * 16);
      if (l > 0) {
        const char* xsrc = (const char*)(hxe + ((size_t)(l - 1) * 2 + (t & 1)) * 32768);
        #pragma unroll
        for (int it = 0; it < 8; it++)
          ld16_sys(xreg[it], xsrc + (size_t)(tid + it * 512) * 16);
      }
      wait_vm0();
      #pragma unroll
      for (int it = 0; it < 8; it++) {
        int c = tid + it * 512;
        int row = c >> 7;
        int o = (c & 127) * 16;
        *(uint4*)(hLDS + row * 2048 + (o ^ ((row & 7) << 4))) = hreg[it];
      }
      if (l > 0) {
        #pragma unroll
        for (int it = 0; it < 8; it++) {
          int c = tid + it * 512;
          int row = c >> 7;
          int o = (c & 127) * 16;
          *(uint4*)(xLDS + row * 2048 + (o ^ ((row & 7) << 4))) = xreg[it];
        }
      }
      __syncthreads();

      if (l == 0 && t + 1 < TLEN) {
        const float* Ztn = Zpre + (size_t)(t + 1) * 32 * G4;
        #pragma unroll
        for (int gg = 0; gg < 4; gg++)
          zn4[gg] = Ztn[(size_t)rr * G4 + gg * HID + j0 + jj];
      }

      if (mfma_on) {
        const char* S = op ? xLDS : hLDS;
        f4 acc0 = {0.f, 0.f, 0.f, 0.f}, acc1 = {0.f, 0.f, 0.f, 0.f};
        #pragma unroll
        for (int kk = 0; kk < 32; kk++) {
          int cb = kk * 64 + klb;
          bf8 a0 = *(const bf8*)(S + r0 * 2048 + (cb ^ swz));
          bf8 a1 = *(const bf8*)(S + r1 * 2048 + (cb ^ swz));
          acc0 = __builtin_amdgcn_mfma_f32_16x16x32_bf16(a0, bw[kk], acc0, 0, 0, 0);
          acc1 = __builtin_amdgcn_mfma_f32_16x16x32_bf16(a1, bw[kk], acc1, 0, 0, 0);
        }
        #pragma unroll
        for (int v = 0; v < 4; v++) {
          zbuf[wave][(lane >> 4) * 4 + v][lane & 15]      = acc0[v];
          zbuf[wave][16 + (lane >> 4) * 4 + v][lane & 15] = acc1[v];
        }
      }
      __syncthreads();

      // ---- combine + gates (thread owns row rr, col j0+jj) ----
      float z[4];
      #pragma unroll
      for (int gg = 0; gg < 4; gg++) z[gg] = zbuf[gg][rr][jj];
      if (l > 0) {
        #pragma unroll
        for (int gg = 0; gg < 4; gg++) z[gg] += zbuf[4 + gg][rr][jj] + bias4[gg];
      } else {
        #pragma unroll
        for (int gg = 0; gg < 4; gg++) z[gg] += zv4[gg];
        #pragma unroll
        for (int gg = 0; gg < 4; gg++) zv4[gg] = zn4[gg];
      }
      float ig = sigmoidf_(z[0]), fg = sigmoidf_(z[1]);
      float gv = tanhf(z[2]),     og = sigmoidf_(z[3]);
      cc = fg * cc + ig * gv;
      float hv = og * tanhf(cc);
      ushort hb = f2bf(hv);
      st2_sys(hxe + ((size_t)l * 2 + (t & 1)) * 32768 + rr * HID + j0 + jj, (unsigned)hb);
      if (t == TLEN - 1) {
        hS [(size_t)l * 32768 + rr * HID + j0 + jj] = hb;
        cSe[(size_t)l * 32768 + rr * HID + j0 + jj] = cc;
      }
      wait_vm0();
    }
    __syncthreads();
    if (tid == 0) st4_sys(flags + bx * 4, (unsigned)(w + 1));
  }
}

// --- decoder per-layer persistent recurrence --------------------------------
__global__ __launch_bounds__(256, 1) void lstm_seq(
    const float*  __restrict__ Zpre,   // [TLEN][32][4096] (incl bias)
    const ushort* __restrict__ Wht,    // [4096][1024]
    const ushort* __restrict__ h0,     // [32][1024] initial h
    float*        __restrict__ cS,     // [32][1024] c state in/out
    ushort*       __restrict__ yout,   // [TLEN][32][1024]
    unsigned*     __restrict__ flags)  // 64 flags, stride 4 dwords
{
  const int jg = blockIdx.x;
  const int j0 = jg * 16;
  const int tid = threadIdx.x;
  const int lane = tid & 63, wave = tid >> 6;
  const int rr = tid >> 3, cp = tid & 7;

  __shared__ __align__(16) char hLDS[65536];
  __shared__ float zbuf[4][32][17];

  float2 cc = *(const float2*)(cS + (size_t)rr * HID + j0 + 2 * cp);

  const ushort* Bp = Wht + (size_t)(wave * HID + j0 + (lane & 15)) * HID + (lane >> 4) * 8;
  bf8 bw[32];
  #pragma unroll
  for (int kk = 0; kk < 32; kk++)
    bw[kk] = *(const bf8*)(Bp + kk * 32);

  const int r0 = lane & 15, r1 = r0 + 16;
  const int klb = (lane >> 4) * 16;
  const int swz = (r0 & 7) << 4;

  float2 zv[4], zn[4];
  #pragma unroll
  for (int g = 0; g < 4; g++)
    zv[g] = *(const float2*)(Zpre + (size_t)rr * G4 + g * HID + j0 + 2 * cp);

  for (int t = 0; t < TLEN; ++t) {
    if (t > 0) {
      if (wave == 0) {
        const unsigned* fp = flags + lane * 4;
        while (__ballot(ld4_sys(fp) < (unsigned)t)) __builtin_amdgcn_s_sleep(1);
      }
      __syncthreads();
    }
    const char* hsrc = (t == 0) ? (const char*)h0
                                : (const char*)(yout + (size_t)(t - 1) * 32 * HID);
    uint4 hreg[16];
    #pragma unroll
    for (int it = 0; it < 16; it++)
      ld16_sys(hreg[it], hsrc + (size_t)(tid + it * 256) * 16);
    wait_vm0();
    #pragma unroll
    for (int it = 0; it < 16; it++) {
      int c = tid + it * 256;
      int row = c >> 7;
      int o = (c & 127) * 16;
      *(uint4*)(hLDS + row * 2048 + (o ^ ((row & 7) << 4))) = hreg[it];
    }
    __syncthreads();

    if (t + 1 < TLEN) {
      const float* Ztn = Zpre + (size_t)(t + 1) * 32 * G4;
      #pragma unroll
      for (int g = 0; g < 4; g++)
        zn[g] = *(const float2*)(Ztn + (size_t)rr * G4 + g * HID + j0 + 2 * cp);
    }

    f4 acc0 = {0.f, 0.f, 0.f, 0.f}, acc1 = {0.f, 0.f, 0.f, 0.f};
    #pragma unroll
    for (int kk = 0; kk < 32; kk++) {
      int cb = kk * 64 + klb;
      bf8 a0 = *(const bf8*)(hLDS + r0 * 2048 + (cb ^ swz));
      bf8 a1 = *(const bf8*)(hLDS + r1 * 2048 + (cb ^ swz));
      acc0 = __builtin_amdgcn_mfma_f32_16x16x32_bf16(a0, bw[kk], acc0, 0, 0, 0);
      acc1 = __builtin_amdgcn_mfma_f32_16x16x32_bf16(a1, bw[kk], acc1, 0, 0, 0);
    }
    #pragma unroll
    for (int v = 0; v < 4; v++) {
      zbuf[wave][(lane >> 4) * 4 + v][lane & 15]      = acc0[v];
      zbuf[wave][16 + (lane >> 4) * 4 + v][lane & 15] = acc1[v];
    }
    __syncthreads();

    float zi0 = zv[0].x + zbuf[0][rr][2 * cp],     zi1 = zv[0].y + zbuf[0][rr][2 * cp + 1];
    float zf0 = zv[1].x + zbuf[1][rr][2 * cp],     zf1 = zv[1].y + zbuf[1][rr][2 * cp + 1];
    float zg0 = zv[2].x + zbuf[2][rr][2 * cp],     zg1 = zv[2].y + zbuf[2][rr][2 * cp + 1];
    float zo0 = zv[3].x + zbuf[3][rr][2 * cp],     zo1 = zv[3].y + zbuf[3][rr][2 * cp + 1];
    cc.x = sigmoidf_(zf0) * cc.x + sigmoidf_(zi0) * tanhf(zg0);
    cc.y = sigmoidf_(zf1) * cc.y + sigmoidf_(zi1) * tanhf(zg1);
    float hv0 = sigmoidf_(zo0) * tanhf(cc.x);
    float hv1 = sigmoidf_(zo1) * tanhf(cc.y);
    unsigned packed = (unsigned)f2bf(hv0) | ((unsigned)f2bf(hv1) << 16);
    st4_sys((char*)(yout + (size_t)t * 32 * HID) + ((size_t)rr * HID + j0 + 2 * cp) * 2,
            packed);
    #pragma unroll
    for (int g = 0; g < 4; g++) zv[g] = zn[g];

    wait_vm0();
    __syncthreads();
    if (tid == 0) st4_sys(flags + jg * 4, (unsigned)(t + 1));
  }
  *(float2*)(cS + (size_t)rr * HID + j0 + 2 * cp) = cc;
}

// --- prep kernels -----------------------------------------------------------
__global__ __launch_bounds__(256) void prep_enc(ushort* hxe, float* cSe,
                                                unsigned* flags) {
  int i = blockIdx.x * 256 + threadIdx.x;      // 768 blocks * 256 = 196608
  hxe[i] = 0;
  if (i < 98304) cSe[i] = 0.f;
  if (i < 192)   flags[i * 4] = 0;
}
__global__ __launch_bounds__(256) void prep_dec0(const ushort* __restrict__ hS2,
                                                 const float* __restrict__ cSe2,
                                                 ushort* h0, float* cS,
                                                 unsigned* flags) {
  int i = blockIdx.x * 256 + threadIdx.x;      // 128 blocks * 256 = 32768
  h0[i] = hS2[i];
  cS[i] = cSe2[i];
  if (i < NBLK_SEQ) flags[i * 4] = 0;
}
__global__ __launch_bounds__(256) void prep_copy(const ushort* __restrict__ src,
                                                 ushort* __restrict__ h0,
                                                 unsigned* __restrict__ flags) {
  int i = blockIdx.x * 256 + threadIdx.x;
  h0[i] = src[i];
  if (i < NBLK_SEQ) flags[i * 4] = 0;
}

// ---------------------------------------------------------------------------
extern "C" void kernel_launch(void* const* d_in, const int* in_sizes, int n_in,
                              void* d_out, int out_size, void* d_ws, size_t ws_size,
                              hipStream_t stream) {
  const int*   enc_ids = (const int*)d_in[0];
  const int*   dec_ids = (const int*)d_in[1];
  const float* emb     = (const float*)d_in[2];
  const float* Wx_enc  = (const float*)d_in[3];
  const float* Wh_enc  = (const float*)d_in[4];
  const float* b_enc   = (const float*)d_in[5];
  const float* Wx_dec  = (const float*)d_in[6];
  const float* Wh_dec  = (const float*)d_in[7];
  const float* b_dec   = (const float*)d_in[8];
  const float* dense_W = (const float*)d_in[9];
  const float* dense_b = (const float*)d_in[10];
  float* out = (float*)d_out;

  // ---- d_ws layout (identical footprint to the proven round-4 run) ----
  char* ws = (char*)d_ws;
  const size_t SZ_BUF = (size_t)4096 * 1024 * 2;   // 8 MiB
  ushort*   bufA   = (ushort*)(ws);
  ushort*   bufB   = (ushort*)(ws + SZ_BUF);
  ushort*   Wxt    = (ushort*)(ws + 2 * SZ_BUF);
  ushort*   Wht    = (ushort*)(ws + 3 * SZ_BUF);
  ushort*   dWt    = (ushort*)(ws + 4 * SZ_BUF);   // VOC*1024*2 B
  char*     p2     = ws + 4 * SZ_BUF + (size_t)VOC * 1024 * 2;
  ushort*   hstate = (ushort*)p2;                            // 64 KiB
  float*    cS     = (float*)(p2 + (size_t)32 * 1024 * 2);   // 128 KiB
  unsigned* flags  = (unsigned*)(p2 + (size_t)32 * 1024 * 2 + (size_t)32 * 1024 * 4);

  // ---- d_out dead-region scratch (500 MB buffer, dense head writes last) --
  char* ob = (char*)d_out;
  float*    Zpre   = out;                                        // [0, 64 MiB)
  ushort*   WhTe   = (ushort*)(ob + (size_t)64  * 1024 * 1024);  // 3 x 8 MiB
  ushort*   WxTe   = (ushort*)(ob + (size_t)88  * 1024 * 1024);  // 2 x 8 MiB
  char*     st     = ob + (size_t)112 * 1024 * 1024;
  ushort*   hxe    = (ushort*)st;                                // 384 KiB
  float*    cSe    = (float*)(st + 393216);                      // 384 KiB
  ushort*   hS     = (ushort*)(st + 786432);                     // 192 KiB
  unsigned* flags2 = (unsigned*)(st + 983040);                   // 3 KiB
  const size_t WSTRIDE = (size_t)G4 * HID;                       // elements

  transpose_cvt<<<dim3(VOC / 32, 1024 / 32), 256, 0, stream>>>(dense_W, dWt, 1024, VOC);

  // ---------------- encoder ----------------
  embed_kernel<<<4096, 256, 0, stream>>>(enc_ids, emb, bufA);
  transpose_cvt<<<dim3(G4 / 32, 32), 256, 0, stream>>>(Wx_enc, Wxt, 1024, G4);
  gemm_bt<<<dim3(G4 / 128, 4096 / 128), 256, 0, stream>>>(bufA, Wxt, b_enc,
                                                          Zpre, 4096, G4, 1024, 0);
  for (int l = 0; l < 3; l++)
    transpose_cvt<<<dim3(G4 / 32, 32), 256, 0, stream>>>(Wh_enc + (size_t)l * 1024 * G4,
                                                         WhTe + l * WSTRIDE, 1024, G4);
  for (int l = 1; l < 3; l++)
    transpose_cvt<<<dim3(G4 / 32, 32), 256, 0, stream>>>(Wx_enc + (size_t)l * 1024 * G4,
                                                         WxTe + (l - 1) * WSTRIDE, 1024, G4);
  prep_enc<<<768, 256, 0, stream>>>(hxe, cSe, flags2);
  enc_wave<<<192, 512, 0, stream>>>(Zpre, WhTe, WxTe, b_enc, hxe, cSe, hS, flags2);

  // ---------------- decoder (serial chaining -> per-layer) ----------------
  embed_kernel<<<4096, 256, 0, stream>>>(dec_ids, emb, bufA);
  ushort* cur = bufA; ushort* oth = bufB;
  for (int l = 0; l < 3; l++) {
    transpose_cvt<<<dim3(G4 / 32, 32), 256, 0, stream>>>(Wx_dec + (size_t)l * 1024 * G4, Wxt, 1024, G4);
    transpose_cvt<<<dim3(G4 / 32, 32), 256, 0, stream>>>(Wh_dec + (size_t)l * 1024 * G4, Wht, 1024, G4);
    gemm_bt<<<dim3(G4 / 128, 4096 / 128), 256, 0, stream>>>(cur, Wxt, b_dec + (size_t)l * G4,
                                                            Zpre, 4096, G4, 1024, 0);
    if (l == 0) {
      prep_dec0<<<128, 256, 0, stream>>>(hS + 2 * 32768, cSe + 2 * 32768, hstate, cS, flags);
    } else {
      const ushort* h0src = cur + (size_t)127 * 32 * HID;
      prep_copy<<<128, 256, 0, stream>>>(h0src, hstate, flags);  // c chains in cS
    }
    lstm_seq<<<NBLK_SEQ, 256, 0, stream>>>(Zpre, Wht, hstate, cS, oth, flags);
    ushort* tmp = cur; cur = oth; oth = tmp;
  }

  // ---------------- dense head: logits[b][t][v] ----------------
  gemm_bt<<<dim3(VOC / 128, 4096 / 128), 256, 0, stream>>>(cur, dWt, dense_b, out,
                                                           4096, VOC, 1024, 1);
}

// Round 8
// 3600.504 us; speedup vs baseline: 4.4517x; 1.0108x over previous
//
#include <hip/hip_runtime.h>

// ---------------------------------------------------------------------------
// Seq2seq: 3-layer LSTM encoder + 3-layer LSTM decoder + dense vocab head
// B=32 T=128 V=32000 E=H=1024 L=3
// Encoder: persistent wavefront kernel (192 blocks = 3 layers x 64 col-blocks,
//   8 waves: 4 gates x {x,h}). Layer l at wave-step w runs t=w-l; 130 steps.
// Decoder: serial layer chaining -> per-layer persistent kernel (64 blocks,
//   4 waves). Waves are K-split (each wave K-slice 256, all 4 gates) ->
//   4x less LDS A-read traffic; padded fp32 partial buffer + combine-sum.
// Exchange: sys-scope (sc0 sc1) ld/st bypass L1/L2, coherent at L3; no fences
//   so L2-resident data (Zpre, weights) stays warm.
// GEMMs: XCD-aware bijective block swizzle (all grids %8 == 0).
// ---------------------------------------------------------------------------

typedef __bf16 bf8 __attribute__((ext_vector_type(8)));
typedef float  f4  __attribute__((ext_vector_type(4)));

#define TLEN  128
#define HID   1024
#define G4    4096
#define VOC   32000
#define NBLK_SEQ 64

__device__ __forceinline__ ushort f2bf(float f) {
  unsigned u = __builtin_bit_cast(unsigned, f);
  u += 0x7fffu + ((u >> 16) & 1u);          // round-to-nearest-even
  return (ushort)(u >> 16);
}
__device__ __forceinline__ float sigmoidf_(float x) { return 1.f / (1.f + expf(-x)); }

// ---- system-scope (bypass L1+L2, coherent at L3) memory ops ----------------
__device__ __forceinline__ void ld16_sys(uint4& v, const void* p) {
  asm volatile("global_load_dwordx4 %0, %1, off sc0 sc1" : "=v"(v) : "v"(p));
}
__device__ __forceinline__ unsigned ld4_sys(const void* p) {
  unsigned v;
  asm volatile("global_load_dword %0, %1, off sc0 sc1\n\ts_waitcnt vmcnt(0)"
               : "=v"(v) : "v"(p) : "memory");
  return v;
}
__device__ __forceinline__ void ld4_sys3(unsigned& a, unsigned& b, unsigned& c,
                                         const void* pa, const void* pb, const void* pc) {
  asm volatile("global_load_dword %0, %3, off sc0 sc1\n\t"
               "global_load_dword %1, %4, off sc0 sc1\n\t"
               "global_load_dword %2, %5, off sc0 sc1\n\t"
               "s_waitcnt vmcnt(0)"
               : "=&v"(a), "=&v"(b), "=&v"(c)
               : "v"(pa), "v"(pb), "v"(pc) : "memory");
}
__device__ __forceinline__ void st4_sys(void* p, unsigned v) {
  asm volatile("global_store_dword %0, %1, off sc0 sc1" :: "v"(p), "v"(v) : "memory");
}
__device__ __forceinline__ void wait_vm0() {
  asm volatile("s_waitcnt vmcnt(0)" ::: "memory");
  __builtin_amdgcn_sched_barrier(0);
}

typedef const __attribute__((address_space(1))) void GvoidC;
typedef __attribute__((address_space(3))) void Lvoid;
__device__ __forceinline__ void g2l16(const void* g, void* l) {
  __builtin_amdgcn_global_load_lds((GvoidC*)g, (Lvoid*)l, 16, 0, 0);
}

// --- embedding gather: out[t*32+b][e] = bf16(emb[ids[b][t]][e]) -------------
__global__ __launch_bounds__(256) void embed_kernel(const int* __restrict__ ids,
    const float* __restrict__ emb, ushort* __restrict__ out) {
  int r = blockIdx.x;            // r = t*32 + b
  int b = r & 31, t = r >> 5;
  int id = ids[b * TLEN + t];
  const float4* src = (const float4*)(emb + (size_t)id * HID);
  float4 v = src[threadIdx.x];
  ushort4 o;
  o.x = f2bf(v.x); o.y = f2bf(v.y); o.z = f2bf(v.z); o.w = f2bf(v.w);
  *(ushort4*)(out + (size_t)r * HID + threadIdx.x * 4) = o;
}

// --- f32 [R][C] -> bf16 [C][R] tiled transpose ------------------------------
__global__ __launch_bounds__(256) void transpose_cvt(const float* __restrict__ W,
    ushort* __restrict__ Wt, int R, int C) {
  __shared__ float tile[32][33];
  int tx = threadIdx.x & 31, ty = threadIdx.x >> 5;   // ty 0..7
  int c0 = blockIdx.x * 32, r0 = blockIdx.y * 32;
  #pragma unroll
  for (int i = 0; i < 32; i += 8)
    tile[ty + i][tx] = W[(size_t)(r0 + ty + i) * C + c0 + tx];
  __syncthreads();
  #pragma unroll
  for (int i = 0; i < 32; i += 8)
    Wt[(size_t)(c0 + ty + i) * R + r0 + tx] = f2bf(tile[tx][ty + i]);
}

// --- bf16 MFMA GEMM: C[M][N] = A[M][K] @ Bt[N][K]^T + bias ------------------
// 128x128 tile; XCD-aware bijective swizzle (requires nwg % 8 == 0; all our
// grids satisfy this: 1024, 1024, 8000).
__global__ __launch_bounds__(256) void gemm_bt(const ushort* __restrict__ A,
    const ushort* __restrict__ Bt, const float* __restrict__ bias,
    float* __restrict__ C, int M, int N, int K, int permute) {
  __shared__ __align__(16) ushort lA[128 * 32];
  __shared__ __align__(16) ushort lB[128 * 32];
  int tid = threadIdx.x;
  int lane = tid & 63, wave = tid >> 6;
  int nwg = gridDim.x * gridDim.y;
  int wg  = blockIdx.y * gridDim.x + blockIdx.x;
  int q   = nwg >> 3;
  int swg = (wg & 7) * q + (wg >> 3);          // bijective when nwg % 8 == 0
  int m0 = (swg / gridDim.x) * 128, n0 = (swg % gridDim.x) * 128;
  int wr = wave >> 1, wc = wave & 1;
  f4 zero = {0.f, 0.f, 0.f, 0.f};
  f4 acc[4][4];
  #pragma unroll
  for (int i = 0; i < 4; i++)
    #pragma unroll
    for (int j = 0; j < 4; j++) acc[i][j] = zero;

  const ushort* Ag = A  + (size_t)(m0 + wave * 32 + (lane >> 2)) * K + (lane & 3) * 8;
  const ushort* Bg = Bt + (size_t)(n0 + wave * 32 + (lane >> 2)) * K + (lane & 3) * 8;
  ushort* lAp = lA + wave * 32 * 32;
  ushort* lBp = lB + wave * 32 * 32;

  for (int kt = 0; kt < K; kt += 32) {
    g2l16(Ag + kt, lAp);
    g2l16(Ag + (size_t)16 * K + kt, lAp + 16 * 32);
    g2l16(Bg + kt, lBp);
    g2l16(Bg + (size_t)16 * K + kt, lBp + 16 * 32);
    __syncthreads();
    bf8 aF[4], bF[4];
    #pragma unroll
    for (int i = 0; i < 4; i++)
      aF[i] = *(const bf8*)(lA + (wr * 64 + i * 16 + (lane & 15)) * 32 + (lane >> 4) * 8);
    #pragma unroll
    for (int j = 0; j < 4; j++)
      bF[j] = *(const bf8*)(lB + (wc * 64 + j * 16 + (lane & 15)) * 32 + (lane >> 4) * 8);
    #pragma unroll
    for (int i = 0; i < 4; i++)
      #pragma unroll
      for (int j = 0; j < 4; j++)
        acc[i][j] = __builtin_amdgcn_mfma_f32_16x16x32_bf16(aF[i], bF[j], acc[i][j], 0, 0, 0);
    __syncthreads();
  }
  #pragma unroll
  for (int i = 0; i < 4; i++) {
    #pragma unroll
    for (int j = 0; j < 4; j++) {
      int col = n0 + wc * 64 + j * 16 + (lane & 15);
      float bv = bias ? bias[col] : 0.f;
      #pragma unroll
      for (int v = 0; v < 4; v++) {
        int row = m0 + wr * 64 + i * 16 + (lane >> 4) * 4 + v;
        int orow = permute ? ((row & 31) * TLEN + (row >> 5)) : row;
        C[(size_t)orow * N + col] = acc[i][j][v] + bv;
      }
    }
  }
}

// --- encoder wavefront: all 3 layers in one persistent kernel ---------------
__global__ __launch_bounds__(512, 1) void enc_wave(
    const float*  __restrict__ Zpre,   // [128][32][4096] layer-0 pregates (incl bias)
    const ushort* __restrict__ WhT,    // 3 x [4096][1024]
    const ushort* __restrict__ WxT,    // 2 x [4096][1024] (layers 1,2 -> idx l-1)
    const float*  __restrict__ bE,     // [3][4096]
    ushort*       __restrict__ hxe,    // [3][2][32][1024] bf16 exchange (pre-zeroed)
    float*        __restrict__ cSe,    // [3][32][1024] c state (pre-zeroed)
    ushort*       __restrict__ hS,     // [3][32][1024] final h out
    unsigned*     __restrict__ flags)  // 192 flags, stride 4 dwords
{
  const int bx = blockIdx.x;
  const int l = bx >> 6, jg = bx & 63;
  const int j0 = jg * 16;
  const int tid = threadIdx.x;
  const int lane = tid & 63, wave = tid >> 6;
  const int g = wave & 3, op = wave >> 2;
  const int rr = tid >> 4, jj = tid & 15;           // combine: row 0..31, col 0..15

  __shared__ __align__(16) char hLDS[65536];
  __shared__ __align__(16) char xLDS[65536];
  __shared__ float zbuf[8][32][17];

  float cc = cSe[(size_t)l * 32768 + rr * HID + j0 + jj];
  float bias4[4];
  #pragma unroll
  for (int gg = 0; gg < 4; gg++)
    bias4[gg] = bE[l * G4 + gg * HID + j0 + jj];

  const bool mfma_on = (l > 0) || (op == 0);
  bf8 bw[32];
  if (mfma_on) {
    const ushort* Wb = op ? (WxT + (size_t)(l - 1) * G4 * HID)
                          : (WhT + (size_t)l * G4 * HID);
    const ushort* Bp = Wb + (size_t)(g * HID + j0 + (lane & 15)) * HID + (lane >> 4) * 8;
    #pragma unroll
    for (int kk = 0; kk < 32; kk++) bw[kk] = *(const bf8*)(Bp + kk * 32);
  }

  const int r0 = lane & 15, r1 = r0 + 16;
  const int klb = (lane >> 4) * 16;
  const int swz = (r0 & 7) << 4;

  float zv4[4], zn4[4];
  if (l == 0) {
    #pragma unroll
    for (int gg = 0; gg < 4; gg++)
      zv4[gg] = Zpre[(size_t)rr * G4 + gg * HID + j0 + jj];
  }

  for (int w = 0; w < 130; ++w) {
    if (w > 0) {
      if (wave == 0) {
        for (;;) {
          unsigned a, b, c;
          ld4_sys3(a, b, c, flags + lane * 4, flags + (64 + lane) * 4,
                   flags + (128 + lane) * 4);
          if (!__ballot(a < (unsigned)w || b < (unsigned)w || c < (unsigned)w)) break;
          __builtin_amdgcn_s_sleep(1);
        }
      }
      __syncthreads();
    }
    const int t = w - l;
    if (t >= 0 && t < TLEN) {
      // ---- stage h_{t-1} (and x = below's y_t for l>0) into LDS ----
      const char* hsrc = (const char*)(hxe + ((size_t)l * 2 + ((t - 1) & 1)) * 32768);
      uint4 hreg[8], xreg[8];
      #pragma unroll
      for (int it = 0; it < 8; it++)
        ld16_sys(hreg[it], hsrc + (size_t)(tid + it * 512) * 16);
      if (l > 0) {
        const char* xsrc = (const char*)(hxe + ((size_t)(l - 1) * 2 + (t & 1)) * 32768);
        #pragma unroll
        for (int it = 0; it < 8; it++)
          ld16_sys(xreg[it], xsrc + (size_t)(tid + it * 512) * 16);
      }
      wait_vm0();
      #pragma unroll
      for (int it = 0; it < 8; it++) {
        int c = tid + it * 512;
        int row = c >> 7;
        int o = (c & 127) * 16;
        *(uint4*)(hLDS + row * 2048 + (o ^ ((row & 7) << 4))) = hreg[it];
      }
      if (l > 0) {
        #pragma unroll
        for (int it = 0; it < 8; it++) {
          int c = tid + it * 512;
          int row = c >> 7;
          int o = (c & 127) * 16;
          *(uint4*)(xLDS + row * 2048 + (o ^ ((row & 7) << 4))) = xreg[it];
        }
      }
      __syncthreads();

      if (l == 0 && t + 1 < TLEN) {
        const float* Ztn = Zpre + (size_t)(t + 1) * 32 * G4;
        #pragma unroll
        for (int gg = 0; gg < 4; gg++)
          zn4[gg] = Ztn[(size_t)rr * G4 + gg * HID + j0 + jj];
      }

      if (mfma_on) {
        const char* S = op ? xLDS : hLDS;
        f4 acc0 = {0.f, 0.f, 0.f, 0.f}, acc1 = {0.f, 0.f, 0.f, 0.f};
        #pragma unroll
        for (int kk = 0; kk < 32; kk++) {
          int cb = kk * 64 + klb;
          bf8 a0 = *(const bf8*)(S + r0 * 2048 + (cb ^ swz));
          bf8 a1 = *(const bf8*)(S + r1 * 2048 + (cb ^ swz));
          acc0 = __builtin_amdgcn_mfma_f32_16x16x32_bf16(a0, bw[kk], acc0, 0, 0, 0);
          acc1 = __builtin_amdgcn_mfma_f32_16x16x32_bf16(a1, bw[kk], acc1, 0, 0, 0);
        }
        #pragma unroll
        for (int v = 0; v < 4; v++) {
          zbuf[wave][(lane >> 4) * 4 + v][lane & 15]      = acc0[v];
          zbuf[wave][16 + (lane >> 4) * 4 + v][lane & 15] = acc1[v];
        }
      }
      __syncthreads();

      // ---- combine + gates (thread owns row rr, col j0+jj) ----
      float z[4];
      #pragma unroll
      for (int gg = 0; gg < 4; gg++) z[gg] = zbuf[gg][rr][jj];
      if (l > 0) {
        #pragma unroll
        for (int gg = 0; gg < 4; gg++) z[gg] += zbuf[4 + gg][rr][jj] + bias4[gg];
      } else {
        #pragma unroll
        for (int gg = 0; gg < 4; gg++) z[gg] += zv4[gg];
        #pragma unroll
        for (int gg = 0; gg < 4; gg++) zv4[gg] = zn4[gg];
      }
      float ig = sigmoidf_(z[0]), fg = sigmoidf_(z[1]);
      float gv = tanhf(z[2]),     og = sigmoidf_(z[3]);
      cc = fg * cc + ig * gv;
      float hv = og * tanhf(cc);
      ushort hb = f2bf(hv);
      // packed publish: even-jj threads store (self | neighbor<<16), 4B aligned
      unsigned u = (unsigned)hb;
      unsigned nb = __shfl_xor(u, 1);
      if ((jj & 1) == 0)
        st4_sys(hxe + ((size_t)l * 2 + (t & 1)) * 32768 + rr * HID + j0 + jj,
                u | (nb << 16));
      if (t == TLEN - 1) {
        hS [(size_t)l * 32768 + rr * HID + j0 + jj] = hb;
        cSe[(size_t)l * 32768 + rr * HID + j0 + jj] = cc;
      }
      wait_vm0();
    }
    __syncthreads();
    if (tid == 0) st4_sys(flags + bx * 4, (unsigned)(w + 1));
  }
}

// --- decoder per-layer persistent recurrence (K-split waves) ----------------
// 64 blocks x 256 threads. Wave w owns K-slice [w*256, w*256+256) for ALL 4
// gates (B-frags 4x8, 128 VGPR) -> each wave reads only 16KB of hLDS/step.
// Partials in padded zp[4][4][32][17]; combine sums 4 K-slices.
__global__ __launch_bounds__(256, 1) void lstm_seq(
    const float*  __restrict__ Zpre,   // [TLEN][32][4096] (incl bias)
    const ushort* __restrict__ Wht,    // [4096][1024]
    const ushort* __restrict__ h0,     // [32][1024] initial h
    float*        __restrict__ cS,     // [32][1024] c state in/out
    ushort*       __restrict__ yout,   // [TLEN][32][1024]
    unsigned*     __restrict__ flags)  // 64 flags, stride 4 dwords
{
  const int jg = blockIdx.x;
  const int j0 = jg * 16;
  const int tid = threadIdx.x;
  const int lane = tid & 63, wave = tid >> 6;
  const int rr = tid >> 3, cp = tid & 7;

  __shared__ __align__(16) char hLDS[65536];
  __shared__ float zp[4][4][32][17];   // [k-slice wave][gate][row][col+pad]

  float2 cc = *(const float2*)(cS + (size_t)rr * HID + j0 + 2 * cp);

  // B frags: this wave's K-slice, all 4 gates
  bf8 bw[4][8];
  #pragma unroll
  for (int g = 0; g < 4; g++) {
    const ushort* Bp = Wht + (size_t)(g * HID + j0 + (lane & 15)) * HID
                     + wave * 256 + (lane >> 4) * 8;
    #pragma unroll
    for (int kk = 0; kk < 8; kk++)
      bw[g][kk] = *(const bf8*)(Bp + kk * 32);
  }

  const int r0 = lane & 15, r1 = r0 + 16;
  const int klb = (lane >> 4) * 16;
  const int swz = (r0 & 7) << 4;
  const int kbase = wave * 512;        // byte offset of wave's K-slice in a row

  float2 zv[4], zn[4];
  #pragma unroll
  for (int g = 0; g < 4; g++)
    zv[g] = *(const float2*)(Zpre + (size_t)rr * G4 + g * HID + j0 + 2 * cp);

  for (int t = 0; t < TLEN; ++t) {
    if (t > 0) {
      if (wave == 0) {
        const unsigned* fp = flags + lane * 4;
        while (__ballot(ld4_sys(fp) < (unsigned)t)) __builtin_amdgcn_s_sleep(1);
      }
      __syncthreads();
    }
    const char* hsrc = (t == 0) ? (const char*)h0
                                : (const char*)(yout + (size_t)(t - 1) * 32 * HID);
    uint4 hreg[16];
    #pragma unroll
    for (int it = 0; it < 16; it++)
      ld16_sys(hreg[it], hsrc + (size_t)(tid + it * 256) * 16);
    wait_vm0();
    #pragma unroll
    for (int it = 0; it < 16; it++) {
      int c = tid + it * 256;
      int row = c >> 7;
      int o = (c & 127) * 16;
      *(uint4*)(hLDS + row * 2048 + (o ^ ((row & 7) << 4))) = hreg[it];
    }
    __syncthreads();

    if (t + 1 < TLEN) {
      const float* Ztn = Zpre + (size_t)(t + 1) * 32 * G4;
      #pragma unroll
      for (int g = 0; g < 4; g++)
        zn[g] = *(const float2*)(Ztn + (size_t)rr * G4 + g * HID + j0 + 2 * cp);
    }

    // ---- h @ Wh partial (this wave's K-slice, all gates) ----
    f4 acc0[4], acc1[4];
    #pragma unroll
    for (int g = 0; g < 4; g++) { acc0[g] = (f4){0,0,0,0}; acc1[g] = (f4){0,0,0,0}; }
    #pragma unroll
    for (int kk = 0; kk < 8; kk++) {
      int cb = kbase + kk * 64 + klb;
      bf8 a0 = *(const bf8*)(hLDS + r0 * 2048 + (cb ^ swz));
      bf8 a1 = *(const bf8*)(hLDS + r1 * 2048 + (cb ^ swz));
      #pragma unroll
      for (int g = 0; g < 4; g++) {
        acc0[g] = __builtin_amdgcn_mfma_f32_16x16x32_bf16(a0, bw[g][kk], acc0[g], 0, 0, 0);
        acc1[g] = __builtin_amdgcn_mfma_f32_16x16x32_bf16(a1, bw[g][kk], acc1[g], 0, 0, 0);
      }
    }
    #pragma unroll
    for (int g = 0; g < 4; g++)
      #pragma unroll
      for (int v = 0; v < 4; v++) {
        zp[wave][g][(lane >> 4) * 4 + v][lane & 15]      = acc0[g][v];
        zp[wave][g][16 + (lane >> 4) * 4 + v][lane & 15] = acc1[g][v];
      }
    __syncthreads();

    // ---- combine partials + gates (thread owns row rr, cols 2cp,2cp+1) ----
    float zx[4], zy[4];
    #pragma unroll
    for (int g = 0; g < 4; g++) {
      zx[g] = zv[g].x + zp[0][g][rr][2 * cp]     + zp[1][g][rr][2 * cp]
                      + zp[2][g][rr][2 * cp]     + zp[3][g][rr][2 * cp];
      zy[g] = zv[g].y + zp[0][g][rr][2 * cp + 1] + zp[1][g][rr][2 * cp + 1]
                      + zp[2][g][rr][2 * cp + 1] + zp[3][g][rr][2 * cp + 1];
    }
    cc.x = sigmoidf_(zx[1]) * cc.x + sigmoidf_(zx[0]) * tanhf(zx[2]);
    cc.y = sigmoidf_(zy[1]) * cc.y + sigmoidf_(zy[0]) * tanhf(zy[2]);
    float hv0 = sigmoidf_(zx[3]) * tanhf(cc.x);
    float hv1 = sigmoidf_(zy[3]) * tanhf(cc.y);
    unsigned packed = (unsigned)f2bf(hv0) | ((unsigned)f2bf(hv1) << 16);
    st4_sys((char*)(yout + (size_t)t * 32 * HID) + ((size_t)rr * HID + j0 + 2 * cp) * 2,
            packed);
    #pragma unroll
    for (int g = 0; g < 4; g++) zv[g] = zn[g];

    wait_vm0();
    __syncthreads();
    if (tid == 0) st4_sys(flags + jg * 4, (unsigned)(t + 1));
  }
  *(float2*)(cS + (size_t)rr * HID + j0 + 2 * cp) = cc;
}

// --- prep kernels -----------------------------------------------------------
__global__ __launch_bounds__(256) void prep_enc(ushort* hxe, float* cSe,
                                                unsigned* flags) {
  int i = blockIdx.x * 256 + threadIdx.x;      // 768 blocks * 256 = 196608
  hxe[i] = 0;
  if (i < 98304) cSe[i] = 0.f;
  if (i < 192)   flags[i * 4] = 0;
}
__global__ __launch_bounds__(256) void prep_dec0(const ushort* __restrict__ hS2,
                                                 const float* __restrict__ cSe2,
                                                 ushort* h0, float* cS,
                                                 unsigned* flags) {
  int i = blockIdx.x * 256 + threadIdx.x;      // 128 blocks * 256 = 32768
  h0[i] = hS2[i];
  cS[i] = cSe2[i];
  if (i < NBLK_SEQ) flags[i * 4] = 0;
}
__global__ __launch_bounds__(256) void prep_copy(const ushort* __restrict__ src,
                                                 ushort* __restrict__ h0,
                                                 unsigned* __restrict__ flags) {
  int i = blockIdx.x * 256 + threadIdx.x;
  h0[i] = src[i];
  if (i < NBLK_SEQ) flags[i * 4] = 0;
}

// ---------------------------------------------------------------------------
extern "C" void kernel_launch(void* const* d_in, const int* in_sizes, int n_in,
                              void* d_out, int out_size, void* d_ws, size_t ws_size,
                              hipStream_t stream) {
  const int*   enc_ids = (const int*)d_in[0];
  const int*   dec_ids = (const int*)d_in[1];
  const float* emb     = (const float*)d_in[2];
  const float* Wx_enc  = (const float*)d_in[3];
  const float* Wh_enc  = (const float*)d_in[4];
  const float* b_enc   = (const float*)d_in[5];
  const float* Wx_dec  = (const float*)d_in[6];
  const float* Wh_dec  = (const float*)d_in[7];
  const float* b_dec   = (const float*)d_in[8];
  const float* dense_W = (const float*)d_in[9];
  const float* dense_b = (const float*)d_in[10];
  float* out = (float*)d_out;

  // ---- d_ws layout (proven footprint) ----
  char* ws = (char*)d_ws;
  const size_t SZ_BUF = (size_t)4096 * 1024 * 2;   // 8 MiB
  ushort*   bufA   = (ushort*)(ws);
  ushort*   bufB   = (ushort*)(ws + SZ_BUF);
  ushort*   Wxt    = (ushort*)(ws + 2 * SZ_BUF);
  ushort*   Wht    = (ushort*)(ws + 3 * SZ_BUF);
  ushort*   dWt    = (ushort*)(ws + 4 * SZ_BUF);   // VOC*1024*2 B
  char*     p2     = ws + 4 * SZ_BUF + (size_t)VOC * 1024 * 2;
  ushort*   hstate = (ushort*)p2;                            // 64 KiB
  float*    cS     = (float*)(p2 + (size_t)32 * 1024 * 2);   // 128 KiB
  unsigned* flags  = (unsigned*)(p2 + (size_t)32 * 1024 * 2 + (size_t)32 * 1024 * 4);

  // ---- d_out dead-region scratch (500 MB buffer, dense head writes last) --
  char* ob = (char*)d_out;
  float*    Zpre   = out;                                        // [0, 64 MiB)
  ushort*   WhTe   = (ushort*)(ob + (size_t)64  * 1024 * 1024);  // 3 x 8 MiB
  ushort*   WxTe   = (ushort*)(ob + (size_t)88  * 1024 * 1024);  // 2 x 8 MiB
  char*     st     = ob + (size_t)112 * 1024 * 1024;
  ushort*   hxe    = (ushort*)st;                                // 384 KiB
  float*    cSe    = (float*)(st + 393216);                      // 384 KiB
  ushort*   hS     = (ushort*)(st + 786432);                     // 192 KiB
  unsigned* flags2 = (unsigned*)(st + 983040);                   // 3 KiB
  const size_t WSTRIDE = (size_t)G4 * HID;                       // elements

  transpose_cvt<<<dim3(VOC / 32, 1024 / 32), 256, 0, stream>>>(dense_W, dWt, 1024, VOC);

  // ---------------- encoder ----------------
  embed_kernel<<<4096, 256, 0, stream>>>(enc_ids, emb, bufA);
  transpose_cvt<<<dim3(G4 / 32, 32), 256, 0, stream>>>(Wx_enc, Wxt, 1024, G4);
  gemm_bt<<<dim3(G4 / 128, 4096 / 128), 256, 0, stream>>>(bufA, Wxt, b_enc,
                                                          Zpre, 4096, G4, 1024, 0);
  for (int l = 0; l < 3; l++)
    transpose_cvt<<<dim3(G4 / 32, 32), 256, 0, stream>>>(Wh_enc + (size_t)l * 1024 * G4,
                                                         WhTe + l * WSTRIDE, 1024, G4);
  for (int l = 1; l < 3; l++)
    transpose_cvt<<<dim3(G4 / 32, 32), 256, 0, stream>>>(Wx_enc + (size_t)l * 1024 * G4,
                                                         WxTe + (l - 1) * WSTRIDE, 1024, G4);
  prep_enc<<<768, 256, 0, stream>>>(hxe, cSe, flags2);
  enc_wave<<<192, 512, 0, stream>>>(Zpre, WhTe, WxTe, b_enc, hxe, cSe, hS, flags2);

  // ---------------- decoder (serial chaining -> per-layer) ----------------
  embed_kernel<<<4096, 256, 0, stream>>>(dec_ids, emb, bufA);
  ushort* cur = bufA; ushort* oth = bufB;
  for (int l = 0; l < 3; l++) {
    transpose_cvt<<<dim3(G4 / 32, 32), 256, 0, stream>>>(Wx_dec + (size_t)l * 1024 * G4, Wxt, 1024, G4);
    transpose_cvt<<<dim3(G4 / 32, 32), 256, 0, stream>>>(Wh_dec + (size_t)l * 1024 * G4, Wht, 1024, G4);
    gemm_bt<<<dim3(G4 / 128, 4096 / 128), 256, 0, stream>>>(cur, Wxt, b_dec + (size_t)l * G4,
                                                            Zpre, 4096, G4, 1024, 0);
    if (l == 0) {
      prep_dec0<<<128, 256, 0, stream>>>(hS + 2 * 32768, cSe + 2 * 32768, hstate, cS, flags);
    } else {
      const ushort* h0src = cur + (size_t)127 * 32 * HID;
      prep_copy<<<128, 256, 0, stream>>>(h0src, hstate, flags);  // c chains in cS
    }
    lstm_seq<<<NBLK_SEQ, 256, 0, stream>>>(Zpre, Wht, hstate, cS, oth, flags);
    ushort* tmp = cur; cur = oth; oth = tmp;
  }

  // ---------------- dense head: logits[b][t][v] ----------------
  gemm_bt<<<dim3(VOC / 128, 4096 / 128), 256, 0, stream>>>(cur, dWt, dense_b, out,
                                                           4096, VOC, 1024, 1);
}

// Round 9
// 3492.380 us; speedup vs baseline: 4.5895x; 1.0310x over previous
//
#include <hip/hip_runtime.h>

// ---------------------------------------------------------------------------
// Seq2seq: 3-layer LSTM encoder + 3-layer LSTM decoder + dense vocab head
// B=32 T=128 V=32000 E=H=1024 L=3
// Encoder: persistent wavefront kernel (192 blocks = 3 layers x 64 col-blocks,
//   8 waves: 4 gates x {x,h}). Layer l at wave-step w runs t=w-l; 130 steps.
// Decoder: per-layer persistent kernel (64 blocks, 4 K-split waves).
//   Exchange in CHUNK layout hx[2][64][32][16] (block jg's 16 cols = 1KB
//   contiguous): publish = 16 full 64B lines (no partial-line RMW), and
//   A-fragments are loaded DIRECTLY from L3 into registers (no LDS staging).
//   yout (linear, for later GEMMs) written with normal cached stores.
// Exchange coherence: sys-scope (sc0 sc1) ld/st bypass L1/L2, coherent at L3.
// GEMMs: XCD-aware bijective block swizzle (all grids %8 == 0).
// ---------------------------------------------------------------------------

typedef __bf16 bf8 __attribute__((ext_vector_type(8)));
typedef float  f4  __attribute__((ext_vector_type(4)));

#define TLEN  128
#define HID   1024
#define G4    4096
#define VOC   32000
#define NBLK_SEQ 64

__device__ __forceinline__ ushort f2bf(float f) {
  unsigned u = __builtin_bit_cast(unsigned, f);
  u += 0x7fffu + ((u >> 16) & 1u);          // round-to-nearest-even
  return (ushort)(u >> 16);
}
__device__ __forceinline__ float sigmoidf_(float x) { return 1.f / (1.f + expf(-x)); }

// ---- system-scope (bypass L1+L2, coherent at L3) memory ops ----------------
__device__ __forceinline__ void ld16_sys(uint4& v, const void* p) {
  asm volatile("global_load_dwordx4 %0, %1, off sc0 sc1" : "=v"(v) : "v"(p));
}
__device__ __forceinline__ unsigned ld4_sys(const void* p) {
  unsigned v;
  asm volatile("global_load_dword %0, %1, off sc0 sc1\n\ts_waitcnt vmcnt(0)"
               : "=v"(v) : "v"(p) : "memory");
  return v;
}
__device__ __forceinline__ void ld4_sys3(unsigned& a, unsigned& b, unsigned& c,
                                         const void* pa, const void* pb, const void* pc) {
  asm volatile("global_load_dword %0, %3, off sc0 sc1\n\t"
               "global_load_dword %1, %4, off sc0 sc1\n\t"
               "global_load_dword %2, %5, off sc0 sc1\n\t"
               "s_waitcnt vmcnt(0)"
               : "=&v"(a), "=&v"(b), "=&v"(c)
               : "v"(pa), "v"(pb), "v"(pc) : "memory");
}
__device__ __forceinline__ void st4_sys(void* p, unsigned v) {
  asm volatile("global_store_dword %0, %1, off sc0 sc1" :: "v"(p), "v"(v) : "memory");
}
__device__ __forceinline__ void wait_vm0() {
  asm volatile("s_waitcnt vmcnt(0)" ::: "memory");
  __builtin_amdgcn_sched_barrier(0);
}

typedef const __attribute__((address_space(1))) void GvoidC;
typedef __attribute__((address_space(3))) void Lvoid;
__device__ __forceinline__ void g2l16(const void* g, void* l) {
  __builtin_amdgcn_global_load_lds((GvoidC*)g, (Lvoid*)l, 16, 0, 0);
}

// --- embedding gather: out[t*32+b][e] = bf16(emb[ids[b][t]][e]) -------------
__global__ __launch_bounds__(256) void embed_kernel(const int* __restrict__ ids,
    const float* __restrict__ emb, ushort* __restrict__ out) {
  int r = blockIdx.x;            // r = t*32 + b
  int b = r & 31, t = r >> 5;
  int id = ids[b * TLEN + t];
  const float4* src = (const float4*)(emb + (size_t)id * HID);
  float4 v = src[threadIdx.x];
  ushort4 o;
  o.x = f2bf(v.x); o.y = f2bf(v.y); o.z = f2bf(v.z); o.w = f2bf(v.w);
  *(ushort4*)(out + (size_t)r * HID + threadIdx.x * 4) = o;
}

// --- f32 [R][C] -> bf16 [C][R] tiled transpose ------------------------------
__global__ __launch_bounds__(256) void transpose_cvt(const float* __restrict__ W,
    ushort* __restrict__ Wt, int R, int C) {
  __shared__ float tile[32][33];
  int tx = threadIdx.x & 31, ty = threadIdx.x >> 5;   // ty 0..7
  int c0 = blockIdx.x * 32, r0 = blockIdx.y * 32;
  #pragma unroll
  for (int i = 0; i < 32; i += 8)
    tile[ty + i][tx] = W[(size_t)(r0 + ty + i) * C + c0 + tx];
  __syncthreads();
  #pragma unroll
  for (int i = 0; i < 32; i += 8)
    Wt[(size_t)(c0 + ty + i) * R + r0 + tx] = f2bf(tile[tx][ty + i]);
}

// --- bf16 MFMA GEMM: C[M][N] = A[M][K] @ Bt[N][K]^T + bias ------------------
// 128x128 tile; XCD-aware bijective swizzle (requires nwg % 8 == 0).
__global__ __launch_bounds__(256) void gemm_bt(const ushort* __restrict__ A,
    const ushort* __restrict__ Bt, const float* __restrict__ bias,
    float* __restrict__ C, int M, int N, int K, int permute) {
  __shared__ __align__(16) ushort lA[128 * 32];
  __shared__ __align__(16) ushort lB[128 * 32];
  int tid = threadIdx.x;
  int lane = tid & 63, wave = tid >> 6;
  int nwg = gridDim.x * gridDim.y;
  int wg  = blockIdx.y * gridDim.x + blockIdx.x;
  int q   = nwg >> 3;
  int swg = (wg & 7) * q + (wg >> 3);          // bijective when nwg % 8 == 0
  int m0 = (swg / gridDim.x) * 128, n0 = (swg % gridDim.x) * 128;
  int wr = wave >> 1, wc = wave & 1;
  f4 zero = {0.f, 0.f, 0.f, 0.f};
  f4 acc[4][4];
  #pragma unroll
  for (int i = 0; i < 4; i++)
    #pragma unroll
    for (int j = 0; j < 4; j++) acc[i][j] = zero;

  const ushort* Ag = A  + (size_t)(m0 + wave * 32 + (lane >> 2)) * K + (lane & 3) * 8;
  const ushort* Bg = Bt + (size_t)(n0 + wave * 32 + (lane >> 2)) * K + (lane & 3) * 8;
  ushort* lAp = lA + wave * 32 * 32;
  ushort* lBp = lB + wave * 32 * 32;

  for (int kt = 0; kt < K; kt += 32) {
    g2l16(Ag + kt, lAp);
    g2l16(Ag + (size_t)16 * K + kt, lAp + 16 * 32);
    g2l16(Bg + kt, lBp);
    g2l16(Bg + (size_t)16 * K + kt, lBp + 16 * 32);
    __syncthreads();
    bf8 aF[4], bF[4];
    #pragma unroll
    for (int i = 0; i < 4; i++)
      aF[i] = *(const bf8*)(lA + (wr * 64 + i * 16 + (lane & 15)) * 32 + (lane >> 4) * 8);
    #pragma unroll
    for (int j = 0; j < 4; j++)
      bF[j] = *(const bf8*)(lB + (wc * 64 + j * 16 + (lane & 15)) * 32 + (lane >> 4) * 8);
    #pragma unroll
    for (int i = 0; i < 4; i++)
      #pragma unroll
      for (int j = 0; j < 4; j++)
        acc[i][j] = __builtin_amdgcn_mfma_f32_16x16x32_bf16(aF[i], bF[j], acc[i][j], 0, 0, 0);
    __syncthreads();
  }
  #pragma unroll
  for (int i = 0; i < 4; i++) {
    #pragma unroll
    for (int j = 0; j < 4; j++) {
      int col = n0 + wc * 64 + j * 16 + (lane & 15);
      float bv = bias ? bias[col] : 0.f;
      #pragma unroll
      for (int v = 0; v < 4; v++) {
        int row = m0 + wr * 64 + i * 16 + (lane >> 4) * 4 + v;
        int orow = permute ? ((row & 31) * TLEN + (row >> 5)) : row;
        C[(size_t)orow * N + col] = acc[i][j][v] + bv;
      }
    }
  }
}

// --- encoder wavefront: all 3 layers in one persistent kernel ---------------
__global__ __launch_bounds__(512, 1) void enc_wave(
    const float*  __restrict__ Zpre,   // [128][32][4096] layer-0 pregates (incl bias)
    const ushort* __restrict__ WhT,    // 3 x [4096][1024]
    const ushort* __restrict__ WxT,    // 2 x [4096][1024] (layers 1,2 -> idx l-1)
    const float*  __restrict__ bE,     // [3][4096]
    ushort*       __restrict__ hxe,    // [3][2][32][1024] bf16 exchange (pre-zeroed)
    float*        __restrict__ cSe,    // [3][32][1024] c state (pre-zeroed)
    ushort*       __restrict__ hS,     // [3][32][1024] final h out
    unsigned*     __restrict__ flags)  // 192 flags, stride 4 dwords
{
  const int bx = blockIdx.x;
  const int l = bx >> 6, jg = bx & 63;
  const int j0 = jg * 16;
  const int tid = threadIdx.x;
  const int lane = tid & 63, wave = tid >> 6;
  const int g = wave & 3, op = wave >> 2;
  const int rr = tid >> 4, jj = tid & 15;           // combine: row 0..31, col 0..15

  __shared__ __align__(16) char hLDS[65536];
  __shared__ __align__(16) char xLDS[65536];
  __shared__ float zbuf[8][32][17];

  float cc = cSe[(size_t)l * 32768 + rr * HID + j0 + jj];
  float bias4[4];
  #pragma unroll
  for (int gg = 0; gg < 4; gg++)
    bias4[gg] = bE[l * G4 + gg * HID + j0 + jj];

  const bool mfma_on = (l > 0) || (op == 0);
  bf8 bw[32];
  if (mfma_on) {
    const ushort* Wb = op ? (WxT + (size_t)(l - 1) * G4 * HID)
                          : (WhT + (size_t)l * G4 * HID);
    const ushort* Bp = Wb + (size_t)(g * HID + j0 + (lane & 15)) * HID + (lane >> 4) * 8;
    #pragma unroll
    for (int kk = 0; kk < 32; kk++) bw[kk] = *(const bf8*)(Bp + kk * 32);
  }

  const int r0 = lane & 15, r1 = r0 + 16;
  const int klb = (lane >> 4) * 16;
  const int swz = (r0 & 7) << 4;

  float zv4[4], zn4[4];
  if (l == 0) {
    #pragma unroll
    for (int gg = 0; gg < 4; gg++)
      zv4[gg] = Zpre[(size_t)rr * G4 + gg * HID + j0 + jj];
  }

  for (int w = 0; w < 130; ++w) {
    if (w > 0) {
      if (wave == 0) {
        for (;;) {
          unsigned a, b, c;
          ld4_sys3(a, b, c, flags + lane * 4, flags + (64 + lane) * 4,
                   flags + (128 + lane) * 4);
          if (!__ballot(a < (unsigned)w || b < (unsigned)w || c < (unsigned)w)) break;
          __builtin_amdgcn_s_sleep(1);
        }
      }
      __syncthreads();
    }
    const int t = w - l;
    if (t >= 0 && t < TLEN) {
      // ---- stage h_{t-1} (and x = below's y_t for l>0) into LDS ----
      const char* hsrc = (const char*)(hxe + ((size_t)l * 2 + ((t - 1) & 1)) * 32768);
      uint4 hreg[8], xreg[8];
      #pragma unroll
      for (int it = 0; it < 8; it++)
        ld16_sys(hreg[it], hsrc + (size_t)(tid + it * 512) * 16);
      if (l > 0) {
        const char* xsrc = (const char*)(hxe + ((size_t)(l - 1) * 2 + (t & 1)) * 32768);
        #pragma unroll
        for (int it = 0; it < 8; it++)
          ld16_sys(xreg[it], xsrc + (size_t)(tid + it * 512) * 16);
      }
      wait_vm0();
      #pragma unroll
      for (int it = 0; it < 8; it++) {
        int c = tid + it * 512;
        int row = c >> 7;
        int o = (c & 127) * 16;
        *(uint4*)(hLDS + row * 2048 + (o ^ ((row & 7) << 4))) = hreg[it];
      }
      if (l > 0) {
        #pragma unroll
        for (int it = 0; it < 8; it++) {
          int c = tid + it * 512;
          int row = c >> 7;
          int o = (c & 127) * 16;
          *(uint4*)(xLDS + row * 2048 + (o ^ ((row & 7) << 4))) = xreg[it];
        }
      }
      __syncthreads();

      if (l == 0 && t + 1 < TLEN) {
        const float* Ztn = Zpre + (size_t)(t + 1) * 32 * G4;
        #pragma unroll
        for (int gg = 0; gg < 4; gg++)
          zn4[gg] = Ztn[(size_t)rr * G4 + gg * HID + j0 + jj];
      }

      if (mfma_on) {
        const char* S = op ? xLDS : hLDS;
        f4 acc0 = {0.f, 0.f, 0.f, 0.f}, acc1 = {0.f, 0.f, 0.f, 0.f};
        #pragma unroll
        for (int kk = 0; kk < 32; kk++) {
          int cb = kk * 64 + klb;
          bf8 a0 = *(const bf8*)(S + r0 * 2048 + (cb ^ swz));
          bf8 a1 = *(const bf8*)(S + r1 * 2048 + (cb ^ swz));
          acc0 = __builtin_amdgcn_mfma_f32_16x16x32_bf16(a0, bw[kk], acc0, 0, 0, 0);
          acc1 = __builtin_amdgcn_mfma_f32_16x16x32_bf16(a1, bw[kk], acc1, 0, 0, 0);
        }
        #pragma unroll
        for (int v = 0; v < 4; v++) {
          zbuf[wave][(lane >> 4) * 4 + v][lane & 15]      = acc0[v];
          zbuf[wave][16 + (lane >> 4) * 4 + v][lane & 15] = acc1[v];
        }
      }
      __syncthreads();

      // ---- combine + gates (thread owns row rr, col j0+jj) ----
      float z[4];
      #pragma unroll
      for (int gg = 0; gg < 4; gg++) z[gg] = zbuf[gg][rr][jj];
      if (l > 0) {
        #pragma unroll
        for (int gg = 0; gg < 4; gg++) z[gg] += zbuf[4 + gg][rr][jj] + bias4[gg];
      } else {
        #pragma unroll
        for (int gg = 0; gg < 4; gg++) z[gg] += zv4[gg];
        #pragma unroll
        for (int gg = 0; gg < 4; gg++) zv4[gg] = zn4[gg];
      }
      float ig = sigmoidf_(z[0]), fg = sigmoidf_(z[1]);
      float gv = tanhf(z[2]),     og = sigmoidf_(z[3]);
      cc = fg * cc + ig * gv;
      float hv = og * tanhf(cc);
      ushort hb = f2bf(hv);
      // packed publish: even-jj threads store (self | neighbor<<16), 4B aligned
      unsigned u = (unsigned)hb;
      unsigned nb = __shfl_xor(u, 1);
      if ((jj & 1) == 0)
        st4_sys(hxe + ((size_t)l * 2 + (t & 1)) * 32768 + rr * HID + j0 + jj,
                u | (nb << 16));
      if (t == TLEN - 1) {
        hS [(size_t)l * 32768 + rr * HID + j0 + jj] = hb;
        cSe[(size_t)l * 32768 + rr * HID + j0 + jj] = cc;
      }
      wait_vm0();
    }
    __syncthreads();
    if (tid == 0) st4_sys(flags + bx * 4, (unsigned)(w + 1));
  }
}

// --- decoder per-layer persistent recurrence --------------------------------
// 64 blocks x 256 threads, K-split waves (wave w: K-slice [w*256,w*256+256),
// all 4 gates). Exchange in CHUNK layout hx[2][64][32][16]: A-fragments are
// loaded straight from L3 into registers (no LDS staging); publish is 1KB
// contiguous (full cache lines). yout (linear) uses normal cached stores.
// Read parity (t+1)&1 (t=0 -> hx[1] = h0 chunks from prep), write parity t&1.
__global__ __launch_bounds__(256, 1) void lstm_seq(
    const float*  __restrict__ Zpre,   // [TLEN][32][4096] (incl bias)
    const ushort* __restrict__ Wht,    // [4096][1024]
    float*        __restrict__ cS,     // [32][1024] c state in/out
    ushort*       __restrict__ yout,   // [TLEN][32][1024] linear out
    ushort*       __restrict__ hx,     // [2][64][32][16] chunked exchange
    unsigned*     __restrict__ flags)  // 64 flags, stride 4 dwords
{
  const int jg = blockIdx.x;
  const int j0 = jg * 16;
  const int tid = threadIdx.x;
  const int lane = tid & 63, wave = tid >> 6;
  const int rr = tid >> 3, cp = tid & 7;

  __shared__ float zp[4][4][32][17];   // [k-slice wave][gate][row][col+pad]

  float2 cc = *(const float2*)(cS + (size_t)rr * HID + j0 + 2 * cp);

  // B frags: this wave's K-slice, all 4 gates (128 VGPR)
  bf8 bw[4][8];
  #pragma unroll
  for (int g = 0; g < 4; g++) {
    const ushort* Bp = Wht + (size_t)(g * HID + j0 + (lane & 15)) * HID
                     + wave * 256 + (lane >> 4) * 8;
    #pragma unroll
    for (int kk = 0; kk < 8; kk++)
      bw[g][kk] = *(const bf8*)(Bp + kk * 32);
  }

  const int r0 = lane & 15, r1 = r0 + 16;
  const int lk = lane >> 4;                         // 0..3
  // A-frag element offsets in chunk layout: chunk = wave*16 + kk*2 + (lk>>1)
  const int aoff0 = wave * 8192 + (lk >> 1) * 512 + r0 * 16 + (lk & 1) * 8;
  const int aoff1 = wave * 8192 + (lk >> 1) * 512 + r1 * 16 + (lk & 1) * 8;

  float2 zv[4], zn[4];
  #pragma unroll
  for (int g = 0; g < 4; g++)
    zv[g] = *(const float2*)(Zpre + (size_t)rr * G4 + g * HID + j0 + 2 * cp);

  for (int t = 0; t < TLEN; ++t) {
    if (t > 0) {
      if (wave == 0) {
        const unsigned* fp = flags + lane * 4;
        while (__ballot(ld4_sys(fp) < (unsigned)t)) __builtin_amdgcn_s_sleep(1);
      }
      __syncthreads();
    }
    // ---- A-fragments direct from L3 (chunked exchange buffer) ----
    const ushort* hsrc = hx + ((t + 1) & 1) * 32768;
    uint4 ha0[8], ha1[8];
    #pragma unroll
    for (int kk = 0; kk < 8; kk++) {
      ld16_sys(ha0[kk], hsrc + aoff0 + kk * 1024);
      ld16_sys(ha1[kk], hsrc + aoff1 + kk * 1024);
    }
    wait_vm0();

    // prefetch next step's Z (normal cached loads; overlap with MFMA)
    if (t + 1 < TLEN) {
      const float* Ztn = Zpre + (size_t)(t + 1) * 32 * G4;
      #pragma unroll
      for (int g = 0; g < 4; g++)
        zn[g] = *(const float2*)(Ztn + (size_t)rr * G4 + g * HID + j0 + 2 * cp);
    }

    // ---- h @ Wh partial (this wave's K-slice, all gates) ----
    f4 acc0[4], acc1[4];
    #pragma unroll
    for (int g = 0; g < 4; g++) { acc0[g] = (f4){0,0,0,0}; acc1[g] = (f4){0,0,0,0}; }
    #pragma unroll
    for (int kk = 0; kk < 8; kk++) {
      bf8 a0 = __builtin_bit_cast(bf8, ha0[kk]);
      bf8 a1 = __builtin_bit_cast(bf8, ha1[kk]);
      #pragma unroll
      for (int g = 0; g < 4; g++) {
        acc0[g] = __builtin_amdgcn_mfma_f32_16x16x32_bf16(a0, bw[g][kk], acc0[g], 0, 0, 0);
        acc1[g] = __builtin_amdgcn_mfma_f32_16x16x32_bf16(a1, bw[g][kk], acc1[g], 0, 0, 0);
      }
    }
    #pragma unroll
    for (int g = 0; g < 4; g++)
      #pragma unroll
      for (int v = 0; v < 4; v++) {
        zp[wave][g][(lane >> 4) * 4 + v][lane & 15]      = acc0[g][v];
        zp[wave][g][16 + (lane >> 4) * 4 + v][lane & 15] = acc1[g][v];
      }
    __syncthreads();

    // ---- combine partials + gates (thread owns row rr, cols 2cp,2cp+1) ----
    float zx[4], zy[4];
    #pragma unroll
    for (int g = 0; g < 4; g++) {
      zx[g] = zv[g].x + zp[0][g][rr][2 * cp]     + zp[1][g][rr][2 * cp]
                      + zp[2][g][rr][2 * cp]     + zp[3][g][rr][2 * cp];
      zy[g] = zv[g].y + zp[0][g][rr][2 * cp + 1] + zp[1][g][rr][2 * cp + 1]
                      + zp[2][g][rr][2 * cp + 1] + zp[3][g][rr][2 * cp + 1];
    }
    cc.x = sigmoidf_(zx[1]) * cc.x + sigmoidf_(zx[0]) * tanhf(zx[2]);
    cc.y = sigmoidf_(zy[1]) * cc.y + sigmoidf_(zy[0]) * tanhf(zy[2]);
    float hv0 = sigmoidf_(zx[3]) * tanhf(cc.x);
    float hv1 = sigmoidf_(zy[3]) * tanhf(cc.y);
    unsigned packed = (unsigned)f2bf(hv0) | ((unsigned)f2bf(hv1) << 16);
    // linear yout: normal cached store (read only by later kernels)
    *(unsigned*)(yout + (size_t)t * 32768 + rr * HID + j0 + 2 * cp) = packed;
    // chunked exchange publish: sys store, full-line pattern
    st4_sys(hx + (size_t)(t & 1) * 32768 + jg * 512 + rr * 16 + 2 * cp, packed);
    #pragma unroll
    for (int g = 0; g < 4; g++) zv[g] = zn[g];

    wait_vm0();
    __syncthreads();
    if (tid == 0) st4_sys(flags + jg * 4, (unsigned)(t + 1));
  }
  *(float2*)(cS + (size_t)rr * HID + j0 + 2 * cp) = cc;
}

// --- prep kernels -----------------------------------------------------------
__global__ __launch_bounds__(256) void prep_enc(ushort* hxe, float* cSe,
                                                unsigned* flags) {
  int i = blockIdx.x * 256 + threadIdx.x;      // 768 blocks * 256 = 196608
  hxe[i] = 0;
  if (i < 98304) cSe[i] = 0.f;
  if (i < 192)   flags[i * 4] = 0;
}
// h0 -> chunk layout into hx[1]; c copy; flag reset
__global__ __launch_bounds__(256) void prep_dec0(const ushort* __restrict__ hS2,
                                                 const float* __restrict__ cSe2,
                                                 float* cS, ushort* hx,
                                                 unsigned* flags) {
  int i = blockIdx.x * 256 + threadIdx.x;      // 128 blocks * 256 = 32768
  int row = i >> 10, col = i & 1023;
  hx[32768 + (col >> 4) * 512 + row * 16 + (col & 15)] = hS2[i];
  cS[i] = cSe2[i];
  if (i < NBLK_SEQ) flags[i * 4] = 0;
}
__global__ __launch_bounds__(256) void prep_copy(const ushort* __restrict__ src,
                                                 ushort* __restrict__ hx,
                                                 unsigned* __restrict__ flags) {
  int i = blockIdx.x * 256 + threadIdx.x;
  int row = i >> 10, col = i & 1023;
  hx[32768 + (col >> 4) * 512 + row * 16 + (col & 15)] = src[i];
  if (i < NBLK_SEQ) flags[i * 4] = 0;
}

// ---------------------------------------------------------------------------
extern "C" void kernel_launch(void* const* d_in, const int* in_sizes, int n_in,
                              void* d_out, int out_size, void* d_ws, size_t ws_size,
                              hipStream_t stream) {
  const int*   enc_ids = (const int*)d_in[0];
  const int*   dec_ids = (const int*)d_in[1];
  const float* emb     = (const float*)d_in[2];
  const float* Wx_enc  = (const float*)d_in[3];
  const float* Wh_enc  = (const float*)d_in[4];
  const float* b_enc   = (const float*)d_in[5];
  const float* Wx_dec  = (const float*)d_in[6];
  const float* Wh_dec  = (const float*)d_in[7];
  const float* b_dec   = (const float*)d_in[8];
  const float* dense_W = (const float*)d_in[9];
  const float* dense_b = (const float*)d_in[10];
  float* out = (float*)d_out;

  // ---- d_ws layout (proven footprint) ----
  char* ws = (char*)d_ws;
  const size_t SZ_BUF = (size_t)4096 * 1024 * 2;   // 8 MiB
  ushort*   bufA   = (ushort*)(ws);
  ushort*   bufB   = (ushort*)(ws + SZ_BUF);
  ushort*   Wxt    = (ushort*)(ws + 2 * SZ_BUF);
  ushort*   Wht    = (ushort*)(ws + 3 * SZ_BUF);
  ushort*   dWt    = (ushort*)(ws + 4 * SZ_BUF);   // VOC*1024*2 B
  char*     p2     = ws + 4 * SZ_BUF + (size_t)VOC * 1024 * 2;
  float*    cS     = (float*)(p2 + (size_t)32 * 1024 * 2);   // 128 KiB
  unsigned* flags  = (unsigned*)(p2 + (size_t)32 * 1024 * 2 + (size_t)32 * 1024 * 4);

  // ---- d_out dead-region scratch (500 MB buffer, dense head writes last) --
  char* ob = (char*)d_out;
  float*    Zpre   = out;                                        // [0, 64 MiB)
  ushort*   WhTe   = (ushort*)(ob + (size_t)64  * 1024 * 1024);  // 3 x 8 MiB
  ushort*   WxTe   = (ushort*)(ob + (size_t)88  * 1024 * 1024);  // 2 x 8 MiB
  char*     st     = ob + (size_t)112 * 1024 * 1024;
  ushort*   hxe    = (ushort*)st;                                // 384 KiB
  float*    cSe    = (float*)(st + 393216);                      // 384 KiB
  ushort*   hS     = (ushort*)(st + 786432);                     // 192 KiB
  unsigned* flags2 = (unsigned*)(st + 983040);                   // 3 KiB
  ushort*   hxD    = (ushort*)(ob + (size_t)120 * 1024 * 1024);  // 128 KiB chunked
  const size_t WSTRIDE = (size_t)G4 * HID;                       // elements

  transpose_cvt<<<dim3(VOC / 32, 1024 / 32), 256, 0, stream>>>(dense_W, dWt, 1024, VOC);

  // ---------------- encoder ----------------
  embed_kernel<<<4096, 256, 0, stream>>>(enc_ids, emb, bufA);
  transpose_cvt<<<dim3(G4 / 32, 32), 256, 0, stream>>>(Wx_enc, Wxt, 1024, G4);
  gemm_bt<<<dim3(G4 / 128, 4096 / 128), 256, 0, stream>>>(bufA, Wxt, b_enc,
                                                          Zpre, 4096, G4, 1024, 0);
  for (int l = 0; l < 3; l++)
    transpose_cvt<<<dim3(G4 / 32, 32), 256, 0, stream>>>(Wh_enc + (size_t)l * 1024 * G4,
                                                         WhTe + l * WSTRIDE, 1024, G4);
  for (int l = 1; l < 3; l++)
    transpose_cvt<<<dim3(G4 / 32, 32), 256, 0, stream>>>(Wx_enc + (size_t)l * 1024 * G4,
                                                         WxTe + (l - 1) * WSTRIDE, 1024, G4);
  prep_enc<<<768, 256, 0, stream>>>(hxe, cSe, flags2);
  enc_wave<<<192, 512, 0, stream>>>(Zpre, WhTe, WxTe, b_enc, hxe, cSe, hS, flags2);

  // ---------------- decoder (serial chaining -> per-layer) ----------------
  embed_kernel<<<4096, 256, 0, stream>>>(dec_ids, emb, bufA);
  ushort* cur = bufA; ushort* oth = bufB;
  for (int l = 0; l < 3; l++) {
    transpose_cvt<<<dim3(G4 / 32, 32), 256, 0, stream>>>(Wx_dec + (size_t)l * 1024 * G4, Wxt, 1024, G4);
    transpose_cvt<<<dim3(G4 / 32, 32), 256, 0, stream>>>(Wh_dec + (size_t)l * 1024 * G4, Wht, 1024, G4);
    gemm_bt<<<dim3(G4 / 128, 4096 / 128), 256, 0, stream>>>(cur, Wxt, b_dec + (size_t)l * G4,
                                                            Zpre, 4096, G4, 1024, 0);
    if (l == 0) {
      prep_dec0<<<128, 256, 0, stream>>>(hS + 2 * 32768, cSe + 2 * 32768, cS, hxD, flags);
    } else {
      const ushort* h0src = cur + (size_t)127 * 32 * HID;
      prep_copy<<<128, 256, 0, stream>>>(h0src, hxD, flags);   // c chains in cS
    }
    lstm_seq<<<NBLK_SEQ, 256, 0, stream>>>(Zpre, Wht, cS, oth, hxD, flags);
    ushort* tmp = cur; cur = oth; oth = tmp;
  }

  // ---------------- dense head: logits[b][t][v] ----------------
  gemm_bt<<<dim3(VOC / 128, 4096 / 128), 256, 0, stream>>>(cur, dWt, dense_b, out,
                                                           4096, VOC, 1024, 1);
}

// Round 10
// 3160.272 us; speedup vs baseline: 5.0718x; 1.1051x over previous
//
#include <hip/hip_runtime.h>

// ---------------------------------------------------------------------------
// Seq2seq: 3-layer LSTM encoder + 3-layer LSTM decoder + dense vocab head
// B=32 T=128 V=32000 E=H=1024 L=3
// Encoder: persistent wavefront kernel (192 blocks = 3 layers x 64 col-blocks,
//   512 thr = 8 waves = {h,x} x {K-slice 0..3}). Layer l at wave-step w runs
//   t=w-l. A-fragments read DIRECTLY from chunked L3 exchange into registers
//   (no LDS staging); partials combined via padded zp LDS buffer.
// Decoder: per-layer persistent kernel (64 blocks, 4 K-split waves), same
//   chunked exchange scheme (proven round 9).
// Exchange coherence: sys-scope (sc0 sc1) ld/st bypass L1/L2, coherent at L3.
// GEMMs: XCD-aware bijective block swizzle (all grids %8 == 0).
// ---------------------------------------------------------------------------

typedef __bf16 bf8 __attribute__((ext_vector_type(8)));
typedef float  f4  __attribute__((ext_vector_type(4)));

#define TLEN  128
#define HID   1024
#define G4    4096
#define VOC   32000
#define NBLK_SEQ 64

__device__ __forceinline__ ushort f2bf(float f) {
  unsigned u = __builtin_bit_cast(unsigned, f);
  u += 0x7fffu + ((u >> 16) & 1u);          // round-to-nearest-even
  return (ushort)(u >> 16);
}
__device__ __forceinline__ float sigmoidf_(float x) { return 1.f / (1.f + expf(-x)); }

// ---- system-scope (bypass L1+L2, coherent at L3) memory ops ----------------
__device__ __forceinline__ void ld16_sys(uint4& v, const void* p) {
  asm volatile("global_load_dwordx4 %0, %1, off sc0 sc1" : "=v"(v) : "v"(p));
}
__device__ __forceinline__ unsigned ld4_sys(const void* p) {
  unsigned v;
  asm volatile("global_load_dword %0, %1, off sc0 sc1\n\ts_waitcnt vmcnt(0)"
               : "=v"(v) : "v"(p) : "memory");
  return v;
}
__device__ __forceinline__ void ld4_sys3(unsigned& a, unsigned& b, unsigned& c,
                                         const void* pa, const void* pb, const void* pc) {
  asm volatile("global_load_dword %0, %3, off sc0 sc1\n\t"
               "global_load_dword %1, %4, off sc0 sc1\n\t"
               "global_load_dword %2, %5, off sc0 sc1\n\t"
               "s_waitcnt vmcnt(0)"
               : "=&v"(a), "=&v"(b), "=&v"(c)
               : "v"(pa), "v"(pb), "v"(pc) : "memory");
}
__device__ __forceinline__ void st4_sys(void* p, unsigned v) {
  asm volatile("global_store_dword %0, %1, off sc0 sc1" :: "v"(p), "v"(v) : "memory");
}
__device__ __forceinline__ void wait_vm0() {
  asm volatile("s_waitcnt vmcnt(0)" ::: "memory");
  __builtin_amdgcn_sched_barrier(0);
}

typedef const __attribute__((address_space(1))) void GvoidC;
typedef __attribute__((address_space(3))) void Lvoid;
__device__ __forceinline__ void g2l16(const void* g, void* l) {
  __builtin_amdgcn_global_load_lds((GvoidC*)g, (Lvoid*)l, 16, 0, 0);
}

// --- embedding gather: out[t*32+b][e] = bf16(emb[ids[b][t]][e]) -------------
__global__ __launch_bounds__(256) void embed_kernel(const int* __restrict__ ids,
    const float* __restrict__ emb, ushort* __restrict__ out) {
  int r = blockIdx.x;            // r = t*32 + b
  int b = r & 31, t = r >> 5;
  int id = ids[b * TLEN + t];
  const float4* src = (const float4*)(emb + (size_t)id * HID);
  float4 v = src[threadIdx.x];
  ushort4 o;
  o.x = f2bf(v.x); o.y = f2bf(v.y); o.z = f2bf(v.z); o.w = f2bf(v.w);
  *(ushort4*)(out + (size_t)r * HID + threadIdx.x * 4) = o;
}

// --- f32 [R][C] -> bf16 [C][R] tiled transpose ------------------------------
__global__ __launch_bounds__(256) void transpose_cvt(const float* __restrict__ W,
    ushort* __restrict__ Wt, int R, int C) {
  __shared__ float tile[32][33];
  int tx = threadIdx.x & 31, ty = threadIdx.x >> 5;   // ty 0..7
  int c0 = blockIdx.x * 32, r0 = blockIdx.y * 32;
  #pragma unroll
  for (int i = 0; i < 32; i += 8)
    tile[ty + i][tx] = W[(size_t)(r0 + ty + i) * C + c0 + tx];
  __syncthreads();
  #pragma unroll
  for (int i = 0; i < 32; i += 8)
    Wt[(size_t)(c0 + ty + i) * R + r0 + tx] = f2bf(tile[tx][ty + i]);
}

// --- bf16 MFMA GEMM: C[M][N] = A[M][K] @ Bt[N][K]^T + bias ------------------
// 128x128 tile; XCD-aware bijective swizzle (requires nwg % 8 == 0).
__global__ __launch_bounds__(256) void gemm_bt(const ushort* __restrict__ A,
    const ushort* __restrict__ Bt, const float* __restrict__ bias,
    float* __restrict__ C, int M, int N, int K, int permute) {
  __shared__ __align__(16) ushort lA[128 * 32];
  __shared__ __align__(16) ushort lB[128 * 32];
  int tid = threadIdx.x;
  int lane = tid & 63, wave = tid >> 6;
  int nwg = gridDim.x * gridDim.y;
  int wg  = blockIdx.y * gridDim.x + blockIdx.x;
  int q   = nwg >> 3;
  int swg = (wg & 7) * q + (wg >> 3);          // bijective when nwg % 8 == 0
  int m0 = (swg / gridDim.x) * 128, n0 = (swg % gridDim.x) * 128;
  int wr = wave >> 1, wc = wave & 1;
  f4 zero = {0.f, 0.f, 0.f, 0.f};
  f4 acc[4][4];
  #pragma unroll
  for (int i = 0; i < 4; i++)
    #pragma unroll
    for (int j = 0; j < 4; j++) acc[i][j] = zero;

  const ushort* Ag = A  + (size_t)(m0 + wave * 32 + (lane >> 2)) * K + (lane & 3) * 8;
  const ushort* Bg = Bt + (size_t)(n0 + wave * 32 + (lane >> 2)) * K + (lane & 3) * 8;
  ushort* lAp = lA + wave * 32 * 32;
  ushort* lBp = lB + wave * 32 * 32;

  for (int kt = 0; kt < K; kt += 32) {
    g2l16(Ag + kt, lAp);
    g2l16(Ag + (size_t)16 * K + kt, lAp + 16 * 32);
    g2l16(Bg + kt, lBp);
    g2l16(Bg + (size_t)16 * K + kt, lBp + 16 * 32);
    __syncthreads();
    bf8 aF[4], bF[4];
    #pragma unroll
    for (int i = 0; i < 4; i++)
      aF[i] = *(const bf8*)(lA + (wr * 64 + i * 16 + (lane & 15)) * 32 + (lane >> 4) * 8);
    #pragma unroll
    for (int j = 0; j < 4; j++)
      bF[j] = *(const bf8*)(lB + (wc * 64 + j * 16 + (lane & 15)) * 32 + (lane >> 4) * 8);
    #pragma unroll
    for (int i = 0; i < 4; i++)
      #pragma unroll
      for (int j = 0; j < 4; j++)
        acc[i][j] = __builtin_amdgcn_mfma_f32_16x16x32_bf16(aF[i], bF[j], acc[i][j], 0, 0, 0);
    __syncthreads();
  }
  #pragma unroll
  for (int i = 0; i < 4; i++) {
    #pragma unroll
    for (int j = 0; j < 4; j++) {
      int col = n0 + wc * 64 + j * 16 + (lane & 15);
      float bv = bias ? bias[col] : 0.f;
      #pragma unroll
      for (int v = 0; v < 4; v++) {
        int row = m0 + wr * 64 + i * 16 + (lane >> 4) * 4 + v;
        int orow = permute ? ((row & 31) * TLEN + (row >> 5)) : row;
        C[(size_t)orow * N + col] = acc[i][j][v] + bv;
      }
    }
  }
}

// --- encoder wavefront: K-split waves, chunked L3 exchange ------------------
// 192 blocks (l = bx>>6, jg = bx&63), 512 thr = 8 waves: op = wave>>2
// (0 -> h@Wh, 1 -> x@Wx), ks = wave&3 (K-slice of 256). Each wave: B-frags for
// all 4 gates over its K-slice (128 VGPR); A-frags direct from chunked hxC.
// hxC layout: [3 layers][2 parity][64 chunks][32 rows][16 cols] bf16.
__global__ __launch_bounds__(512, 1) void enc_wave(
    const float*  __restrict__ Zpre,   // [128][32][4096] layer-0 pregates (incl bias)
    const ushort* __restrict__ WhT,    // 3 x [4096][1024]
    const ushort* __restrict__ WxT,    // 2 x [4096][1024] (layers 1,2 -> idx l-1)
    const float*  __restrict__ bE,     // [3][4096]
    ushort*       __restrict__ hxC,    // [3][2][64][32][16] chunked (pre-zeroed)
    float*        __restrict__ cSe,    // [3][32][1024] c state (pre-zeroed)
    ushort*       __restrict__ hS,     // [3][32][1024] final h out (linear)
    unsigned*     __restrict__ flags)  // 192 flags, stride 4 dwords
{
  const int bx = blockIdx.x;
  const int l = bx >> 6, jg = bx & 63;
  const int j0 = jg * 16;
  const int tid = threadIdx.x;
  const int lane = tid & 63, wave = tid >> 6;
  const int op = wave >> 2, ks = wave & 3;
  const int rr = tid >> 4, jj = tid & 15;           // combine: 512 thr = 32x16

  __shared__ float zp[8][4][32][17];   // [wave][gate][row][col+pad]

  float cc = cSe[(size_t)l * 32768 + rr * HID + j0 + jj];
  float bias4[4];
  #pragma unroll
  for (int g = 0; g < 4; g++)
    bias4[g] = bE[l * G4 + g * HID + j0 + jj];

  const bool mfma_on = (l > 0) || (op == 0);
  bf8 bw[4][8];
  if (mfma_on) {
    const ushort* Wb = op ? (WxT + (size_t)(l - 1) * G4 * HID)
                          : (WhT + (size_t)l * G4 * HID);
    #pragma unroll
    for (int g = 0; g < 4; g++) {
      const ushort* Bp = Wb + (size_t)(g * HID + j0 + (lane & 15)) * HID
                       + ks * 256 + (lane >> 4) * 8;
      #pragma unroll
      for (int kk = 0; kk < 8; kk++)
        bw[g][kk] = *(const bf8*)(Bp + kk * 32);
    }
  }

  const int r0 = lane & 15, r1 = r0 + 16;
  const int lk = lane >> 4;
  // chunk layout A-frag offsets (ushort units): chunk = ks*16 + kk*2 + (lk>>1)
  const int aoff0 = ks * 8192 + (lk >> 1) * 512 + r0 * 16 + (lk & 1) * 8;
  const int aoff1 = ks * 8192 + (lk >> 1) * 512 + r1 * 16 + (lk & 1) * 8;

  float zv4[4], zn4[4];
  if (l == 0) {
    #pragma unroll
    for (int g = 0; g < 4; g++)
      zv4[g] = Zpre[(size_t)rr * G4 + g * HID + j0 + jj];
  }

  for (int w = 0; w < 130; ++w) {
    if (w > 0) {
      if (wave == 0) {
        for (;;) {
          unsigned a, b, c;
          ld4_sys3(a, b, c, flags + lane * 4, flags + (64 + lane) * 4,
                   flags + (128 + lane) * 4);
          if (!__ballot(a < (unsigned)w || b < (unsigned)w || c < (unsigned)w)) break;
          __builtin_amdgcn_s_sleep(1);
        }
      }
      __syncthreads();
    }
    const int t = w - l;
    if (t >= 0 && t < TLEN) {
      // ---- A-fragments direct from chunked L3 exchange ----
      uint4 ha0[8], ha1[8];
      if (mfma_on) {
        const ushort* src = (op == 0)
          ? hxC + ((size_t)l * 2 + ((t - 1) & 1)) * 32768          // own h_{t-1}
          : hxC + ((size_t)(l - 1) * 2 + (t & 1)) * 32768;         // below's y_t
        #pragma unroll
        for (int kk = 0; kk < 8; kk++) {
          ld16_sys(ha0[kk], src + aoff0 + kk * 1024);
          ld16_sys(ha1[kk], src + aoff1 + kk * 1024);
        }
        wait_vm0();
      }

      if (l == 0 && t + 1 < TLEN) {
        const float* Ztn = Zpre + (size_t)(t + 1) * 32 * G4;
        #pragma unroll
        for (int g = 0; g < 4; g++)
          zn4[g] = Ztn[(size_t)rr * G4 + g * HID + j0 + jj];
      }

      if (mfma_on) {
        f4 acc0[4], acc1[4];
        #pragma unroll
        for (int g = 0; g < 4; g++) { acc0[g] = (f4){0,0,0,0}; acc1[g] = (f4){0,0,0,0}; }
        #pragma unroll
        for (int kk = 0; kk < 8; kk++) {
          bf8 a0 = __builtin_bit_cast(bf8, ha0[kk]);
          bf8 a1 = __builtin_bit_cast(bf8, ha1[kk]);
          #pragma unroll
          for (int g = 0; g < 4; g++) {
            acc0[g] = __builtin_amdgcn_mfma_f32_16x16x32_bf16(a0, bw[g][kk], acc0[g], 0, 0, 0);
            acc1[g] = __builtin_amdgcn_mfma_f32_16x16x32_bf16(a1, bw[g][kk], acc1[g], 0, 0, 0);
          }
        }
        #pragma unroll
        for (int g = 0; g < 4; g++)
          #pragma unroll
          for (int v = 0; v < 4; v++) {
            zp[wave][g][(lane >> 4) * 4 + v][lane & 15]      = acc0[g][v];
            zp[wave][g][16 + (lane >> 4) * 4 + v][lane & 15] = acc1[g][v];
          }
      }
      __syncthreads();

      // ---- combine + gates (thread owns row rr, col j0+jj) ----
      float z[4];
      #pragma unroll
      for (int g = 0; g < 4; g++) {
        float s = zp[0][g][rr][jj] + zp[1][g][rr][jj]
                + zp[2][g][rr][jj] + zp[3][g][rr][jj];
        if (l > 0)
          s += zp[4][g][rr][jj] + zp[5][g][rr][jj]
             + zp[6][g][rr][jj] + zp[7][g][rr][jj] + bias4[g];
        else
          s += zv4[g];
        z[g] = s;
      }
      if (l == 0) {
        #pragma unroll
        for (int g = 0; g < 4; g++) zv4[g] = zn4[g];
      }
      float ig = sigmoidf_(z[0]), fg = sigmoidf_(z[1]);
      float gv = tanhf(z[2]),     og = sigmoidf_(z[3]);
      cc = fg * cc + ig * gv;
      float hv = og * tanhf(cc);
      ushort hb = f2bf(hv);
      // chunked publish: even-jj threads store packed 4B (full-line pattern)
      unsigned u = (unsigned)hb;
      unsigned nb = __shfl_xor(u, 1);
      if ((jj & 1) == 0)
        st4_sys(hxC + ((size_t)l * 2 + (t & 1)) * 32768 + jg * 512 + rr * 16 + jj,
                u | (nb << 16));
      if (t == TLEN - 1) {
        hS [(size_t)l * 32768 + rr * HID + j0 + jj] = hb;
        cSe[(size_t)l * 32768 + rr * HID + j0 + jj] = cc;
      }
      wait_vm0();
    }
    __syncthreads();
    if (tid == 0) st4_sys(flags + bx * 4, (unsigned)(w + 1));
  }
}

// --- decoder per-layer persistent recurrence (proven round-9 scheme) --------
__global__ __launch_bounds__(256, 1) void lstm_seq(
    const float*  __restrict__ Zpre,   // [TLEN][32][4096] (incl bias)
    const ushort* __restrict__ Wht,    // [4096][1024]
    float*        __restrict__ cS,     // [32][1024] c state in/out
    ushort*       __restrict__ yout,   // [TLEN][32][1024] linear out
    ushort*       __restrict__ hx,     // [2][64][32][16] chunked exchange
    unsigned*     __restrict__ flags)  // 64 flags, stride 4 dwords
{
  const int jg = blockIdx.x;
  const int j0 = jg * 16;
  const int tid = threadIdx.x;
  const int lane = tid & 63, wave = tid >> 6;
  const int rr = tid >> 3, cp = tid & 7;

  __shared__ float zp[4][4][32][17];   // [k-slice wave][gate][row][col+pad]

  float2 cc = *(const float2*)(cS + (size_t)rr * HID + j0 + 2 * cp);

  bf8 bw[4][8];
  #pragma unroll
  for (int g = 0; g < 4; g++) {
    const ushort* Bp = Wht + (size_t)(g * HID + j0 + (lane & 15)) * HID
                     + wave * 256 + (lane >> 4) * 8;
    #pragma unroll
    for (int kk = 0; kk < 8; kk++)
      bw[g][kk] = *(const bf8*)(Bp + kk * 32);
  }

  const int r0 = lane & 15, r1 = r0 + 16;
  const int lk = lane >> 4;
  const int aoff0 = wave * 8192 + (lk >> 1) * 512 + r0 * 16 + (lk & 1) * 8;
  const int aoff1 = wave * 8192 + (lk >> 1) * 512 + r1 * 16 + (lk & 1) * 8;

  float2 zv[4], zn[4];
  #pragma unroll
  for (int g = 0; g < 4; g++)
    zv[g] = *(const float2*)(Zpre + (size_t)rr * G4 + g * HID + j0 + 2 * cp);

  for (int t = 0; t < TLEN; ++t) {
    if (t > 0) {
      if (wave == 0) {
        const unsigned* fp = flags + lane * 4;
        while (__ballot(ld4_sys(fp) < (unsigned)t)) __builtin_amdgcn_s_sleep(1);
      }
      __syncthreads();
    }
    const ushort* hsrc = hx + ((t + 1) & 1) * 32768;
    uint4 ha0[8], ha1[8];
    #pragma unroll
    for (int kk = 0; kk < 8; kk++) {
      ld16_sys(ha0[kk], hsrc + aoff0 + kk * 1024);
      ld16_sys(ha1[kk], hsrc + aoff1 + kk * 1024);
    }
    wait_vm0();

    if (t + 1 < TLEN) {
      const float* Ztn = Zpre + (size_t)(t + 1) * 32 * G4;
      #pragma unroll
      for (int g = 0; g < 4; g++)
        zn[g] = *(const float2*)(Ztn + (size_t)rr * G4 + g * HID + j0 + 2 * cp);
    }

    f4 acc0[4], acc1[4];
    #pragma unroll
    for (int g = 0; g < 4; g++) { acc0[g] = (f4){0,0,0,0}; acc1[g] = (f4){0,0,0,0}; }
    #pragma unroll
    for (int kk = 0; kk < 8; kk++) {
      bf8 a0 = __builtin_bit_cast(bf8, ha0[kk]);
      bf8 a1 = __builtin_bit_cast(bf8, ha1[kk]);
      #pragma unroll
      for (int g = 0; g < 4; g++) {
        acc0[g] = __builtin_amdgcn_mfma_f32_16x16x32_bf16(a0, bw[g][kk], acc0[g], 0, 0, 0);
        acc1[g] = __builtin_amdgcn_mfma_f32_16x16x32_bf16(a1, bw[g][kk], acc1[g], 0, 0, 0);
      }
    }
    #pragma unroll
    for (int g = 0; g < 4; g++)
      #pragma unroll
      for (int v = 0; v < 4; v++) {
        zp[wave][g][(lane >> 4) * 4 + v][lane & 15]      = acc0[g][v];
        zp[wave][g][16 + (lane >> 4) * 4 + v][lane & 15] = acc1[g][v];
      }
    __syncthreads();

    float zx[4], zy[4];
    #pragma unroll
    for (int g = 0; g < 4; g++) {
      zx[g] = zv[g].x + zp[0][g][rr][2 * cp]     + zp[1][g][rr][2 * cp]
                      + zp[2][g][rr][2 * cp]     + zp[3][g][rr][2 * cp];
      zy[g] = zv[g].y + zp[0][g][rr][2 * cp + 1] + zp[1][g][rr][2 * cp + 1]
                      + zp[2][g][rr][2 * cp + 1] + zp[3][g][rr][2 * cp + 1];
    }
    cc.x = sigmoidf_(zx[1]) * cc.x + sigmoidf_(zx[0]) * tanhf(zx[2]);
    cc.y = sigmoidf_(zy[1]) * cc.y + sigmoidf_(zy[0]) * tanhf(zy[2]);
    float hv0 = sigmoidf_(zx[3]) * tanhf(cc.x);
    float hv1 = sigmoidf_(zy[3]) * tanhf(cc.y);
    unsigned packed = (unsigned)f2bf(hv0) | ((unsigned)f2bf(hv1) << 16);
    *(unsigned*)(yout + (size_t)t * 32768 + rr * HID + j0 + 2 * cp) = packed;
    st4_sys(hx + (size_t)(t & 1) * 32768 + jg * 512 + rr * 16 + 2 * cp, packed);
    #pragma unroll
    for (int g = 0; g < 4; g++) zv[g] = zn[g];

    wait_vm0();
    __syncthreads();
    if (tid == 0) st4_sys(flags + jg * 4, (unsigned)(t + 1));
  }
  *(float2*)(cS + (size_t)rr * HID + j0 + 2 * cp) = cc;
}

// --- prep kernels -----------------------------------------------------------
__global__ __launch_bounds__(256) void prep_enc(ushort* hxC, float* cSe,
                                                unsigned* flags) {
  int i = blockIdx.x * 256 + threadIdx.x;      // 768 blocks * 256 = 196608
  hxC[i] = 0;
  if (i < 98304) cSe[i] = 0.f;
  if (i < 192)   flags[i * 4] = 0;
}
// h0 -> chunk layout into hx[1]; c copy; flag reset
__global__ __launch_bounds__(256) void prep_dec0(const ushort* __restrict__ hS2,
                                                 const float* __restrict__ cSe2,
                                                 float* cS, ushort* hx,
                                                 unsigned* flags) {
  int i = blockIdx.x * 256 + threadIdx.x;      // 128 blocks * 256 = 32768
  int row = i >> 10, col = i & 1023;
  hx[32768 + (col >> 4) * 512 + row * 16 + (col & 15)] = hS2[i];
  cS[i] = cSe2[i];
  if (i < NBLK_SEQ) flags[i * 4] = 0;
}
__global__ __launch_bounds__(256) void prep_copy(const ushort* __restrict__ src,
                                                 ushort* __restrict__ hx,
                                                 unsigned* __restrict__ flags) {
  int i = blockIdx.x * 256 + threadIdx.x;
  int row = i >> 10, col = i & 1023;
  hx[32768 + (col >> 4) * 512 + row * 16 + (col & 15)] = src[i];
  if (i < NBLK_SEQ) flags[i * 4] = 0;
}

// ---------------------------------------------------------------------------
extern "C" void kernel_launch(void* const* d_in, const int* in_sizes, int n_in,
                              void* d_out, int out_size, void* d_ws, size_t ws_size,
                              hipStream_t stream) {
  const int*   enc_ids = (const int*)d_in[0];
  const int*   dec_ids = (const int*)d_in[1];
  const float* emb     = (const float*)d_in[2];
  const float* Wx_enc  = (const float*)d_in[3];
  const float* Wh_enc  = (const float*)d_in[4];
  const float* b_enc   = (const float*)d_in[5];
  const float* Wx_dec  = (const float*)d_in[6];
  const float* Wh_dec  = (const float*)d_in[7];
  const float* b_dec   = (const float*)d_in[8];
  const float* dense_W = (const float*)d_in[9];
  const float* dense_b = (const float*)d_in[10];
  float* out = (float*)d_out;

  // ---- d_ws layout (proven footprint) ----
  char* ws = (char*)d_ws;
  const size_t SZ_BUF = (size_t)4096 * 1024 * 2;   // 8 MiB
  ushort*   bufA   = (ushort*)(ws);
  ushort*   bufB   = (ushort*)(ws + SZ_BUF);
  ushort*   Wxt    = (ushort*)(ws + 2 * SZ_BUF);
  ushort*   Wht    = (ushort*)(ws + 3 * SZ_BUF);
  ushort*   dWt    = (ushort*)(ws + 4 * SZ_BUF);   // VOC*1024*2 B
  char*     p2     = ws + 4 * SZ_BUF + (size_t)VOC * 1024 * 2;
  float*    cS     = (float*)(p2 + (size_t)32 * 1024 * 2);   // 128 KiB
  unsigned* flags  = (unsigned*)(p2 + (size_t)32 * 1024 * 2 + (size_t)32 * 1024 * 4);

  // ---- d_out dead-region scratch (500 MB buffer, dense head writes last) --
  char* ob = (char*)d_out;
  float*    Zpre   = out;                                        // [0, 64 MiB)
  ushort*   WhTe   = (ushort*)(ob + (size_t)64  * 1024 * 1024);  // 3 x 8 MiB
  ushort*   WxTe   = (ushort*)(ob + (size_t)88  * 1024 * 1024);  // 2 x 8 MiB
  char*     st     = ob + (size_t)112 * 1024 * 1024;
  ushort*   hxC    = (ushort*)st;                                // 384 KiB chunked
  float*    cSe    = (float*)(st + 393216);                      // 384 KiB
  ushort*   hS     = (ushort*)(st + 786432);                     // 192 KiB
  unsigned* flags2 = (unsigned*)(st + 983040);                   // 3 KiB
  ushort*   hxD    = (ushort*)(ob + (size_t)120 * 1024 * 1024);  // 128 KiB chunked
  const size_t WSTRIDE = (size_t)G4 * HID;                       // elements

  transpose_cvt<<<dim3(VOC / 32, 1024 / 32), 256, 0, stream>>>(dense_W, dWt, 1024, VOC);

  // ---------------- encoder ----------------
  embed_kernel<<<4096, 256, 0, stream>>>(enc_ids, emb, bufA);
  transpose_cvt<<<dim3(G4 / 32, 32), 256, 0, stream>>>(Wx_enc, Wxt, 1024, G4);
  gemm_bt<<<dim3(G4 / 128, 4096 / 128), 256, 0, stream>>>(bufA, Wxt, b_enc,
                                                          Zpre, 4096, G4, 1024, 0);
  for (int l = 0; l < 3; l++)
    transpose_cvt<<<dim3(G4 / 32, 32), 256, 0, stream>>>(Wh_enc + (size_t)l * 1024 * G4,
                                                         WhTe + l * WSTRIDE, 1024, G4);
  for (int l = 1; l < 3; l++)
    transpose_cvt<<<dim3(G4 / 32, 32), 256, 0, stream>>>(Wx_enc + (size_t)l * 1024 * G4,
                                                         WxTe + (l - 1) * WSTRIDE, 1024, G4);
  prep_enc<<<768, 256, 0, stream>>>(hxC, cSe, flags2);
  enc_wave<<<192, 512, 0, stream>>>(Zpre, WhTe, WxTe, b_enc, hxC, cSe, hS, flags2);

  // ---------------- decoder (serial chaining -> per-layer) ----------------
  embed_kernel<<<4096, 256, 0, stream>>>(dec_ids, emb, bufA);
  ushort* cur = bufA; ushort* oth = bufB;
  for (int l = 0; l < 3; l++) {
    transpose_cvt<<<dim3(G4 / 32, 32), 256, 0, stream>>>(Wx_dec + (size_t)l * 1024 * G4, Wxt, 1024, G4);
    transpose_cvt<<<dim3(G4 / 32, 32), 256, 0, stream>>>(Wh_dec + (size_t)l * 1024 * G4, Wht, 1024, G4);
    gemm_bt<<<dim3(G4 / 128, 4096 / 128), 256, 0, stream>>>(cur, Wxt, b_dec + (size_t)l * G4,
                                                            Zpre, 4096, G4, 1024, 0);
    if (l == 0) {
      prep_dec0<<<128, 256, 0, stream>>>(hS + 2 * 32768, cSe + 2 * 32768, cS, hxD, flags);
    } else {
      const ushort* h0src = cur + (size_t)127 * 32 * HID;
      prep_copy<<<128, 256, 0, stream>>>(h0src, hxD, flags);   // c chains in cS
    }
    lstm_seq<<<NBLK_SEQ, 256, 0, stream>>>(Zpre, Wht, cS, oth, hxD, flags);
    ushort* tmp = cur; cur = oth; oth = tmp;
  }

  // ---------------- dense head: logits[b][t][v] ----------------
  gemm_bt<<<dim3(VOC / 128, 4096 / 128), 256, 0, stream>>>(cur, dWt, dense_b, out,
                                                           4096, VOC, 1024, 1);
}

// Round 11
// 3134.235 us; speedup vs baseline: 5.1139x; 1.0083x over previous
//
#include <hip/hip_runtime.h>

// ---------------------------------------------------------------------------
// Seq2seq: 3-layer LSTM encoder + 3-layer LSTM decoder + dense vocab head
// B=32 T=128 V=32000 E=H=1024 L=3
// Encoder: persistent wavefront kernel (192 blocks = 3 layers x 64 col-blocks,
//   512 thr = 8 waves = {h,x} x {K-slice 0..3}). A-frags direct from chunked
//   L3 exchange into registers. All-wave polling (no post-poll barrier).
// Decoder: per-layer persistent kernel (64 blocks, 4 K-split waves), chunked
//   L3 exchange; flags monotonic ACROSS layers (fbase = l*128) and layer
//   l+1's h0 is already in the correct parity slot -> no inter-layer preps.
// Exchange coherence: sys-scope (sc0 sc1) ld/st bypass L1/L2, coherent at L3.
// GEMMs: 128x128 tile, BK=64 via dual 32-wide LDS buffers (half the barrier
//   count of BK=32); XCD-aware bijective block swizzle (all grids %8 == 0).
// ---------------------------------------------------------------------------

typedef __bf16 bf8 __attribute__((ext_vector_type(8)));
typedef float  f4  __attribute__((ext_vector_type(4)));

#define TLEN  128
#define HID   1024
#define G4    4096
#define VOC   32000
#define NBLK_SEQ 64

__device__ __forceinline__ ushort f2bf(float f) {
  unsigned u = __builtin_bit_cast(unsigned, f);
  u += 0x7fffu + ((u >> 16) & 1u);          // round-to-nearest-even
  return (ushort)(u >> 16);
}
__device__ __forceinline__ float sigmoidf_(float x) { return 1.f / (1.f + expf(-x)); }

// ---- system-scope (bypass L1+L2, coherent at L3) memory ops ----------------
__device__ __forceinline__ void ld16_sys(uint4& v, const void* p) {
  asm volatile("global_load_dwordx4 %0, %1, off sc0 sc1" : "=v"(v) : "v"(p));
}
__device__ __forceinline__ unsigned ld4_sys(const void* p) {
  unsigned v;
  asm volatile("global_load_dword %0, %1, off sc0 sc1\n\ts_waitcnt vmcnt(0)"
               : "=v"(v) : "v"(p) : "memory");
  return v;
}
__device__ __forceinline__ void ld4_sys3(unsigned& a, unsigned& b, unsigned& c,
                                         const void* pa, const void* pb, const void* pc) {
  asm volatile("global_load_dword %0, %3, off sc0 sc1\n\t"
               "global_load_dword %1, %4, off sc0 sc1\n\t"
               "global_load_dword %2, %5, off sc0 sc1\n\t"
               "s_waitcnt vmcnt(0)"
               : "=&v"(a), "=&v"(b), "=&v"(c)
               : "v"(pa), "v"(pb), "v"(pc) : "memory");
}
__device__ __forceinline__ void st4_sys(void* p, unsigned v) {
  asm volatile("global_store_dword %0, %1, off sc0 sc1" :: "v"(p), "v"(v) : "memory");
}
__device__ __forceinline__ void wait_vm0() {
  asm volatile("s_waitcnt vmcnt(0)" ::: "memory");
  __builtin_amdgcn_sched_barrier(0);
}

typedef const __attribute__((address_space(1))) void GvoidC;
typedef __attribute__((address_space(3))) void Lvoid;
__device__ __forceinline__ void g2l16(const void* g, void* l) {
  __builtin_amdgcn_global_load_lds((GvoidC*)g, (Lvoid*)l, 16, 0, 0);
}

// --- embedding gather: out[t*32+b][e] = bf16(emb[ids[b][t]][e]) -------------
__global__ __launch_bounds__(256) void embed_kernel(const int* __restrict__ ids,
    const float* __restrict__ emb, ushort* __restrict__ out) {
  int r = blockIdx.x;            // r = t*32 + b
  int b = r & 31, t = r >> 5;
  int id = ids[b * TLEN + t];
  const float4* src = (const float4*)(emb + (size_t)id * HID);
  float4 v = src[threadIdx.x];
  ushort4 o;
  o.x = f2bf(v.x); o.y = f2bf(v.y); o.z = f2bf(v.z); o.w = f2bf(v.w);
  *(ushort4*)(out + (size_t)r * HID + threadIdx.x * 4) = o;
}

// --- f32 [R][C] -> bf16 [C][R] tiled transpose ------------------------------
__global__ __launch_bounds__(256) void transpose_cvt(const float* __restrict__ W,
    ushort* __restrict__ Wt, int R, int C) {
  __shared__ float tile[32][33];
  int tx = threadIdx.x & 31, ty = threadIdx.x >> 5;   // ty 0..7
  int c0 = blockIdx.x * 32, r0 = blockIdx.y * 32;
  #pragma unroll
  for (int i = 0; i < 32; i += 8)
    tile[ty + i][tx] = W[(size_t)(r0 + ty + i) * C + c0 + tx];
  __syncthreads();
  #pragma unroll
  for (int i = 0; i < 32; i += 8)
    Wt[(size_t)(c0 + ty + i) * R + r0 + tx] = f2bf(tile[tx][ty + i]);
}

// --- bf16 MFMA GEMM: C[M][N] = A[M][K] @ Bt[N][K]^T + bias ------------------
// 128x128 tile, BK=64 via two 32-wide LDS buffers (one barrier pair / 64-K).
// XCD-aware bijective swizzle (requires nwg % 8 == 0; grids 1024/1024/8000).
// K must be a multiple of 64 (K = 1024 for all calls here).
__global__ __launch_bounds__(256) void gemm_bt(const ushort* __restrict__ A,
    const ushort* __restrict__ Bt, const float* __restrict__ bias,
    float* __restrict__ C, int M, int N, int K, int permute) {
  __shared__ __align__(16) ushort lA[2 * 128 * 32];
  __shared__ __align__(16) ushort lB[2 * 128 * 32];
  int tid = threadIdx.x;
  int lane = tid & 63, wave = tid >> 6;
  int nwg = gridDim.x * gridDim.y;
  int wg  = blockIdx.y * gridDim.x + blockIdx.x;
  int q   = nwg >> 3;
  int swg = (wg & 7) * q + (wg >> 3);          // bijective when nwg % 8 == 0
  int m0 = (swg / gridDim.x) * 128, n0 = (swg % gridDim.x) * 128;
  int wr = wave >> 1, wc = wave & 1;
  f4 zero = {0.f, 0.f, 0.f, 0.f};
  f4 acc[4][4];
  #pragma unroll
  for (int i = 0; i < 4; i++)
    #pragma unroll
    for (int j = 0; j < 4; j++) acc[i][j] = zero;

  const ushort* Ag = A  + (size_t)(m0 + wave * 32 + (lane >> 2)) * K + (lane & 3) * 8;
  const ushort* Bg = Bt + (size_t)(n0 + wave * 32 + (lane >> 2)) * K + (lane & 3) * 8;
  ushort* lApa = lA + wave * 1024;            // buf 0, rows wave*32..
  ushort* lApb = lA + 4096 + wave * 1024;     // buf 1
  ushort* lBpa = lB + wave * 1024;
  ushort* lBpb = lB + 4096 + wave * 1024;

  for (int kt = 0; kt < K; kt += 64) {
    g2l16(Ag + kt,                    lApa);
    g2l16(Ag + (size_t)16 * K + kt,       lApa + 512);
    g2l16(Ag + kt + 32,               lApb);
    g2l16(Ag + (size_t)16 * K + kt + 32,  lApb + 512);
    g2l16(Bg + kt,                    lBpa);
    g2l16(Bg + (size_t)16 * K + kt,       lBpa + 512);
    g2l16(Bg + kt + 32,               lBpb);
    g2l16(Bg + (size_t)16 * K + kt + 32,  lBpb + 512);
    __syncthreads();
    #pragma unroll
    for (int h = 0; h < 2; h++) {
      const ushort* ab = lA + h * 4096;
      const ushort* bb = lB + h * 4096;
      bf8 aF[4], bF[4];
      #pragma unroll
      for (int i = 0; i < 4; i++)
        aF[i] = *(const bf8*)(ab + (wr * 64 + i * 16 + (lane & 15)) * 32 + (lane >> 4) * 8);
      #pragma unroll
      for (int j = 0; j < 4; j++)
        bF[j] = *(const bf8*)(bb + (wc * 64 + j * 16 + (lane & 15)) * 32 + (lane >> 4) * 8);
      #pragma unroll
      for (int i = 0; i < 4; i++)
        #pragma unroll
        for (int j = 0; j < 4; j++)
          acc[i][j] = __builtin_amdgcn_mfma_f32_16x16x32_bf16(aF[i], bF[j], acc[i][j], 0, 0, 0);
    }
    __syncthreads();
  }
  #pragma unroll
  for (int i = 0; i < 4; i++) {
    #pragma unroll
    for (int j = 0; j < 4; j++) {
      int col = n0 + wc * 64 + j * 16 + (lane & 15);
      float bv = bias ? bias[col] : 0.f;
      #pragma unroll
      for (int v = 0; v < 4; v++) {
        int row = m0 + wr * 64 + i * 16 + (lane >> 4) * 4 + v;
        int orow = permute ? ((row & 31) * TLEN + (row >> 5)) : row;
        C[(size_t)orow * N + col] = acc[i][j][v] + bv;
      }
    }
  }
}

// --- encoder wavefront: K-split waves, chunked L3 exchange ------------------
// 192 blocks (l = bx>>6, jg = bx&63), 512 thr = 8 waves: op = wave>>2
// (0 -> h@Wh, 1 -> x@Wx), ks = wave&3 (K-slice of 256). All data-reading
// waves poll independently (no post-poll barrier).
__global__ __launch_bounds__(512, 1) void enc_wave(
    const float*  __restrict__ Zpre,   // [128][32][4096] layer-0 pregates (incl bias)
    const ushort* __restrict__ WhT,    // 3 x [4096][1024]
    const ushort* __restrict__ WxT,    // 2 x [4096][1024] (layers 1,2 -> idx l-1)
    const float*  __restrict__ bE,     // [3][4096]
    ushort*       __restrict__ hxC,    // [3][2][64][32][16] chunked (pre-zeroed)
    float*        __restrict__ cSe,    // [3][32][1024] c state (pre-zeroed)
    ushort*       __restrict__ hS,     // [3][32][1024] final h out (linear)
    unsigned*     __restrict__ flags)  // 192 flags, stride 4 dwords
{
  const int bx = blockIdx.x;
  const int l = bx >> 6, jg = bx & 63;
  const int j0 = jg * 16;
  const int tid = threadIdx.x;
  const int lane = tid & 63, wave = tid >> 6;
  const int op = wave >> 2, ks = wave & 3;
  const int rr = tid >> 4, jj = tid & 15;           // combine: 512 thr = 32x16

  __shared__ float zp[8][4][32][17];   // [wave][gate][row][col+pad]

  float cc = cSe[(size_t)l * 32768 + rr * HID + j0 + jj];
  float bias4[4];
  #pragma unroll
  for (int g = 0; g < 4; g++)
    bias4[g] = bE[l * G4 + g * HID + j0 + jj];

  const bool mfma_on = (l > 0) || (op == 0);
  bf8 bw[4][8];
  if (mfma_on) {
    const ushort* Wb = op ? (WxT + (size_t)(l - 1) * G4 * HID)
                          : (WhT + (size_t)l * G4 * HID);
    #pragma unroll
    for (int g = 0; g < 4; g++) {
      const ushort* Bp = Wb + (size_t)(g * HID + j0 + (lane & 15)) * HID
                       + ks * 256 + (lane >> 4) * 8;
      #pragma unroll
      for (int kk = 0; kk < 8; kk++)
        bw[g][kk] = *(const bf8*)(Bp + kk * 32);
    }
  }

  const int r0 = lane & 15, r1 = r0 + 16;
  const int lk = lane >> 4;
  const int aoff0 = ks * 8192 + (lk >> 1) * 512 + r0 * 16 + (lk & 1) * 8;
  const int aoff1 = ks * 8192 + (lk >> 1) * 512 + r1 * 16 + (lk & 1) * 8;

  float zv4[4], zn4[4];
  if (l == 0) {
    #pragma unroll
    for (int g = 0; g < 4; g++)
      zv4[g] = Zpre[(size_t)rr * G4 + g * HID + j0 + jj];
  }

  for (int w = 0; w < 130; ++w) {
    // all data-reading waves poll independently; no barrier afterward
    if (w > 0 && mfma_on) {
      for (;;) {
        unsigned a, b, c;
        ld4_sys3(a, b, c, flags + lane * 4, flags + (64 + lane) * 4,
                 flags + (128 + lane) * 4);
        if (!__ballot(a < (unsigned)w || b < (unsigned)w || c < (unsigned)w)) break;
      }
    }
    const int t = w - l;
    if (t >= 0 && t < TLEN) {
      // ---- A-fragments direct from chunked L3 exchange ----
      uint4 ha0[8], ha1[8];
      if (mfma_on) {
        const ushort* src = (op == 0)
          ? hxC + ((size_t)l * 2 + ((t - 1) & 1)) * 32768          // own h_{t-1}
          : hxC + ((size_t)(l - 1) * 2 + (t & 1)) * 32768;         // below's y_t
        #pragma unroll
        for (int kk = 0; kk < 8; kk++) {
          ld16_sys(ha0[kk], src + aoff0 + kk * 1024);
          ld16_sys(ha1[kk], src + aoff1 + kk * 1024);
        }
        wait_vm0();
      }

      if (l == 0 && t + 1 < TLEN) {
        const float* Ztn = Zpre + (size_t)(t + 1) * 32 * G4;
        #pragma unroll
        for (int g = 0; g < 4; g++)
          zn4[g] = Ztn[(size_t)rr * G4 + g * HID + j0 + jj];
      }

      if (mfma_on) {
        f4 acc0[4], acc1[4];
        #pragma unroll
        for (int g = 0; g < 4; g++) { acc0[g] = (f4){0,0,0,0}; acc1[g] = (f4){0,0,0,0}; }
        #pragma unroll
        for (int kk = 0; kk < 8; kk++) {
          bf8 a0 = __builtin_bit_cast(bf8, ha0[kk]);
          bf8 a1 = __builtin_bit_cast(bf8, ha1[kk]);
          #pragma unroll
          for (int g = 0; g < 4; g++) {
            acc0[g] = __builtin_amdgcn_mfma_f32_16x16x32_bf16(a0, bw[g][kk], acc0[g], 0, 0, 0);
            acc1[g] = __builtin_amdgcn_mfma_f32_16x16x32_bf16(a1, bw[g][kk], acc1[g], 0, 0, 0);
          }
        }
        #pragma unroll
        for (int g = 0; g < 4; g++)
          #pragma unroll
          for (int v = 0; v < 4; v++) {
            zp[wave][g][(lane >> 4) * 4 + v][lane & 15]      = acc0[g][v];
            zp[wave][g][16 + (lane >> 4) * 4 + v][lane & 15] = acc1[g][v];
          }
      }
      __syncthreads();

      // ---- combine + gates (thread owns row rr, col j0+jj) ----
      float z[4];
      #pragma unroll
      for (int g = 0; g < 4; g++) {
        float s = zp[0][g][rr][jj] + zp[1][g][rr][jj]
                + zp[2][g][rr][jj] + zp[3][g][rr][jj];
        if (l > 0)
          s += zp[4][g][rr][jj] + zp[5][g][rr][jj]
             + zp[6][g][rr][jj] + zp[7][g][rr][jj] + bias4[g];
        else
          s += zv4[g];
        z[g] = s;
      }
      if (l == 0) {
        #pragma unroll
        for (int g = 0; g < 4; g++) zv4[g] = zn4[g];
      }
      float ig = sigmoidf_(z[0]), fg = sigmoidf_(z[1]);
      float gv = tanhf(z[2]),     og = sigmoidf_(z[3]);
      cc = fg * cc + ig * gv;
      float hv = og * tanhf(cc);
      ushort hb = f2bf(hv);
      // chunked publish: even-jj threads store packed 4B (full-line pattern)
      unsigned u = (unsigned)hb;
      unsigned nb = __shfl_xor(u, 1);
      if ((jj & 1) == 0)
        st4_sys(hxC + ((size_t)l * 2 + (t & 1)) * 32768 + jg * 512 + rr * 16 + jj,
                u | (nb << 16));
      if (t == TLEN - 1) {
        hS [(size_t)l * 32768 + rr * HID + j0 + jj] = hb;
        cSe[(size_t)l * 32768 + rr * HID + j0 + jj] = cc;
      }
      wait_vm0();
    }
    __syncthreads();
    if (tid == 0) st4_sys(flags + bx * 4, (unsigned)(w + 1));
  }
}

// --- decoder per-layer persistent recurrence --------------------------------
// Flags monotonic across layers: layer l uses fbase = l*TLEN; h0 for layers
// 1,2 is already in the correct parity slot (prev layer's last publish).
__global__ __launch_bounds__(256, 1) void lstm_seq(
    const float*  __restrict__ Zpre,   // [TLEN][32][4096] (incl bias)
    const ushort* __restrict__ Wht,    // [4096][1024]
    float*        __restrict__ cS,     // [32][1024] c state in/out
    ushort*       __restrict__ yout,   // [TLEN][32][1024] linear out
    ushort*       __restrict__ hx,     // [2][64][32][16] chunked exchange
    unsigned*     __restrict__ flags,  // 64 flags, stride 4 dwords
    unsigned fbase)
{
  const int jg = blockIdx.x;
  const int j0 = jg * 16;
  const int tid = threadIdx.x;
  const int lane = tid & 63, wave = tid >> 6;
  const int rr = tid >> 3, cp = tid & 7;

  __shared__ float zp[4][4][32][17];   // [k-slice wave][gate][row][col+pad]

  float2 cc = *(const float2*)(cS + (size_t)rr * HID + j0 + 2 * cp);

  bf8 bw[4][8];
  #pragma unroll
  for (int g = 0; g < 4; g++) {
    const ushort* Bp = Wht + (size_t)(g * HID + j0 + (lane & 15)) * HID
                     + wave * 256 + (lane >> 4) * 8;
    #pragma unroll
    for (int kk = 0; kk < 8; kk++)
      bw[g][kk] = *(const bf8*)(Bp + kk * 32);
  }

  const int r0 = lane & 15, r1 = r0 + 16;
  const int lk = lane >> 4;
  const int aoff0 = wave * 8192 + (lk >> 1) * 512 + r0 * 16 + (lk & 1) * 8;
  const int aoff1 = wave * 8192 + (lk >> 1) * 512 + r1 * 16 + (lk & 1) * 8;

  float2 zv[4], zn[4];
  #pragma unroll
  for (int g = 0; g < 4; g++)
    zv[g] = *(const float2*)(Zpre + (size_t)rr * G4 + g * HID + j0 + 2 * cp);

  for (int t = 0; t < TLEN; ++t) {
    // all 4 waves poll independently; no barrier afterward
    if (t > 0) {
      const unsigned* fp = flags + lane * 4;
      const unsigned want = fbase + (unsigned)t;
      while (__ballot(ld4_sys(fp) < want)) {}
    }
    const ushort* hsrc = hx + ((t + 1) & 1) * 32768;
    uint4 ha0[8], ha1[8];
    #pragma unroll
    for (int kk = 0; kk < 8; kk++) {
      ld16_sys(ha0[kk], hsrc + aoff0 + kk * 1024);
      ld16_sys(ha1[kk], hsrc + aoff1 + kk * 1024);
    }
    wait_vm0();

    if (t + 1 < TLEN) {
      const float* Ztn = Zpre + (size_t)(t + 1) * 32 * G4;
      #pragma unroll
      for (int g = 0; g < 4; g++)
        zn[g] = *(const float2*)(Ztn + (size_t)rr * G4 + g * HID + j0 + 2 * cp);
    }

    f4 acc0[4], acc1[4];
    #pragma unroll
    for (int g = 0; g < 4; g++) { acc0[g] = (f4){0,0,0,0}; acc1[g] = (f4){0,0,0,0}; }
    #pragma unroll
    for (int kk = 0; kk < 8; kk++) {
      bf8 a0 = __builtin_bit_cast(bf8, ha0[kk]);
      bf8 a1 = __builtin_bit_cast(bf8, ha1[kk]);
      #pragma unroll
      for (int g = 0; g < 4; g++) {
        acc0[g] = __builtin_amdgcn_mfma_f32_16x16x32_bf16(a0, bw[g][kk], acc0[g], 0, 0, 0);
        acc1[g] = __builtin_amdgcn_mfma_f32_16x16x32_bf16(a1, bw[g][kk], acc1[g], 0, 0, 0);
      }
    }
    #pragma unroll
    for (int g = 0; g < 4; g++)
      #pragma unroll
      for (int v = 0; v < 4; v++) {
        zp[wave][g][(lane >> 4) * 4 + v][lane & 15]      = acc0[g][v];
        zp[wave][g][16 + (lane >> 4) * 4 + v][lane & 15] = acc1[g][v];
      }
    __syncthreads();

    float zx[4], zy[4];
    #pragma unroll
    for (int g = 0; g < 4; g++) {
      zx[g] = zv[g].x + zp[0][g][rr][2 * cp]     + zp[1][g][rr][2 * cp]
                      + zp[2][g][rr][2 * cp]     + zp[3][g][rr][2 * cp];
      zy[g] = zv[g].y + zp[0][g][rr][2 * cp + 1] + zp[1][g][rr][2 * cp + 1]
                      + zp[2][g][rr][2 * cp + 1] + zp[3][g][rr][2 * cp + 1];
    }
    cc.x = sigmoidf_(zx[1]) * cc.x + sigmoidf_(zx[0]) * tanhf(zx[2]);
    cc.y = sigmoidf_(zy[1]) * cc.y + sigmoidf_(zy[0]) * tanhf(zy[2]);
    float hv0 = sigmoidf_(zx[3]) * tanhf(cc.x);
    float hv1 = sigmoidf_(zy[3]) * tanhf(cc.y);
    unsigned packed = (unsigned)f2bf(hv0) | ((unsigned)f2bf(hv1) << 16);
    *(unsigned*)(yout + (size_t)t * 32768 + rr * HID + j0 + 2 * cp) = packed;
    st4_sys(hx + (size_t)(t & 1) * 32768 + jg * 512 + rr * 16 + 2 * cp, packed);
    #pragma unroll
    for (int g = 0; g < 4; g++) zv[g] = zn[g];

    wait_vm0();
    __syncthreads();
    if (tid == 0) st4_sys(flags + jg * 4, fbase + (unsigned)(t + 1));
  }
  *(float2*)(cS + (size_t)rr * HID + j0 + 2 * cp) = cc;
}

// --- prep kernels -----------------------------------------------------------
__global__ __launch_bounds__(256) void prep_enc(ushort* hxC, float* cSe,
                                                unsigned* flags) {
  int i = blockIdx.x * 256 + threadIdx.x;      // 768 blocks * 256 = 196608
  hxC[i] = 0;
  if (i < 98304) cSe[i] = 0.f;
  if (i < 192)   flags[i * 4] = 0;
}
// enc final state -> chunk layout into hx[1]; c copy; flags zeroed (once)
__global__ __launch_bounds__(256) void prep_dec0(const ushort* __restrict__ hS2,
                                                 const float* __restrict__ cSe2,
                                                 float* cS, ushort* hx,
                                                 unsigned* flags) {
  int i = blockIdx.x * 256 + threadIdx.x;      // 128 blocks * 256 = 32768
  int row = i >> 10, col = i & 1023;
  hx[32768 + (col >> 4) * 512 + row * 16 + (col & 15)] = hS2[i];
  cS[i] = cSe2[i];
  if (i < NBLK_SEQ) flags[i * 4] = 0;
}

// ---------------------------------------------------------------------------
extern "C" void kernel_launch(void* const* d_in, const int* in_sizes, int n_in,
                              void* d_out, int out_size, void* d_ws, size_t ws_size,
                              hipStream_t stream) {
  const int*   enc_ids = (const int*)d_in[0];
  const int*   dec_ids = (const int*)d_in[1];
  const float* emb     = (const float*)d_in[2];
  const float* Wx_enc  = (const float*)d_in[3];
  const float* Wh_enc  = (const float*)d_in[4];
  const float* b_enc   = (const float*)d_in[5];
  const float* Wx_dec  = (const float*)d_in[6];
  const float* Wh_dec  = (const float*)d_in[7];
  const float* b_dec   = (const float*)d_in[8];
  const float* dense_W = (const float*)d_in[9];
  const float* dense_b = (const float*)d_in[10];
  float* out = (float*)d_out;

  // ---- d_ws layout (proven footprint) ----
  char* ws = (char*)d_ws;
  const size_t SZ_BUF = (size_t)4096 * 1024 * 2;   // 8 MiB
  ushort*   bufA   = (ushort*)(ws);
  ushort*   bufB   = (ushort*)(ws + SZ_BUF);
  ushort*   Wxt    = (ushort*)(ws + 2 * SZ_BUF);
  ushort*   Wht    = (ushort*)(ws + 3 * SZ_BUF);
  ushort*   dWt    = (ushort*)(ws + 4 * SZ_BUF);   // VOC*1024*2 B
  char*     p2     = ws + 4 * SZ_BUF + (size_t)VOC * 1024 * 2;
  float*    cS     = (float*)(p2 + (size_t)32 * 1024 * 2);   // 128 KiB
  unsigned* flags  = (unsigned*)(p2 + (size_t)32 * 1024 * 2 + (size_t)32 * 1024 * 4);

  // ---- d_out dead-region scratch (500 MB buffer, dense head writes last) --
  char* ob = (char*)d_out;
  float*    Zpre   = out;                                        // [0, 64 MiB)
  ushort*   WhTe   = (ushort*)(ob + (size_t)64  * 1024 * 1024);  // 3 x 8 MiB
  ushort*   WxTe   = (ushort*)(ob + (size_t)88  * 1024 * 1024);  // 2 x 8 MiB
  char*     st     = ob + (size_t)112 * 1024 * 1024;
  ushort*   hxC    = (ushort*)st;                                // 384 KiB chunked
  float*    cSe    = (float*)(st + 393216);                      // 384 KiB
  ushort*   hS     = (ushort*)(st + 786432);                     // 192 KiB
  unsigned* flags2 = (unsigned*)(st + 983040);                   // 3 KiB
  ushort*   hxD    = (ushort*)(ob + (size_t)120 * 1024 * 1024);  // 128 KiB chunked
  const size_t WSTRIDE = (size_t)G4 * HID;                       // elements

  transpose_cvt<<<dim3(VOC / 32, 1024 / 32), 256, 0, stream>>>(dense_W, dWt, 1024, VOC);

  // ---------------- encoder ----------------
  embed_kernel<<<4096, 256, 0, stream>>>(enc_ids, emb, bufA);
  transpose_cvt<<<dim3(G4 / 32, 32), 256, 0, stream>>>(Wx_enc, Wxt, 1024, G4);
  gemm_bt<<<dim3(G4 / 128, 4096 / 128), 256, 0, stream>>>(bufA, Wxt, b_enc,
                                                          Zpre, 4096, G4, 1024, 0);
  for (int l = 0; l < 3; l++)
    transpose_cvt<<<dim3(G4 / 32, 32), 256, 0, stream>>>(Wh_enc + (size_t)l * 1024 * G4,
                                                         WhTe + l * WSTRIDE, 1024, G4);
  for (int l = 1; l < 3; l++)
    transpose_cvt<<<dim3(G4 / 32, 32), 256, 0, stream>>>(Wx_enc + (size_t)l * 1024 * G4,
                                                         WxTe + (l - 1) * WSTRIDE, 1024, G4);
  prep_enc<<<768, 256, 0, stream>>>(hxC, cSe, flags2);
  enc_wave<<<192, 512, 0, stream>>>(Zpre, WhTe, WxTe, b_enc, hxC, cSe, hS, flags2);

  // ---------------- decoder (serial chaining -> per-layer) ----------------
  embed_kernel<<<4096, 256, 0, stream>>>(dec_ids, emb, bufA);
  ushort* cur = bufA; ushort* oth = bufB;
  for (int l = 0; l < 3; l++) {
    transpose_cvt<<<dim3(G4 / 32, 32), 256, 0, stream>>>(Wx_dec + (size_t)l * 1024 * G4, Wxt, 1024, G4);
    transpose_cvt<<<dim3(G4 / 32, 32), 256, 0, stream>>>(Wh_dec + (size_t)l * 1024 * G4, Wht, 1024, G4);
    gemm_bt<<<dim3(G4 / 128, 4096 / 128), 256, 0, stream>>>(cur, Wxt, b_dec + (size_t)l * G4,
                                                            Zpre, 4096, G4, 1024, 0);
    if (l == 0)
      prep_dec0<<<128, 256, 0, stream>>>(hS + 2 * 32768, cSe + 2 * 32768, cS, hxD, flags);
    // layers 1,2: h0 already in hxD parity-1 slot; c chains in cS; flags continue
    lstm_seq<<<NBLK_SEQ, 256, 0, stream>>>(Zpre, Wht, cS, oth, hxD, flags,
                                           (unsigned)(l * TLEN));
    ushort* tmp = cur; cur = oth; oth = tmp;
  }

  // ---------------- dense head: logits[b][t][v] ----------------
  gemm_bt<<<dim3(VOC / 128, 4096 / 128), 256, 0, stream>>>(cur, dWt, dense_b, out,
                                                           4096, VOC, 1024, 1);
}

// Round 12
// 3044.670 us; speedup vs baseline: 5.2643x; 1.0294x over previous
//
#include <hip/hip_runtime.h>

// ---------------------------------------------------------------------------
// Seq2seq: 3-layer LSTM encoder + 3-layer LSTM decoder + dense vocab head
// B=32 T=128 V=32000 E=H=1024 L=3
// Encoder: persistent wavefront kernel (192 blocks = 3 layers x 64 col-blocks,
//   512 thr = 8 waves = {h,x} x {K-slice 0..3}). A-frags direct from chunked
//   L3 exchange into registers. Poll: wave0-only + s_sleep + barrier (the
//   all-wave no-sleep variant regressed: 4600 poll streams contend at L3).
// Decoder: per-layer persistent kernel (64 blocks, 4 K-split waves), chunked
//   L3 exchange; all-wave polling (only 256 streams: fine); flags monotonic
//   ACROSS layers (fbase = l*128); h0 for layers 1,2 already in parity slot.
// Exchange coherence: sys-scope (sc0 sc1) ld/st bypass L1/L2, coherent at L3.
// GEMMs: 128x128 tile, BK=64 via dual 32-wide LDS buffers; XCD-aware
//   bijective block swizzle (all grids %8 == 0).
// ---------------------------------------------------------------------------

typedef __bf16 bf8 __attribute__((ext_vector_type(8)));
typedef float  f4  __attribute__((ext_vector_type(4)));

#define TLEN  128
#define HID   1024
#define G4    4096
#define VOC   32000
#define NBLK_SEQ 64

__device__ __forceinline__ ushort f2bf(float f) {
  unsigned u = __builtin_bit_cast(unsigned, f);
  u += 0x7fffu + ((u >> 16) & 1u);          // round-to-nearest-even
  return (ushort)(u >> 16);
}
__device__ __forceinline__ float sigmoidf_(float x) { return 1.f / (1.f + expf(-x)); }

// ---- system-scope (bypass L1+L2, coherent at L3) memory ops ----------------
__device__ __forceinline__ void ld16_sys(uint4& v, const void* p) {
  asm volatile("global_load_dwordx4 %0, %1, off sc0 sc1" : "=v"(v) : "v"(p));
}
__device__ __forceinline__ unsigned ld4_sys(const void* p) {
  unsigned v;
  asm volatile("global_load_dword %0, %1, off sc0 sc1\n\ts_waitcnt vmcnt(0)"
               : "=v"(v) : "v"(p) : "memory");
  return v;
}
__device__ __forceinline__ void ld4_sys3(unsigned& a, unsigned& b, unsigned& c,
                                         const void* pa, const void* pb, const void* pc) {
  asm volatile("global_load_dword %0, %3, off sc0 sc1\n\t"
               "global_load_dword %1, %4, off sc0 sc1\n\t"
               "global_load_dword %2, %5, off sc0 sc1\n\t"
               "s_waitcnt vmcnt(0)"
               : "=&v"(a), "=&v"(b), "=&v"(c)
               : "v"(pa), "v"(pb), "v"(pc) : "memory");
}
__device__ __forceinline__ void st4_sys(void* p, unsigned v) {
  asm volatile("global_store_dword %0, %1, off sc0 sc1" :: "v"(p), "v"(v) : "memory");
}
__device__ __forceinline__ void wait_vm0() {
  asm volatile("s_waitcnt vmcnt(0)" ::: "memory");
  __builtin_amdgcn_sched_barrier(0);
}

typedef const __attribute__((address_space(1))) void GvoidC;
typedef __attribute__((address_space(3))) void Lvoid;
__device__ __forceinline__ void g2l16(const void* g, void* l) {
  __builtin_amdgcn_global_load_lds((GvoidC*)g, (Lvoid*)l, 16, 0, 0);
}

// --- embedding gather: out[t*32+b][e] = bf16(emb[ids[b][t]][e]) -------------
__global__ __launch_bounds__(256) void embed_kernel(const int* __restrict__ ids,
    const float* __restrict__ emb, ushort* __restrict__ out) {
  int r = blockIdx.x;            // r = t*32 + b
  int b = r & 31, t = r >> 5;
  int id = ids[b * TLEN + t];
  const float4* src = (const float4*)(emb + (size_t)id * HID);
  float4 v = src[threadIdx.x];
  ushort4 o;
  o.x = f2bf(v.x); o.y = f2bf(v.y); o.z = f2bf(v.z); o.w = f2bf(v.w);
  *(ushort4*)(out + (size_t)r * HID + threadIdx.x * 4) = o;
}

// --- f32 [R][C] -> bf16 [C][R] tiled transpose ------------------------------
__global__ __launch_bounds__(256) void transpose_cvt(const float* __restrict__ W,
    ushort* __restrict__ Wt, int R, int C) {
  __shared__ float tile[32][33];
  int tx = threadIdx.x & 31, ty = threadIdx.x >> 5;   // ty 0..7
  int c0 = blockIdx.x * 32, r0 = blockIdx.y * 32;
  #pragma unroll
  for (int i = 0; i < 32; i += 8)
    tile[ty + i][tx] = W[(size_t)(r0 + ty + i) * C + c0 + tx];
  __syncthreads();
  #pragma unroll
  for (int i = 0; i < 32; i += 8)
    Wt[(size_t)(c0 + ty + i) * R + r0 + tx] = f2bf(tile[tx][ty + i]);
}

// --- bf16 MFMA GEMM: C[M][N] = A[M][K] @ Bt[N][K]^T + bias ------------------
// 128x128 tile, BK=64 via two 32-wide LDS buffers (one barrier pair / 64-K).
// XCD-aware bijective swizzle (requires nwg % 8 == 0; grids 1024/1024/8000).
__global__ __launch_bounds__(256) void gemm_bt(const ushort* __restrict__ A,
    const ushort* __restrict__ Bt, const float* __restrict__ bias,
    float* __restrict__ C, int M, int N, int K, int permute) {
  __shared__ __align__(16) ushort lA[2 * 128 * 32];
  __shared__ __align__(16) ushort lB[2 * 128 * 32];
  int tid = threadIdx.x;
  int lane = tid & 63, wave = tid >> 6;
  int nwg = gridDim.x * gridDim.y;
  int wg  = blockIdx.y * gridDim.x + blockIdx.x;
  int q   = nwg >> 3;
  int swg = (wg & 7) * q + (wg >> 3);          // bijective when nwg % 8 == 0
  int m0 = (swg / gridDim.x) * 128, n0 = (swg % gridDim.x) * 128;
  int wr = wave >> 1, wc = wave & 1;
  f4 zero = {0.f, 0.f, 0.f, 0.f};
  f4 acc[4][4];
  #pragma unroll
  for (int i = 0; i < 4; i++)
    #pragma unroll
    for (int j = 0; j < 4; j++) acc[i][j] = zero;

  const ushort* Ag = A  + (size_t)(m0 + wave * 32 + (lane >> 2)) * K + (lane & 3) * 8;
  const ushort* Bg = Bt + (size_t)(n0 + wave * 32 + (lane >> 2)) * K + (lane & 3) * 8;
  ushort* lApa = lA + wave * 1024;            // buf 0, rows wave*32..
  ushort* lApb = lA + 4096 + wave * 1024;     // buf 1
  ushort* lBpa = lB + wave * 1024;
  ushort* lBpb = lB + 4096 + wave * 1024;

  for (int kt = 0; kt < K; kt += 64) {
    g2l16(Ag + kt,                    lApa);
    g2l16(Ag + (size_t)16 * K + kt,       lApa + 512);
    g2l16(Ag + kt + 32,               lApb);
    g2l16(Ag + (size_t)16 * K + kt + 32,  lApb + 512);
    g2l16(Bg + kt,                    lBpa);
    g2l16(Bg + (size_t)16 * K + kt,       lBpa + 512);
    g2l16(Bg + kt + 32,               lBpb);
    g2l16(Bg + (size_t)16 * K + kt + 32,  lBpb + 512);
    __syncthreads();
    #pragma unroll
    for (int h = 0; h < 2; h++) {
      const ushort* ab = lA + h * 4096;
      const ushort* bb = lB + h * 4096;
      bf8 aF[4], bF[4];
      #pragma unroll
      for (int i = 0; i < 4; i++)
        aF[i] = *(const bf8*)(ab + (wr * 64 + i * 16 + (lane & 15)) * 32 + (lane >> 4) * 8);
      #pragma unroll
      for (int j = 0; j < 4; j++)
        bF[j] = *(const bf8*)(bb + (wc * 64 + j * 16 + (lane & 15)) * 32 + (lane >> 4) * 8);
      #pragma unroll
      for (int i = 0; i < 4; i++)
        #pragma unroll
        for (int j = 0; j < 4; j++)
          acc[i][j] = __builtin_amdgcn_mfma_f32_16x16x32_bf16(aF[i], bF[j], acc[i][j], 0, 0, 0);
    }
    __syncthreads();
  }
  #pragma unroll
  for (int i = 0; i < 4; i++) {
    #pragma unroll
    for (int j = 0; j < 4; j++) {
      int col = n0 + wc * 64 + j * 16 + (lane & 15);
      float bv = bias ? bias[col] : 0.f;
      #pragma unroll
      for (int v = 0; v < 4; v++) {
        int row = m0 + wr * 64 + i * 16 + (lane >> 4) * 4 + v;
        int orow = permute ? ((row & 31) * TLEN + (row >> 5)) : row;
        C[(size_t)orow * N + col] = acc[i][j][v] + bv;
      }
    }
  }
}

// --- encoder wavefront: K-split waves, chunked L3 exchange ------------------
// 192 blocks (l = bx>>6, jg = bx&63), 512 thr = 8 waves: op = wave>>2
// (0 -> h@Wh, 1 -> x@Wx), ks = wave&3 (K-slice of 256).
// Poll: wave0 only + s_sleep, then barrier (proven round-10 structure).
__global__ __launch_bounds__(512, 1) void enc_wave(
    const float*  __restrict__ Zpre,   // [128][32][4096] layer-0 pregates (incl bias)
    const ushort* __restrict__ WhT,    // 3 x [4096][1024]
    const ushort* __restrict__ WxT,    // 2 x [4096][1024] (layers 1,2 -> idx l-1)
    const float*  __restrict__ bE,     // [3][4096]
    ushort*       __restrict__ hxC,    // [3][2][64][32][16] chunked (pre-zeroed)
    float*        __restrict__ cSe,    // [3][32][1024] c state (pre-zeroed)
    ushort*       __restrict__ hS,     // [3][32][1024] final h out (linear)
    unsigned*     __restrict__ flags)  // 192 flags, stride 4 dwords
{
  const int bx = blockIdx.x;
  const int l = bx >> 6, jg = bx & 63;
  const int j0 = jg * 16;
  const int tid = threadIdx.x;
  const int lane = tid & 63, wave = tid >> 6;
  const int op = wave >> 2, ks = wave & 3;
  const int rr = tid >> 4, jj = tid & 15;           // combine: 512 thr = 32x16

  __shared__ float zp[8][4][32][17];   // [wave][gate][row][col+pad]

  float cc = cSe[(size_t)l * 32768 + rr * HID + j0 + jj];
  float bias4[4];
  #pragma unroll
  for (int g = 0; g < 4; g++)
    bias4[g] = bE[l * G4 + g * HID + j0 + jj];

  const bool mfma_on = (l > 0) || (op == 0);
  bf8 bw[4][8];
  if (mfma_on) {
    const ushort* Wb = op ? (WxT + (size_t)(l - 1) * G4 * HID)
                          : (WhT + (size_t)l * G4 * HID);
    #pragma unroll
    for (int g = 0; g < 4; g++) {
      const ushort* Bp = Wb + (size_t)(g * HID + j0 + (lane & 15)) * HID
                       + ks * 256 + (lane >> 4) * 8;
      #pragma unroll
      for (int kk = 0; kk < 8; kk++)
        bw[g][kk] = *(const bf8*)(Bp + kk * 32);
    }
  }

  const int r0 = lane & 15, r1 = r0 + 16;
  const int lk = lane >> 4;
  const int aoff0 = ks * 8192 + (lk >> 1) * 512 + r0 * 16 + (lk & 1) * 8;
  const int aoff1 = ks * 8192 + (lk >> 1) * 512 + r1 * 16 + (lk & 1) * 8;

  float zv4[4], zn4[4];
  if (l == 0) {
    #pragma unroll
    for (int g = 0; g < 4; g++)
      zv4[g] = Zpre[(size_t)rr * G4 + g * HID + j0 + jj];
  }

  for (int w = 0; w < 130; ++w) {
    if (w > 0) {
      if (wave == 0) {
        for (;;) {
          unsigned a, b, c;
          ld4_sys3(a, b, c, flags + lane * 4, flags + (64 + lane) * 4,
                   flags + (128 + lane) * 4);
          if (!__ballot(a < (unsigned)w || b < (unsigned)w || c < (unsigned)w)) break;
          __builtin_amdgcn_s_sleep(1);
        }
      }
      __syncthreads();
    }
    const int t = w - l;
    if (t >= 0 && t < TLEN) {
      // ---- A-fragments direct from chunked L3 exchange ----
      uint4 ha0[8], ha1[8];
      if (mfma_on) {
        const ushort* src = (op == 0)
          ? hxC + ((size_t)l * 2 + ((t - 1) & 1)) * 32768          // own h_{t-1}
          : hxC + ((size_t)(l - 1) * 2 + (t & 1)) * 32768;         // below's y_t
        #pragma unroll
        for (int kk = 0; kk < 8; kk++) {
          ld16_sys(ha0[kk], src + aoff0 + kk * 1024);
          ld16_sys(ha1[kk], src + aoff1 + kk * 1024);
        }
        wait_vm0();
      }

      if (l == 0 && t + 1 < TLEN) {
        const float* Ztn = Zpre + (size_t)(t + 1) * 32 * G4;
        #pragma unroll
        for (int g = 0; g < 4; g++)
          zn4[g] = Ztn[(size_t)rr * G4 + g * HID + j0 + jj];
      }

      if (mfma_on) {
        f4 acc0[4], acc1[4];
        #pragma unroll
        for (int g = 0; g < 4; g++) { acc0[g] = (f4){0,0,0,0}; acc1[g] = (f4){0,0,0,0}; }
        #pragma unroll
        for (int kk = 0; kk < 8; kk++) {
          bf8 a0 = __builtin_bit_cast(bf8, ha0[kk]);
          bf8 a1 = __builtin_bit_cast(bf8, ha1[kk]);
          #pragma unroll
          for (int g = 0; g < 4; g++) {
            acc0[g] = __builtin_amdgcn_mfma_f32_16x16x32_bf16(a0, bw[g][kk], acc0[g], 0, 0, 0);
            acc1[g] = __builtin_amdgcn_mfma_f32_16x16x32_bf16(a1, bw[g][kk], acc1[g], 0, 0, 0);
          }
        }
        #pragma unroll
        for (int g = 0; g < 4; g++)
          #pragma unroll
          for (int v = 0; v < 4; v++) {
            zp[wave][g][(lane >> 4) * 4 + v][lane & 15]      = acc0[g][v];
            zp[wave][g][16 + (lane >> 4) * 4 + v][lane & 15] = acc1[g][v];
          }
      }
      __syncthreads();

      // ---- combine + gates (thread owns row rr, col j0+jj) ----
      float z[4];
      #pragma unroll
      for (int g = 0; g < 4; g++) {
        float s = zp[0][g][rr][jj] + zp[1][g][rr][jj]
                + zp[2][g][rr][jj] + zp[3][g][rr][jj];
        if (l > 0)
          s += zp[4][g][rr][jj] + zp[5][g][rr][jj]
             + zp[6][g][rr][jj] + zp[7][g][rr][jj] + bias4[g];
        else
          s += zv4[g];
        z[g] = s;
      }
      if (l == 0) {
        #pragma unroll
        for (int g = 0; g < 4; g++) zv4[g] = zn4[g];
      }
      float ig = sigmoidf_(z[0]), fg = sigmoidf_(z[1]);
      float gv = tanhf(z[2]),     og = sigmoidf_(z[3]);
      cc = fg * cc + ig * gv;
      float hv = og * tanhf(cc);
      ushort hb = f2bf(hv);
      // chunked publish: even-jj threads store packed 4B (full-line pattern)
      unsigned u = (unsigned)hb;
      unsigned nb = __shfl_xor(u, 1);
      if ((jj & 1) == 0)
        st4_sys(hxC + ((size_t)l * 2 + (t & 1)) * 32768 + jg * 512 + rr * 16 + jj,
                u | (nb << 16));
      if (t == TLEN - 1) {
        hS [(size_t)l * 32768 + rr * HID + j0 + jj] = hb;
        cSe[(size_t)l * 32768 + rr * HID + j0 + jj] = cc;
      }
      wait_vm0();
    }
    __syncthreads();
    if (tid == 0) st4_sys(flags + bx * 4, (unsigned)(w + 1));
  }
}

// --- decoder per-layer persistent recurrence --------------------------------
// Flags monotonic across layers: layer l uses fbase = l*TLEN; h0 for layers
// 1,2 is already in the correct parity slot (prev layer's last publish).
__global__ __launch_bounds__(256, 1) void lstm_seq(
    const float*  __restrict__ Zpre,   // [TLEN][32][4096] (incl bias)
    const ushort* __restrict__ Wht,    // [4096][1024]
    float*        __restrict__ cS,     // [32][1024] c state in/out
    ushort*       __restrict__ yout,   // [TLEN][32][1024] linear out
    ushort*       __restrict__ hx,     // [2][64][32][16] chunked exchange
    unsigned*     __restrict__ flags,  // 64 flags, stride 4 dwords
    unsigned fbase)
{
  const int jg = blockIdx.x;
  const int j0 = jg * 16;
  const int tid = threadIdx.x;
  const int lane = tid & 63, wave = tid >> 6;
  const int rr = tid >> 3, cp = tid & 7;

  __shared__ float zp[4][4][32][17];   // [k-slice wave][gate][row][col+pad]

  float2 cc = *(const float2*)(cS + (size_t)rr * HID + j0 + 2 * cp);

  bf8 bw[4][8];
  #pragma unroll
  for (int g = 0; g < 4; g++) {
    const ushort* Bp = Wht + (size_t)(g * HID + j0 + (lane & 15)) * HID
                     + wave * 256 + (lane >> 4) * 8;
    #pragma unroll
    for (int kk = 0; kk < 8; kk++)
      bw[g][kk] = *(const bf8*)(Bp + kk * 32);
  }

  const int r0 = lane & 15, r1 = r0 + 16;
  const int lk = lane >> 4;
  const int aoff0 = wave * 8192 + (lk >> 1) * 512 + r0 * 16 + (lk & 1) * 8;
  const int aoff1 = wave * 8192 + (lk >> 1) * 512 + r1 * 16 + (lk & 1) * 8;

  float2 zv[4], zn[4];
  #pragma unroll
  for (int g = 0; g < 4; g++)
    zv[g] = *(const float2*)(Zpre + (size_t)rr * G4 + g * HID + j0 + 2 * cp);

  for (int t = 0; t < TLEN; ++t) {
    // all 4 waves poll independently; no barrier afterward (256 streams: ok)
    if (t > 0) {
      const unsigned* fp = flags + lane * 4;
      const unsigned want = fbase + (unsigned)t;
      while (__ballot(ld4_sys(fp) < want)) {}
    }
    const ushort* hsrc = hx + ((t + 1) & 1) * 32768;
    uint4 ha0[8], ha1[8];
    #pragma unroll
    for (int kk = 0; kk < 8; kk++) {
      ld16_sys(ha0[kk], hsrc + aoff0 + kk * 1024);
      ld16_sys(ha1[kk], hsrc + aoff1 + kk * 1024);
    }
    wait_vm0();

    if (t + 1 < TLEN) {
      const float* Ztn = Zpre + (size_t)(t + 1) * 32 * G4;
      #pragma unroll
      for (int g = 0; g < 4; g++)
        zn[g] = *(const float2*)(Ztn + (size_t)rr * G4 + g * HID + j0 + 2 * cp);
    }

    f4 acc0[4], acc1[4];
    #pragma unroll
    for (int g = 0; g < 4; g++) { acc0[g] = (f4){0,0,0,0}; acc1[g] = (f4){0,0,0,0}; }
    #pragma unroll
    for (int kk = 0; kk < 8; kk++) {
      bf8 a0 = __builtin_bit_cast(bf8, ha0[kk]);
      bf8 a1 = __builtin_bit_cast(bf8, ha1[kk]);
      #pragma unroll
      for (int g = 0; g < 4; g++) {
        acc0[g] = __builtin_amdgcn_mfma_f32_16x16x32_bf16(a0, bw[g][kk], acc0[g], 0, 0, 0);
        acc1[g] = __builtin_amdgcn_mfma_f32_16x16x32_bf16(a1, bw[g][kk], acc1[g], 0, 0, 0);
      }
    }
    #pragma unroll
    for (int g = 0; g < 4; g++)
      #pragma unroll
      for (int v = 0; v < 4; v++) {
        zp[wave][g][(lane >> 4) * 4 + v][lane & 15]      = acc0[g][v];
        zp[wave][g][16 + (lane >> 4) * 4 + v][lane & 15] = acc1[g][v];
      }
    __syncthreads();

    float zx[4], zy[4];
    #pragma unroll
    for (int g = 0; g < 4; g++) {
      zx[g] = zv[g].x + zp[0][g][rr][2 * cp]     + zp[1][g][rr][2 * cp]
                      + zp[2][g][rr][2 * cp]     + zp[3][g][rr][2 * cp];
      zy[g] = zv[g].y + zp[0][g][rr][2 * cp + 1] + zp[1][g][rr][2 * cp + 1]
                      + zp[2][g][rr][2 * cp + 1] + zp[3][g][rr][2 * cp + 1];
    }
    cc.x = sigmoidf_(zx[1]) * cc.x + sigmoidf_(zx[0]) * tanhf(zx[2]);
    cc.y = sigmoidf_(zy[1]) * cc.y + sigmoidf_(zy[0]) * tanhf(zy[2]);
    float hv0 = sigmoidf_(zx[3]) * tanhf(cc.x);
    float hv1 = sigmoidf_(zy[3]) * tanhf(cc.y);
    unsigned packed = (unsigned)f2bf(hv0) | ((unsigned)f2bf(hv1) << 16);
    *(unsigned*)(yout + (size_t)t * 32768 + rr * HID + j0 + 2 * cp) = packed;
    st4_sys(hx + (size_t)(t & 1) * 32768 + jg * 512 + rr * 16 + 2 * cp, packed);
    #pragma unroll
    for (int g = 0; g < 4; g++) zv[g] = zn[g];

    wait_vm0();
    __syncthreads();
    if (tid == 0) st4_sys(flags + jg * 4, fbase + (unsigned)(t + 1));
  }
  *(float2*)(cS + (size_t)rr * HID + j0 + 2 * cp) = cc;
}

// --- prep kernels -----------------------------------------------------------
__global__ __launch_bounds__(256) void prep_enc(ushort* hxC, float* cSe,
                                                unsigned* flags) {
  int i = blockIdx.x * 256 + threadIdx.x;      // 768 blocks * 256 = 196608
  hxC[i] = 0;
  if (i < 98304) cSe[i] = 0.f;
  if (i < 192)   flags[i * 4] = 0;
}
// enc final state -> chunk layout into hx[1]; c copy; flags zeroed (once)
__global__ __launch_bounds__(256) void prep_dec0(const ushort* __restrict__ hS2,
                                                 const float* __restrict__ cSe2,
                                                 float* cS, ushort* hx,
                                                 unsigned* flags) {
  int i = blockIdx.x * 256 + threadIdx.x;      // 128 blocks * 256 = 32768
  int row = i >> 10, col = i & 1023;
  hx[32768 + (col >> 4) * 512 + row * 16 + (col & 15)] = hS2[i];
  cS[i] = cSe2[i];
  if (i < NBLK_SEQ) flags[i * 4] = 0;
}

// ---------------------------------------------------------------------------
extern "C" void kernel_launch(void* const* d_in, const int* in_sizes, int n_in,
                              void* d_out, int out_size, void* d_ws, size_t ws_size,
                              hipStream_t stream) {
  const int*   enc_ids = (const int*)d_in[0];
  const int*   dec_ids = (const int*)d_in[1];
  const float* emb     = (const float*)d_in[2];
  const float* Wx_enc  = (const float*)d_in[3];
  const float* Wh_enc  = (const float*)d_in[4];
  const float* b_enc   = (const float*)d_in[5];
  const float* Wx_dec  = (const float*)d_in[6];
  const float* Wh_dec  = (const float*)d_in[7];
  const float* b_dec   = (const float*)d_in[8];
  const float* dense_W = (const float*)d_in[9];
  const float* dense_b = (const float*)d_in[10];
  float* out = (float*)d_out;

  // ---- d_ws layout (proven footprint) ----
  char* ws = (char*)d_ws;
  const size_t SZ_BUF = (size_t)4096 * 1024 * 2;   // 8 MiB
  ushort*   bufA   = (ushort*)(ws);
  ushort*   bufB   = (ushort*)(ws + SZ_BUF);
  ushort*   Wxt    = (ushort*)(ws + 2 * SZ_BUF);
  ushort*   Wht    = (ushort*)(ws + 3 * SZ_BUF);
  ushort*   dWt    = (ushort*)(ws + 4 * SZ_BUF);   // VOC*1024*2 B
  char*     p2     = ws + 4 * SZ_BUF + (size_t)VOC * 1024 * 2;
  float*    cS     = (float*)(p2 + (size_t)32 * 1024 * 2);   // 128 KiB
  unsigned* flags  = (unsigned*)(p2 + (size_t)32 * 1024 * 2 + (size_t)32 * 1024 * 4);

  // ---- d_out dead-region scratch (500 MB buffer, dense head writes last) --
  char* ob = (char*)d_out;
  float*    Zpre   = out;                                        // [0, 64 MiB)
  ushort*   WhTe   = (ushort*)(ob + (size_t)64  * 1024 * 1024);  // 3 x 8 MiB
  ushort*   WxTe   = (ushort*)(ob + (size_t)88  * 1024 * 1024);  // 2 x 8 MiB
  char*     st     = ob + (size_t)112 * 1024 * 1024;
  ushort*   hxC    = (ushort*)st;                                // 384 KiB chunked
  float*    cSe    = (float*)(st + 393216);                      // 384 KiB
  ushort*   hS     = (ushort*)(st + 786432);                     // 192 KiB
  unsigned* flags2 = (unsigned*)(st + 983040);                   // 3 KiB
  ushort*   hxD    = (ushort*)(ob + (size_t)120 * 1024 * 1024);  // 128 KiB chunked
  const size_t WSTRIDE = (size_t)G4 * HID;                       // elements

  transpose_cvt<<<dim3(VOC / 32, 1024 / 32), 256, 0, stream>>>(dense_W, dWt, 1024, VOC);

  // ---------------- encoder ----------------
  embed_kernel<<<4096, 256, 0, stream>>>(enc_ids, emb, bufA);
  transpose_cvt<<<dim3(G4 / 32, 32), 256, 0, stream>>>(Wx_enc, Wxt, 1024, G4);
  gemm_bt<<<dim3(G4 / 128, 4096 / 128), 256, 0, stream>>>(bufA, Wxt, b_enc,
                                                          Zpre, 4096, G4, 1024, 0);
  for (int l = 0; l < 3; l++)
    transpose_cvt<<<dim3(G4 / 32, 32), 256, 0, stream>>>(Wh_enc + (size_t)l * 1024 * G4,
                                                         WhTe + l * WSTRIDE, 1024, G4);
  for (int l = 1; l < 3; l++)
    transpose_cvt<<<dim3(G4 / 32, 32), 256, 0, stream>>>(Wx_enc + (size_t)l * 1024 * G4,
                                                         WxTe + (l - 1) * WSTRIDE, 1024, G4);
  prep_enc<<<768, 256, 0, stream>>>(hxC, cSe, flags2);
  enc_wave<<<192, 512, 0, stream>>>(Zpre, WhTe, WxTe, b_enc, hxC, cSe, hS, flags2);

  // ---------------- decoder (serial chaining -> per-layer) ----------------
  embed_kernel<<<4096, 256, 0, stream>>>(dec_ids, emb, bufA);
  ushort* cur = bufA; ushort* oth = bufB;
  for (int l = 0; l < 3; l++) {
    transpose_cvt<<<dim3(G4 / 32, 32), 256, 0, stream>>>(Wx_dec + (size_t)l * 1024 * G4, Wxt, 1024, G4);
    transpose_cvt<<<dim3(G4 / 32, 32), 256, 0, stream>>>(Wh_dec + (size_t)l * 1024 * G4, Wht, 1024, G4);
    gemm_bt<<<dim3(G4 / 128, 4096 / 128), 256, 0, stream>>>(cur, Wxt, b_dec + (size_t)l * G4,
                                                            Zpre, 4096, G4, 1024, 0);
    if (l == 0)
      prep_dec0<<<128, 256, 0, stream>>>(hS + 2 * 32768, cSe + 2 * 32768, cS, hxD, flags);
    // layers 1,2: h0 already in hxD parity-1 slot; c chains in cS; flags continue
    lstm_seq<<<NBLK_SEQ, 256, 0, stream>>>(Zpre, Wht, cS, oth, hxD, flags,
                                           (unsigned)(l * TLEN));
    ushort* tmp = cur; cur = oth; oth = tmp;
  }

  // ---------------- dense head: logits[b][t][v] ----------------
  gemm_bt<<<dim3(VOC / 128, 4096 / 128), 256, 0, stream>>>(cur, dWt, dense_b, out,
                                                           4096, VOC, 1024, 1);
}